// Round 13
// baseline (166.010 us; speedup 1.0000x reference)
//
#include <hip/hip_runtime.h>
#include <math.h>

typedef __bf16 bf16;
typedef __attribute__((ext_vector_type(8))) __bf16 bf16x8;
typedef __attribute__((ext_vector_type(4))) __bf16 bf16x4;
typedef __attribute__((ext_vector_type(4))) float f32x4;

typedef __attribute__((address_space(1))) unsigned int glb_u32;
typedef __attribute__((address_space(3))) unsigned int lds_u32;

#define NEGV (-4294967295.0f)
#define SCL2 0.18033688011112042f  /* 0.125 * log2(e), folded into Q */

__device__ __forceinline__ void async_cp16(const void* g, void* l) {
  __builtin_amdgcn_global_load_lds((glb_u32*)g, (lds_u32*)l, 16, 0, 0);
}

// ---- DPP 16-lane butterfly reduce (VALU pipe, not LDS) --------------------
template <int CTRL>
__device__ __forceinline__ float dppf(float x) {
  return __builtin_bit_cast(float,
      __builtin_amdgcn_mov_dpp(__builtin_bit_cast(int, x), CTRL, 0xF, 0xF, true));
}
__device__ __forceinline__ float dpp_max16(float x) {
  x = fmaxf(x, dppf<0xB1>(x));   // quad_perm xor1
  x = fmaxf(x, dppf<0x4E>(x));   // quad_perm xor2
  x = fmaxf(x, dppf<0x141>(x));  // row_half_mirror
  x = fmaxf(x, dppf<0x140>(x));  // row_mirror
  return x;
}

// ---------------- weight transpose + convert: T[n][k] = W[k][n] -----------
__global__ __launch_bounds__(256) void wt_kernel(
    const float* __restrict__ W0, const float* __restrict__ W1,
    const float* __restrict__ W2, const float* __restrict__ W3,
    short* T0, short* T1, short* T2, short* T3) {
  __shared__ float tile[64][65];
  const float* W = blockIdx.z == 0 ? W0 : (blockIdx.z == 1 ? W1 : (blockIdx.z == 2 ? W2 : W3));
  bf16* T = (bf16*)(blockIdx.z == 0 ? T0 : (blockIdx.z == 1 ? T1 : (blockIdx.z == 2 ? T2 : T3)));
  const int k0 = blockIdx.y * 64, n0 = blockIdx.x * 64;
  const int tid = threadIdx.x;
  const int c = tid & 63, rr = tid >> 6;
#pragma unroll
  for (int i = 0; i < 16; i++) {
    int r = i * 4 + rr;
    tile[r][c] = W[(size_t)(k0 + r) * 1024 + n0 + c];
  }
  __syncthreads();
#pragma unroll
  for (int i = 0; i < 16; i++) {
    int r = i * 4 + rr;
    T[(size_t)(n0 + r) * 1024 + k0 + c] = (bf16)tile[c][r];
  }
}

// ---------------- QKV projection GEMM: Y = relu(X @ W + b) ----------------
// A operand staged DIRECTLY from fp32 inputs (cvt3 kernel deleted); f32->bf16
// conversion happens at fragment-load (same rounding as before). A-tile rows
// are 128B -> XOR-swizzle (row&7)<<4 on stage-source and frag-read (else
// 16-way bank conflict).
__global__ __launch_bounds__(256) void qkv_gemm(
    const float* __restrict__ Xq, const float* __restrict__ Xk,
    const float* __restrict__ Xv,
    const short* Wtq_, const short* Wtk_, const short* Wtv_,
    const float* __restrict__ bq_, const float* __restrict__ bk_, const float* __restrict__ bv_,
    short* Qo_, short* Ko_, short* Vto_) {
  __shared__ float Af[128][32];     // fp32 A tile, 128B rows, swizzled
  __shared__ bf16 Blds[128][32];
  const int which = blockIdx.z;
  const float* X = which == 0 ? Xq : (which == 1 ? Xk : Xv);
  const bf16* Wt = (const bf16*)(which == 0 ? Wtq_ : (which == 1 ? Wtk_ : Wtv_));
  const float* bias = which == 0 ? bq_ : (which == 1 ? bk_ : bv_);
  const int m0 = blockIdx.y * 128, n0 = blockIdx.x * 128;
  const int tid = threadIdx.x, wid = tid >> 6, lane = tid & 63;
  const int wr = wid >> 1, wc = wid & 1;
  const int l15 = lane & 15, lg = lane >> 4;
  const f32x4 vzero = {0.f, 0.f, 0.f, 0.f};
  f32x4 acc[4][4];
#pragma unroll
  for (int m = 0; m < 4; m++)
#pragma unroll
    for (int n = 0; n < 4; n++) acc[m][n] = vzero;

  // A staging: 8 lanes per 128B row; one call = 8 rows; 4 calls/wave
  const int asrow = lane >> 3;                  // 0..7
  const int acbs = ((lane & 7) * 16) ^ ((asrow & 7) << 4);
  // B staging: 4 lanes per 64B row; one call = 16 rows; 2 calls/wave
  const int bsr = wid * 32 + (lane >> 2);
  const int bscb = (lane & 3) * 16;

  for (int kt = 0; kt < 32; ++kt) {
#pragma unroll
    for (int c = 0; c < 4; c++) {
      const char* ga = (const char*)(X + (size_t)(m0 + wid * 32 + c * 8 + asrow) * 1024 + kt * 32) + acbs;
      async_cp16(ga, &Af[wid * 32 + c * 8][0]);
    }
    const char* gb = (const char*)(Wt + (size_t)(n0 + bsr) * 1024 + kt * 32) + bscb;
    async_cp16(gb, &Blds[wid * 32][0]);
    async_cp16(gb + 16 * 2048, &Blds[wid * 32 + 16][0]);
    __syncthreads();
    bf16x8 a[4], bb[4];
#pragma unroll
    for (int m = 0; m < 4; m++) {
      const int row = wr * 64 + m * 16 + l15;
      const int swz = (row & 7) << 4;
      const char* ar = (const char*)&Af[0][0] + row * 128;
      const float4 f0 = *(const float4*)(ar + ((lg * 32) ^ swz));
      const float4 f1 = *(const float4*)(ar + ((lg * 32 + 16) ^ swz));
      a[m][0] = (bf16)f0.x; a[m][1] = (bf16)f0.y; a[m][2] = (bf16)f0.z; a[m][3] = (bf16)f0.w;
      a[m][4] = (bf16)f1.x; a[m][5] = (bf16)f1.y; a[m][6] = (bf16)f1.z; a[m][7] = (bf16)f1.w;
    }
#pragma unroll
    for (int n = 0; n < 4; n++) bb[n] = *(const bf16x8*)&Blds[wc * 64 + n * 16 + l15][lg * 8];
#pragma unroll
    for (int m = 0; m < 4; m++)
#pragma unroll
      for (int n = 0; n < 4; n++)
        acc[m][n] = __builtin_amdgcn_mfma_f32_16x16x32_bf16(a[m], bb[n], acc[m][n], 0, 0, 0);
    __syncthreads();
  }

  if (which != 2) {
    bf16* Y = (bf16*)(which == 0 ? Qo_ : Ko_);
    const float osc = (which == 0) ? SCL2 : 1.0f;
#pragma unroll
    for (int n = 0; n < 4; n++) {
      const int col = n0 + wc * 64 + n * 16 + l15;
      const float bv = bias[col];
#pragma unroll
      for (int m = 0; m < 4; m++) {
        const int row0 = m0 + wr * 64 + m * 16 + lg * 4;
#pragma unroll
        for (int r = 0; r < 4; r++) {
          float v = acc[m][n][r] + bv;
          v = v > 0.f ? v : 0.f;
          Y[(size_t)(row0 + r) * 1024 + col] = (bf16)(v * osc);
        }
      }
    }
  } else {
    bf16* Vt = (bf16*)Vto_;
#pragma unroll
    for (int n = 0; n < 4; n++) {
      const int col = n0 + wc * 64 + n * 16 + l15;
      const float bv = bias[col];
#pragma unroll
      for (int m = 0; m < 4; m++) {
        const int row0 = m0 + wr * 64 + m * 16 + lg * 4;
        const int bb2 = row0 >> 11;
        const int s2 = row0 & 2047;
        bf16x4 pk;
#pragma unroll
        for (int r = 0; r < 4; r++) {
          float v = acc[m][n][r] + bv;
          v = v > 0.f ? v : 0.f;
          pk[r] = (bf16)v;
        }
        *(bf16x4*)(Vt + ((size_t)bb2 * 1024 + col) * 2048 + s2) = pk;
      }
    }
  }
}

// ---------------- output projection GEMM (bf16 out) -----------------------
__global__ __launch_bounds__(256) void out_gemm(
    const short* A_, const short* Wt_, const float* __restrict__ bias,
    short* __restrict__ Y_) {
  __shared__ bf16 Alds[128][32];
  __shared__ bf16 Blds[128][32];
  const bf16* X = (const bf16*)A_;
  const bf16* Wt = (const bf16*)Wt_;
  bf16* Y = (bf16*)Y_;
  const int m0 = blockIdx.y * 128, n0 = blockIdx.x * 128;
  const int tid = threadIdx.x, wid = tid >> 6, lane = tid & 63;
  const int wr = wid >> 1, wc = wid & 1;
  const int l15 = lane & 15, lg = lane >> 4;
  const f32x4 vzero = {0.f, 0.f, 0.f, 0.f};
  f32x4 acc[4][4];
#pragma unroll
  for (int m = 0; m < 4; m++)
#pragma unroll
    for (int n = 0; n < 4; n++) acc[m][n] = vzero;

  const int sr = wid * 32 + (lane >> 2);
  const int scb = (lane & 3) * 16;

  for (int kt = 0; kt < 32; ++kt) {
    const char* ga = (const char*)(X + (size_t)(m0 + sr) * 1024 + kt * 32) + scb;
    async_cp16(ga, &Alds[wid * 32][0]);
    async_cp16(ga + 16 * 2048, &Alds[wid * 32 + 16][0]);
    const char* gb = (const char*)(Wt + (size_t)(n0 + sr) * 1024 + kt * 32) + scb;
    async_cp16(gb, &Blds[wid * 32][0]);
    async_cp16(gb + 16 * 2048, &Blds[wid * 32 + 16][0]);
    __syncthreads();
    bf16x8 a[4], bb[4];
#pragma unroll
    for (int m = 0; m < 4; m++) a[m] = *(const bf16x8*)&Alds[wr * 64 + m * 16 + l15][lg * 8];
#pragma unroll
    for (int n = 0; n < 4; n++) bb[n] = *(const bf16x8*)&Blds[wc * 64 + n * 16 + l15][lg * 8];
#pragma unroll
    for (int m = 0; m < 4; m++)
#pragma unroll
      for (int n = 0; n < 4; n++)
        acc[m][n] = __builtin_amdgcn_mfma_f32_16x16x32_bf16(a[m], bb[n], acc[m][n], 0, 0, 0);
    __syncthreads();
  }
#pragma unroll
  for (int n = 0; n < 4; n++) {
    const int col = n0 + wc * 64 + n * 16 + l15;
    const float bv = bias[col];
#pragma unroll
    for (int m = 0; m < 4; m++) {
      const int row0 = m0 + wr * 64 + m * 16 + lg * 4;
#pragma unroll
      for (int r = 0; r < 4; r++) {
        float v = acc[m][n][r] + bv;
        Y[(size_t)(row0 + r) * 1024 + col] = (bf16)(v > 0.f ? v : 0.f);
      }
    }
  }
}

// ------ key padding mask as bitmask: bit(row%32) of word[row/32] ----------
__global__ __launch_bounds__(256) void key_mask_kernel(const short* Kb_,
                                                       unsigned* __restrict__ kbits) {
  __shared__ unsigned bits[4];
  const bf16* Kb = (const bf16*)Kb_;
  const int wid = threadIdx.x >> 6, lane = threadIdx.x & 63;
  const int row0 = blockIdx.x * 32 + wid * 8;
  unsigned mybits = 0;
#pragma unroll
  for (int i = 0; i < 8; i++) {
    const bf16x8* p = (const bf16x8*)(Kb + (size_t)(row0 + i) * 1024);
    bf16x8 v0 = p[lane];
    bf16x8 v1 = p[64 + lane];
    float s = 0.f;
#pragma unroll
    for (int jj = 0; jj < 8; jj++) s += (float)v0[jj] + (float)v1[jj];
    for (int m = 32; m; m >>= 1) s += __shfl_xor(s, m);
    if (s != 0.f) mybits |= 1u << (wid * 8 + i);
  }
  if (lane == 0) bits[wid] = mybits;
  __syncthreads();
  if (threadIdx.x == 0) kbits[blockIdx.x] = bits[0] | bits[1] | bits[2] | bits[3];
}

// ---------------- causal flash attention, v8.1 (proven 66.6us) -------------
__device__ __forceinline__ bf16x8 lds_read_swz(const bf16* base, int row, int cbyte) {
  return *(const bf16x8*)((const char*)base + row * 128 + (cbyte ^ ((row & 7) << 4)));
}

__global__ __launch_bounds__(128) void attn_kernel(
    const short* Q_, const short* K_, const short* Vt_,
    const unsigned* __restrict__ kbits, short* O_) {
  __shared__ bf16 Klds[2][64][64];
  __shared__ bf16 Vlds[2][64][64];
  __shared__ bf16 Plds[2][16][64];
  const bf16* Q = (const bf16*)Q_;
  const bf16* K = (const bf16*)K_;
  const bf16* Vt = (const bf16*)Vt_;
  bf16* O = (bf16*)O_;

  // bijective XCD-grouping decode: all blocks of one (h,b) on one XCD
  const int f = blockIdx.x;
  const int xcd = f & 7, idx = f >> 3;
  const int qtb = idx & 31;
  const int hb = xcd + 8 * (idx >> 5);   // 0..31
  const int h = hb & 15, b = hb >> 4;

  const int tid = threadIdx.x, wid = tid >> 6, lane = tid & 63;
  const int l15 = lane & 15, lg = lane >> 4;
  const f32x4 vzero = {0.f, 0.f, 0.f, 0.f};
  bf16* const pbase = &Plds[wid][0][0];

  const int srow = lane >> 3;        // 0..7
  const int cb = (lane & 7) * 16;    // byte col in 128B row
  const int cbs = cb ^ ((srow & 7) << 4);  // pre-swizzled source col

  bf16x8 vones;
#pragma unroll
  for (int i = 0; i < 8; i++) vones[i] = (bf16)1.0f;

  for (int seg = 0; seg < 2; ++seg) {
    const int qt = (seg == 0) ? qtb : 63 - qtb;
    const int q0 = qt * 32;
    const int nkt = (32 * qt + 95) >> 6;

    const int qrow = q0 + wid * 16 + l15;
    const bf16* qp = Q + ((size_t)b * 2048 + qrow) * 1024 + h * 64;
    const bf16x8 qf0 = *(const bf16x8*)(qp + lg * 8);
    const bf16x8 qf1 = *(const bf16x8*)(qp + 32 + lg * 8);

    float Mrow[4];
    f32x4 oacc[4], oaccL;
#pragma unroll
    for (int r = 0; r < 4; r++) Mrow[r] = -INFINITY;
#pragma unroll
    for (int n = 0; n < 4; n++) oacc[n] = vzero;
    oaccL = vzero;
    float Mmin = -INFINITY;

    // running stage pointers (advance by one 64-key tile per STAGE call)
    const char* kn = (const char*)(K + ((size_t)b * 2048 + wid * 32 + srow) * 1024 + h * 64) + cbs;
    const char* vn = (const char*)(Vt + ((size_t)b * 1024 + h * 64 + wid * 32 + srow) * 2048) + cbs;

    auto STAGE = [&](int buf) {
#pragma unroll
      for (int c = 0; c < 4; c++) {
        async_cp16(kn + c * 16384, &Klds[buf][wid * 32 + c * 8][0]);
        async_cp16(vn + c * 32768, &Vlds[buf][wid * 32 + c * 8][0]);
      }
      kn += 131072;   // 64 K-rows * 2048 B
      vn += 128;      // 64 tokens * 2 B
    };

    STAGE(0);
    __syncthreads();
    int cur = 0;
    for (int kt = 0; kt < nkt; ++kt) {
      if (kt + 1 < nkt) STAGE(cur ^ 1);

      // ---- S = Q K^T ----
      f32x4 sacc[4];
#pragma unroll
      for (int n = 0; n < 4; n++) sacc[n] = vzero;
      {
        bf16x8 kf[4];
#pragma unroll
        for (int n = 0; n < 4; n++)
          kf[n] = lds_read_swz(&Klds[cur][0][0], n * 16 + l15, lg * 16);
        __builtin_amdgcn_s_setprio(1);
#pragma unroll
        for (int n = 0; n < 4; n++)
          sacc[n] = __builtin_amdgcn_mfma_f32_16x16x32_bf16(qf0, kf[n], sacc[n], 0, 0, 0);
        __builtin_amdgcn_s_setprio(0);
#pragma unroll
        for (int n = 0; n < 4; n++)
          kf[n] = lds_read_swz(&Klds[cur][0][0], n * 16 + l15, 64 + lg * 16);
        __builtin_amdgcn_s_setprio(1);
#pragma unroll
        for (int n = 0; n < 4; n++)
          sacc[n] = __builtin_amdgcn_mfma_f32_16x16x32_bf16(qf1, kf[n], sacc[n], 0, 0, 0);
        __builtin_amdgcn_s_setprio(0);
      }

      // ---- key-padding bitmask + causal: wave-uniform fast path ----
      const unsigned w0 = kbits[b * 64 + kt * 2];
      const unsigned w1 = kbits[b * 64 + kt * 2 + 1];
      const bool last = (kt == nkt - 1);
      if (last || ((w0 & w1) != 0xFFFFFFFFu)) {
        const int qrow0 = q0 + wid * 16 + lg * 4;
#pragma unroll
        for (int n = 0; n < 4; n++) {
          const unsigned wsel = (n < 2) ? w0 : w1;
          const bool on = (wsel >> ((n & 1) * 16 + l15)) & 1;
          const int kcol = kt * 64 + n * 16 + l15;
#pragma unroll
          for (int r = 0; r < 4; r++) {
            float sc = sacc[n][r];
            if (!on) sc = NEGV;
            if (last && kcol > qrow0 + r) sc = NEGV;
            sacc[n][r] = sc;
          }
        }
      }

      // ---- deferred-max gate: ONE dpp chain on the common path ----
      {
        float lm = sacc[0][0];
#pragma unroll
        for (int n = 0; n < 4; n++)
#pragma unroll
          for (int r = 0; r < 4; r++) lm = fmaxf(lm, sacc[n][r]);
        const float gmax = dpp_max16(lm);
        if (!__all(gmax <= Mmin + 8.f)) {
#pragma unroll
          for (int r = 0; r < 4; r++) {
            float tm = fmaxf(fmaxf(sacc[0][r], sacc[1][r]), fmaxf(sacc[2][r], sacc[3][r]));
            tm = dpp_max16(tm);
            const float Mn = fmaxf(Mrow[r], tm);
            const float sc = exp2f(Mrow[r] - Mn);
            Mrow[r] = Mn;
#pragma unroll
            for (int n = 0; n < 4; n++) oacc[n][r] *= sc;
            oaccL[r] *= sc;
          }
          Mmin = fminf(fminf(Mrow[0], Mrow[1]), fminf(Mrow[2], Mrow[3]));
        }
      }

      // ---- P = exp2(S - M) -> per-wave LDS ----
#pragma unroll
      for (int n = 0; n < 4; n++)
#pragma unroll
        for (int r = 0; r < 4; r++) {
          const float p = exp2f(sacc[n][r] - Mrow[r]);
          const int prow = lg * 4 + r;
          *(bf16*)((char*)pbase + prow * 128 +
                   (((n * 16 + l15) * 2) ^ ((prow & 7) << 4))) = (bf16)p;
        }

      // ---- O += P V ; L += P * 1 ----
#pragma unroll
      for (int ks = 0; ks < 2; ks++) {
        bf16x8 vf[4];
#pragma unroll
        for (int nd = 0; nd < 4; nd++)
          vf[nd] = lds_read_swz(&Vlds[cur][0][0], nd * 16 + l15, ks * 64 + lg * 16);
        const bf16x8 pf = lds_read_swz(pbase, l15, ks * 64 + lg * 16);
        __builtin_amdgcn_s_setprio(1);
#pragma unroll
        for (int nd = 0; nd < 4; nd++)
          oacc[nd] = __builtin_amdgcn_mfma_f32_16x16x32_bf16(pf, vf[nd], oacc[nd], 0, 0, 0);
        oaccL = __builtin_amdgcn_mfma_f32_16x16x32_bf16(pf, vones, oaccL, 0, 0, 0);
        __builtin_amdgcn_s_setprio(0);
      }

      __syncthreads();
      cur ^= 1;
    }

    // ---- epilogue: O /= L ----
    float inv[4];
#pragma unroll
    for (int r = 0; r < 4; r++) inv[r] = 1.0f / oaccL[r];
#pragma unroll
    for (int nd = 0; nd < 4; nd++) {
      const int col = h * 64 + nd * 16 + l15;
#pragma unroll
      for (int r = 0; r < 4; r++) {
        const float v = oacc[nd][r] * inv[r];
        O[((size_t)b * 2048 + q0 + wid * 16 + lg * 4 + r) * 1024 + col] = (bf16)v;
      }
    }
  }
}

// ---------------- residual + LayerNorm (unbiased std, eps on std) ---------
// proj is now bf16 (written by out_gemm).
__global__ __launch_bounds__(256) void ln_kernel(const float* __restrict__ qin,
                                                 const short* __restrict__ proj_,
                                                 float* __restrict__ out) {
  __shared__ float sbuf[4];
  const bf16* proj = (const bf16*)proj_;
  const int row = blockIdx.x, tid = threadIdx.x;
  const size_t base = (size_t)row * 1024 + tid * 4;
  const float4 a = *(const float4*)(qin + base);
  const bf16x4 pb = *(const bf16x4*)(proj + base);
  const float x0 = a.x + (float)pb[0], x1 = a.y + (float)pb[1];
  const float x2 = a.z + (float)pb[2], x3 = a.w + (float)pb[3];
  float s = x0 + x1 + x2 + x3;
  for (int m = 32; m; m >>= 1) s += __shfl_xor(s, m);
  if ((tid & 63) == 0) sbuf[tid >> 6] = s;
  __syncthreads();
  s = sbuf[0] + sbuf[1] + sbuf[2] + sbuf[3];
  const float mean = s * (1.f / 1024.f);
  const float d0 = x0 - mean, d1 = x1 - mean, d2 = x2 - mean, d3 = x3 - mean;
  float ss = d0 * d0 + d1 * d1 + d2 * d2 + d3 * d3;
  __syncthreads();
  for (int m = 32; m; m >>= 1) ss += __shfl_xor(ss, m);
  if ((tid & 63) == 0) sbuf[tid >> 6] = ss;
  __syncthreads();
  ss = sbuf[0] + sbuf[1] + sbuf[2] + sbuf[3];
  const float inv = 1.f / (sqrtf(ss * (1.f / 1023.f)) + 1e-8f);
  float4 o;
  o.x = d0 * inv; o.y = d1 * inv; o.z = d2 * inv; o.w = d3 * inv;
  *(float4*)(out + base) = o;
}

// ---------------- host orchestration --------------------------------------
extern "C" void kernel_launch(void* const* d_in, const int* in_sizes, int n_in,
                              void* d_out, int out_size, void* d_ws, size_t ws_size,
                              hipStream_t stream) {
  (void)in_sizes; (void)n_in; (void)out_size; (void)ws_size;
  const float* queries = (const float*)d_in[0];
  const float* keys    = (const float*)d_in[1];
  const float* values  = (const float*)d_in[2];
  const float* Wq = (const float*)d_in[3];  const float* bq = (const float*)d_in[4];
  const float* Wk = (const float*)d_in[5];  const float* bk = (const float*)d_in[6];
  const float* Wv = (const float*)d_in[7];  const float* bv = (const float*)d_in[8];
  const float* Wo = (const float*)d_in[9];  const float* bo = (const float*)d_in[10];
  float* out = (float*)d_out;

  char* w = (char*)d_ws;
  const size_t SZ_X = (size_t)4096 * 1024 * 2;   // 8 MB (bf16 [4096,1024])
  const size_t SZ_W = (size_t)1024 * 1024 * 2;   // 2 MB
  short* Wtq = (short*)w; w += SZ_W;
  short* Wtk = (short*)w; w += SZ_W;
  short* Wtv = (short*)w; w += SZ_W;
  short* Wto = (short*)w; w += SZ_W;
  short* Qb  = (short*)w; w += SZ_X;
  short* Kb  = (short*)w; w += SZ_X;
  short* Vtb = (short*)w; w += SZ_X;
  short* Ab  = (short*)w; w += SZ_X;
  short* proj = (short*)w; w += SZ_X;
  unsigned* kbits = (unsigned*)w; w += 4096;

  wt_kernel<<<dim3(16, 16, 4), 256, 0, stream>>>(Wq, Wk, Wv, Wo, Wtq, Wtk, Wtv, Wto);
  qkv_gemm<<<dim3(8, 32, 3), 256, 0, stream>>>(queries, keys, values,
                                               Wtq, Wtk, Wtv,
                                               bq, bk, bv, Qb, Kb, Vtb);
  key_mask_kernel<<<128, 256, 0, stream>>>(Kb, kbits);
  attn_kernel<<<1024, 128, 0, stream>>>(Qb, Kb, Vtb, kbits, Ab);
  out_gemm<<<dim3(8, 32), 256, 0, stream>>>(Ab, Wto, bo, proj);
  ln_kernel<<<4096, 256, 0, stream>>>(queries, proj, out);
}

// Round 14
// 165.104 us; speedup vs baseline: 1.0055x; 1.0055x over previous
//
#include <hip/hip_runtime.h>
#include <math.h>

typedef __bf16 bf16;
typedef __attribute__((ext_vector_type(8))) __bf16 bf16x8;
typedef __attribute__((ext_vector_type(4))) __bf16 bf16x4;
typedef __attribute__((ext_vector_type(4))) float f32x4;

typedef __attribute__((address_space(1))) unsigned int glb_u32;
typedef __attribute__((address_space(3))) unsigned int lds_u32;

#define NEGV (-4294967295.0f)
#define SCL2 0.18033688011112042f  /* 0.125 * log2(e), folded into Q */

__device__ __forceinline__ void async_cp16(const void* g, void* l) {
  __builtin_amdgcn_global_load_lds((glb_u32*)g, (lds_u32*)l, 16, 0, 0);
}

// ---- DPP 16-lane butterfly reduce (VALU pipe, not LDS) --------------------
template <int CTRL>
__device__ __forceinline__ float dppf(float x) {
  return __builtin_bit_cast(float,
      __builtin_amdgcn_mov_dpp(__builtin_bit_cast(int, x), CTRL, 0xF, 0xF, true));
}
__device__ __forceinline__ float dpp_max16(float x) {
  x = fmaxf(x, dppf<0xB1>(x));   // quad_perm xor1
  x = fmaxf(x, dppf<0x4E>(x));   // quad_perm xor2
  x = fmaxf(x, dppf<0x141>(x));  // row_half_mirror
  x = fmaxf(x, dppf<0x140>(x));  // row_mirror
  return x;
}

// ---------------- weight transpose + convert: T[n][k] = W[k][n] -----------
__global__ __launch_bounds__(256) void wt_kernel(
    const float* __restrict__ W0, const float* __restrict__ W1,
    const float* __restrict__ W2, const float* __restrict__ W3,
    short* T0, short* T1, short* T2, short* T3) {
  __shared__ float tile[64][65];
  const float* W = blockIdx.z == 0 ? W0 : (blockIdx.z == 1 ? W1 : (blockIdx.z == 2 ? W2 : W3));
  bf16* T = (bf16*)(blockIdx.z == 0 ? T0 : (blockIdx.z == 1 ? T1 : (blockIdx.z == 2 ? T2 : T3)));
  const int k0 = blockIdx.y * 64, n0 = blockIdx.x * 64;
  const int tid = threadIdx.x;
  const int c = tid & 63, rr = tid >> 6;
#pragma unroll
  for (int i = 0; i < 16; i++) {
    int r = i * 4 + rr;
    tile[r][c] = W[(size_t)(k0 + r) * 1024 + n0 + c];
  }
  __syncthreads();
#pragma unroll
  for (int i = 0; i < 16; i++) {
    int r = i * 4 + rr;
    T[(size_t)(n0 + r) * 1024 + k0 + c] = (bf16)tile[c][r];
  }
}

// ---------------- QKV projection GEMM: Y = relu(X @ W + b) ----------------
// fp32-A staged direct (no cvt kernel). 1D grid with XCD-group swizzle:
// the 8 n-blocks sharing one (m-tile, which) A-panel all land on ONE XCD,
// so the 512KB fp32 panel is fetched from HBM once and L2-served 7 times.
// B stage/read use the ((row>>1)&3)<<4 involution (64B rows): 8-way -> 2-way.
__global__ __launch_bounds__(256) void qkv_gemm(
    const float* __restrict__ Xq, const float* __restrict__ Xk,
    const float* __restrict__ Xv,
    const short* Wtq_, const short* Wtk_, const short* Wtv_,
    const float* __restrict__ bq_, const float* __restrict__ bk_, const float* __restrict__ bv_,
    short* Qo_, short* Ko_, short* Vto_) {
  __shared__ float Af[128][32];     // fp32 A tile, 128B rows, swizzled
  __shared__ bf16 Blds[128][32];    // B tile, 64B rows, swizzled
  // XCD-group decode: f = xcd + 8*(ggrp*8 + n), group g = xcd + 8*ggrp
  const int f = blockIdx.x;
  const int xcd = f & 7;
  const int s = f >> 3;              // 0..95
  const int g = xcd + 8 * (s >> 3);  // 0..95: (which, m-tile) group
  const int n0 = (s & 7) * 128;
  const int which = g >> 5;          // 0..2
  const int m0 = (g & 31) * 128;
  const float* X = which == 0 ? Xq : (which == 1 ? Xk : Xv);
  const bf16* Wt = (const bf16*)(which == 0 ? Wtq_ : (which == 1 ? Wtk_ : Wtv_));
  const float* bias = which == 0 ? bq_ : (which == 1 ? bk_ : bv_);
  const int tid = threadIdx.x, wid = tid >> 6, lane = tid & 63;
  const int wr = wid >> 1, wc = wid & 1;
  const int l15 = lane & 15, lg = lane >> 4;
  const f32x4 vzero = {0.f, 0.f, 0.f, 0.f};
  f32x4 acc[4][4];
#pragma unroll
  for (int m = 0; m < 4; m++)
#pragma unroll
    for (int n = 0; n < 4; n++) acc[m][n] = vzero;

  // A staging: 8 lanes per 128B row; one call = 8 rows; 4 calls/wave
  const int asrow = lane >> 3;                  // 0..7
  const int acbs = ((lane & 7) * 16) ^ ((asrow & 7) << 4);
  // B staging: 4 lanes per 64B row; one call = 16 rows; 2 calls/wave
  const int bsrow = lane >> 2;                  // 0..15
  const int bscb = ((lane & 3) * 16) ^ (((bsrow >> 1) & 3) << 4);

  for (int kt = 0; kt < 32; ++kt) {
#pragma unroll
    for (int c = 0; c < 4; c++) {
      const char* ga = (const char*)(X + (size_t)(m0 + wid * 32 + c * 8 + asrow) * 1024 + kt * 32) + acbs;
      async_cp16(ga, &Af[wid * 32 + c * 8][0]);
    }
#pragma unroll
    for (int c = 0; c < 2; c++) {
      const char* gb = (const char*)(Wt + (size_t)(n0 + wid * 32 + c * 16 + bsrow) * 1024 + kt * 32) + bscb;
      async_cp16(gb, &Blds[wid * 32 + c * 16][0]);
    }
    __syncthreads();
    bf16x8 a[4], bb[4];
#pragma unroll
    for (int m = 0; m < 4; m++) {
      const int row = wr * 64 + m * 16 + l15;
      const int swz = (row & 7) << 4;
      const char* ar = (const char*)&Af[0][0] + row * 128;
      const float4 f0 = *(const float4*)(ar + ((lg * 32) ^ swz));
      const float4 f1 = *(const float4*)(ar + ((lg * 32 + 16) ^ swz));
      a[m][0] = (bf16)f0.x; a[m][1] = (bf16)f0.y; a[m][2] = (bf16)f0.z; a[m][3] = (bf16)f0.w;
      a[m][4] = (bf16)f1.x; a[m][5] = (bf16)f1.y; a[m][6] = (bf16)f1.z; a[m][7] = (bf16)f1.w;
    }
#pragma unroll
    for (int n = 0; n < 4; n++) {
      const int row = wc * 64 + n * 16 + l15;
      bb[n] = *(const bf16x8*)((const char*)&Blds[0][0] + row * 64 +
                               ((lg * 16) ^ (((row >> 1) & 3) << 4)));
    }
#pragma unroll
    for (int m = 0; m < 4; m++)
#pragma unroll
      for (int n = 0; n < 4; n++)
        acc[m][n] = __builtin_amdgcn_mfma_f32_16x16x32_bf16(a[m], bb[n], acc[m][n], 0, 0, 0);
    __syncthreads();
  }

  if (which != 2) {
    bf16* Y = (bf16*)(which == 0 ? Qo_ : Ko_);
    const float osc = (which == 0) ? SCL2 : 1.0f;
#pragma unroll
    for (int n = 0; n < 4; n++) {
      const int col = n0 + wc * 64 + n * 16 + l15;
      const float bv = bias[col];
#pragma unroll
      for (int m = 0; m < 4; m++) {
        const int row0 = m0 + wr * 64 + m * 16 + lg * 4;
#pragma unroll
        for (int r = 0; r < 4; r++) {
          float v = acc[m][n][r] + bv;
          v = v > 0.f ? v : 0.f;
          Y[(size_t)(row0 + r) * 1024 + col] = (bf16)(v * osc);
        }
      }
    }
  } else {
    bf16* Vt = (bf16*)Vto_;
#pragma unroll
    for (int n = 0; n < 4; n++) {
      const int col = n0 + wc * 64 + n * 16 + l15;
      const float bv = bias[col];
#pragma unroll
      for (int m = 0; m < 4; m++) {
        const int row0 = m0 + wr * 64 + m * 16 + lg * 4;
        const int bb2 = row0 >> 11;
        const int s2 = row0 & 2047;
        bf16x4 pk;
#pragma unroll
        for (int r = 0; r < 4; r++) {
          float v = acc[m][n][r] + bv;
          v = v > 0.f ? v : 0.f;
          pk[r] = (bf16)v;
        }
        *(bf16x4*)(Vt + ((size_t)bb2 * 1024 + col) * 2048 + s2) = pk;
      }
    }
  }
}

// ---------------- output projection GEMM (bf16 out) -----------------------
__global__ __launch_bounds__(256) void out_gemm(
    const short* A_, const short* Wt_, const float* __restrict__ bias,
    short* __restrict__ Y_) {
  __shared__ bf16 Alds[128][32];
  __shared__ bf16 Blds[128][32];
  const bf16* X = (const bf16*)A_;
  const bf16* Wt = (const bf16*)Wt_;
  bf16* Y = (bf16*)Y_;
  const int m0 = blockIdx.y * 128, n0 = blockIdx.x * 128;
  const int tid = threadIdx.x, wid = tid >> 6, lane = tid & 63;
  const int wr = wid >> 1, wc = wid & 1;
  const int l15 = lane & 15, lg = lane >> 4;
  const f32x4 vzero = {0.f, 0.f, 0.f, 0.f};
  f32x4 acc[4][4];
#pragma unroll
  for (int m = 0; m < 4; m++)
#pragma unroll
    for (int n = 0; n < 4; n++) acc[m][n] = vzero;

  const int sr = wid * 32 + (lane >> 2);
  const int scb = (lane & 3) * 16;

  for (int kt = 0; kt < 32; ++kt) {
    const char* ga = (const char*)(X + (size_t)(m0 + sr) * 1024 + kt * 32) + scb;
    async_cp16(ga, &Alds[wid * 32][0]);
    async_cp16(ga + 16 * 2048, &Alds[wid * 32 + 16][0]);
    const char* gb = (const char*)(Wt + (size_t)(n0 + sr) * 1024 + kt * 32) + scb;
    async_cp16(gb, &Blds[wid * 32][0]);
    async_cp16(gb + 16 * 2048, &Blds[wid * 32 + 16][0]);
    __syncthreads();
    bf16x8 a[4], bb[4];
#pragma unroll
    for (int m = 0; m < 4; m++) a[m] = *(const bf16x8*)&Alds[wr * 64 + m * 16 + l15][lg * 8];
#pragma unroll
    for (int n = 0; n < 4; n++) bb[n] = *(const bf16x8*)&Blds[wc * 64 + n * 16 + l15][lg * 8];
#pragma unroll
    for (int m = 0; m < 4; m++)
#pragma unroll
      for (int n = 0; n < 4; n++)
        acc[m][n] = __builtin_amdgcn_mfma_f32_16x16x32_bf16(a[m], bb[n], acc[m][n], 0, 0, 0);
    __syncthreads();
  }
#pragma unroll
  for (int n = 0; n < 4; n++) {
    const int col = n0 + wc * 64 + n * 16 + l15;
    const float bv = bias[col];
#pragma unroll
    for (int m = 0; m < 4; m++) {
      const int row0 = m0 + wr * 64 + m * 16 + lg * 4;
#pragma unroll
      for (int r = 0; r < 4; r++) {
        float v = acc[m][n][r] + bv;
        Y[(size_t)(row0 + r) * 1024 + col] = (bf16)(v > 0.f ? v : 0.f);
      }
    }
  }
}

// ------ key padding mask as bitmask: bit(row%32) of word[row/32] ----------
__global__ __launch_bounds__(256) void key_mask_kernel(const short* Kb_,
                                                       unsigned* __restrict__ kbits) {
  __shared__ unsigned bits[4];
  const bf16* Kb = (const bf16*)Kb_;
  const int wid = threadIdx.x >> 6, lane = threadIdx.x & 63;
  const int row0 = blockIdx.x * 32 + wid * 8;
  unsigned mybits = 0;
#pragma unroll
  for (int i = 0; i < 8; i++) {
    const bf16x8* p = (const bf16x8*)(Kb + (size_t)(row0 + i) * 1024);
    bf16x8 v0 = p[lane];
    bf16x8 v1 = p[64 + lane];
    float s = 0.f;
#pragma unroll
    for (int jj = 0; jj < 8; jj++) s += (float)v0[jj] + (float)v1[jj];
    for (int m = 32; m; m >>= 1) s += __shfl_xor(s, m);
    if (s != 0.f) mybits |= 1u << (wid * 8 + i);
  }
  if (lane == 0) bits[wid] = mybits;
  __syncthreads();
  if (threadIdx.x == 0) kbits[blockIdx.x] = bits[0] | bits[1] | bits[2] | bits[3];
}

// ---------------- causal flash attention, v8.1 (proven 66.6us) -------------
__device__ __forceinline__ bf16x8 lds_read_swz(const bf16* base, int row, int cbyte) {
  return *(const bf16x8*)((const char*)base + row * 128 + (cbyte ^ ((row & 7) << 4)));
}

__global__ __launch_bounds__(128) void attn_kernel(
    const short* Q_, const short* K_, const short* Vt_,
    const unsigned* __restrict__ kbits, short* O_) {
  __shared__ bf16 Klds[2][64][64];
  __shared__ bf16 Vlds[2][64][64];
  __shared__ bf16 Plds[2][16][64];
  const bf16* Q = (const bf16*)Q_;
  const bf16* K = (const bf16*)K_;
  const bf16* Vt = (const bf16*)Vt_;
  bf16* O = (bf16*)O_;

  // bijective XCD-grouping decode: all blocks of one (h,b) on one XCD
  const int f = blockIdx.x;
  const int xcd = f & 7, idx = f >> 3;
  const int qtb = idx & 31;
  const int hb = xcd + 8 * (idx >> 5);   // 0..31
  const int h = hb & 15, b = hb >> 4;

  const int tid = threadIdx.x, wid = tid >> 6, lane = tid & 63;
  const int l15 = lane & 15, lg = lane >> 4;
  const f32x4 vzero = {0.f, 0.f, 0.f, 0.f};
  bf16* const pbase = &Plds[wid][0][0];

  const int srow = lane >> 3;        // 0..7
  const int cb = (lane & 7) * 16;    // byte col in 128B row
  const int cbs = cb ^ ((srow & 7) << 4);  // pre-swizzled source col

  bf16x8 vones;
#pragma unroll
  for (int i = 0; i < 8; i++) vones[i] = (bf16)1.0f;

  for (int seg = 0; seg < 2; ++seg) {
    const int qt = (seg == 0) ? qtb : 63 - qtb;
    const int q0 = qt * 32;
    const int nkt = (32 * qt + 95) >> 6;

    const int qrow = q0 + wid * 16 + l15;
    const bf16* qp = Q + ((size_t)b * 2048 + qrow) * 1024 + h * 64;
    const bf16x8 qf0 = *(const bf16x8*)(qp + lg * 8);
    const bf16x8 qf1 = *(const bf16x8*)(qp + 32 + lg * 8);

    float Mrow[4];
    f32x4 oacc[4], oaccL;
#pragma unroll
    for (int r = 0; r < 4; r++) Mrow[r] = -INFINITY;
#pragma unroll
    for (int n = 0; n < 4; n++) oacc[n] = vzero;
    oaccL = vzero;
    float Mmin = -INFINITY;

    // running stage pointers (advance by one 64-key tile per STAGE call)
    const char* kn = (const char*)(K + ((size_t)b * 2048 + wid * 32 + srow) * 1024 + h * 64) + cbs;
    const char* vn = (const char*)(Vt + ((size_t)b * 1024 + h * 64 + wid * 32 + srow) * 2048) + cbs;

    auto STAGE = [&](int buf) {
#pragma unroll
      for (int c = 0; c < 4; c++) {
        async_cp16(kn + c * 16384, &Klds[buf][wid * 32 + c * 8][0]);
        async_cp16(vn + c * 32768, &Vlds[buf][wid * 32 + c * 8][0]);
      }
      kn += 131072;   // 64 K-rows * 2048 B
      vn += 128;      // 64 tokens * 2 B
    };

    STAGE(0);
    __syncthreads();
    int cur = 0;
    for (int kt = 0; kt < nkt; ++kt) {
      if (kt + 1 < nkt) STAGE(cur ^ 1);

      // ---- S = Q K^T ----
      f32x4 sacc[4];
#pragma unroll
      for (int n = 0; n < 4; n++) sacc[n] = vzero;
      {
        bf16x8 kf[4];
#pragma unroll
        for (int n = 0; n < 4; n++)
          kf[n] = lds_read_swz(&Klds[cur][0][0], n * 16 + l15, lg * 16);
        __builtin_amdgcn_s_setprio(1);
#pragma unroll
        for (int n = 0; n < 4; n++)
          sacc[n] = __builtin_amdgcn_mfma_f32_16x16x32_bf16(qf0, kf[n], sacc[n], 0, 0, 0);
        __builtin_amdgcn_s_setprio(0);
#pragma unroll
        for (int n = 0; n < 4; n++)
          kf[n] = lds_read_swz(&Klds[cur][0][0], n * 16 + l15, 64 + lg * 16);
        __builtin_amdgcn_s_setprio(1);
#pragma unroll
        for (int n = 0; n < 4; n++)
          sacc[n] = __builtin_amdgcn_mfma_f32_16x16x32_bf16(qf1, kf[n], sacc[n], 0, 0, 0);
        __builtin_amdgcn_s_setprio(0);
      }

      // ---- key-padding bitmask + causal: wave-uniform fast path ----
      const unsigned w0 = kbits[b * 64 + kt * 2];
      const unsigned w1 = kbits[b * 64 + kt * 2 + 1];
      const bool last = (kt == nkt - 1);
      if (last || ((w0 & w1) != 0xFFFFFFFFu)) {
        const int qrow0 = q0 + wid * 16 + lg * 4;
#pragma unroll
        for (int n = 0; n < 4; n++) {
          const unsigned wsel = (n < 2) ? w0 : w1;
          const bool on = (wsel >> ((n & 1) * 16 + l15)) & 1;
          const int kcol = kt * 64 + n * 16 + l15;
#pragma unroll
          for (int r = 0; r < 4; r++) {
            float sc = sacc[n][r];
            if (!on) sc = NEGV;
            if (last && kcol > qrow0 + r) sc = NEGV;
            sacc[n][r] = sc;
          }
        }
      }

      // ---- deferred-max gate: ONE dpp chain on the common path ----
      {
        float lm = sacc[0][0];
#pragma unroll
        for (int n = 0; n < 4; n++)
#pragma unroll
          for (int r = 0; r < 4; r++) lm = fmaxf(lm, sacc[n][r]);
        const float gmax = dpp_max16(lm);
        if (!__all(gmax <= Mmin + 8.f)) {
#pragma unroll
          for (int r = 0; r < 4; r++) {
            float tm = fmaxf(fmaxf(sacc[0][r], sacc[1][r]), fmaxf(sacc[2][r], sacc[3][r]));
            tm = dpp_max16(tm);
            const float Mn = fmaxf(Mrow[r], tm);
            const float sc = exp2f(Mrow[r] - Mn);
            Mrow[r] = Mn;
#pragma unroll
            for (int n = 0; n < 4; n++) oacc[n][r] *= sc;
            oaccL[r] *= sc;
          }
          Mmin = fminf(fminf(Mrow[0], Mrow[1]), fminf(Mrow[2], Mrow[3]));
        }
      }

      // ---- P = exp2(S - M) -> per-wave LDS ----
#pragma unroll
      for (int n = 0; n < 4; n++)
#pragma unroll
        for (int r = 0; r < 4; r++) {
          const float p = exp2f(sacc[n][r] - Mrow[r]);
          const int prow = lg * 4 + r;
          *(bf16*)((char*)pbase + prow * 128 +
                   (((n * 16 + l15) * 2) ^ ((prow & 7) << 4))) = (bf16)p;
        }

      // ---- O += P V ; L += P * 1 ----
#pragma unroll
      for (int ks = 0; ks < 2; ks++) {
        bf16x8 vf[4];
#pragma unroll
        for (int nd = 0; nd < 4; nd++)
          vf[nd] = lds_read_swz(&Vlds[cur][0][0], nd * 16 + l15, ks * 64 + lg * 16);
        const bf16x8 pf = lds_read_swz(pbase, l15, ks * 64 + lg * 16);
        __builtin_amdgcn_s_setprio(1);
#pragma unroll
        for (int nd = 0; nd < 4; nd++)
          oacc[nd] = __builtin_amdgcn_mfma_f32_16x16x32_bf16(pf, vf[nd], oacc[nd], 0, 0, 0);
        oaccL = __builtin_amdgcn_mfma_f32_16x16x32_bf16(pf, vones, oaccL, 0, 0, 0);
        __builtin_amdgcn_s_setprio(0);
      }

      __syncthreads();
      cur ^= 1;
    }

    // ---- epilogue: O /= L ----
    float inv[4];
#pragma unroll
    for (int r = 0; r < 4; r++) inv[r] = 1.0f / oaccL[r];
#pragma unroll
    for (int nd = 0; nd < 4; nd++) {
      const int col = h * 64 + nd * 16 + l15;
#pragma unroll
      for (int r = 0; r < 4; r++) {
        const float v = oacc[nd][r] * inv[r];
        O[((size_t)b * 2048 + q0 + wid * 16 + lg * 4 + r) * 1024 + col] = (bf16)v;
      }
    }
  }
}

// ---------------- residual + LayerNorm (unbiased std, eps on std) ---------
// proj is bf16 (written by out_gemm).
__global__ __launch_bounds__(256) void ln_kernel(const float* __restrict__ qin,
                                                 const short* __restrict__ proj_,
                                                 float* __restrict__ out) {
  __shared__ float sbuf[4];
  const bf16* proj = (const bf16*)proj_;
  const int row = blockIdx.x, tid = threadIdx.x;
  const size_t base = (size_t)row * 1024 + tid * 4;
  const float4 a = *(const float4*)(qin + base);
  const bf16x4 pb = *(const bf16x4*)(proj + base);
  const float x0 = a.x + (float)pb[0], x1 = a.y + (float)pb[1];
  const float x2 = a.z + (float)pb[2], x3 = a.w + (float)pb[3];
  float s = x0 + x1 + x2 + x3;
  for (int m = 32; m; m >>= 1) s += __shfl_xor(s, m);
  if ((tid & 63) == 0) sbuf[tid >> 6] = s;
  __syncthreads();
  s = sbuf[0] + sbuf[1] + sbuf[2] + sbuf[3];
  const float mean = s * (1.f / 1024.f);
  const float d0 = x0 - mean, d1 = x1 - mean, d2 = x2 - mean, d3 = x3 - mean;
  float ss = d0 * d0 + d1 * d1 + d2 * d2 + d3 * d3;
  __syncthreads();
  for (int m = 32; m; m >>= 1) ss += __shfl_xor(ss, m);
  if ((tid & 63) == 0) sbuf[tid >> 6] = ss;
  __syncthreads();
  ss = sbuf[0] + sbuf[1] + sbuf[2] + sbuf[3];
  const float inv = 1.f / (sqrtf(ss * (1.f / 1023.f)) + 1e-8f);
  float4 o;
  o.x = d0 * inv; o.y = d1 * inv; o.z = d2 * inv; o.w = d3 * inv;
  *(float4*)(out + base) = o;
}

// ---------------- host orchestration --------------------------------------
extern "C" void kernel_launch(void* const* d_in, const int* in_sizes, int n_in,
                              void* d_out, int out_size, void* d_ws, size_t ws_size,
                              hipStream_t stream) {
  (void)in_sizes; (void)n_in; (void)out_size; (void)ws_size;
  const float* queries = (const float*)d_in[0];
  const float* keys    = (const float*)d_in[1];
  const float* values  = (const float*)d_in[2];
  const float* Wq = (const float*)d_in[3];  const float* bq = (const float*)d_in[4];
  const float* Wk = (const float*)d_in[5];  const float* bk = (const float*)d_in[6];
  const float* Wv = (const float*)d_in[7];  const float* bv = (const float*)d_in[8];
  const float* Wo = (const float*)d_in[9];  const float* bo = (const float*)d_in[10];
  float* out = (float*)d_out;

  char* w = (char*)d_ws;
  const size_t SZ_X = (size_t)4096 * 1024 * 2;   // 8 MB (bf16 [4096,1024])
  const size_t SZ_W = (size_t)1024 * 1024 * 2;   // 2 MB
  short* Wtq = (short*)w; w += SZ_W;
  short* Wtk = (short*)w; w += SZ_W;
  short* Wtv = (short*)w; w += SZ_W;
  short* Wto = (short*)w; w += SZ_W;
  short* Qb  = (short*)w; w += SZ_X;
  short* Kb  = (short*)w; w += SZ_X;
  short* Vtb = (short*)w; w += SZ_X;
  short* Ab  = (short*)w; w += SZ_X;
  short* proj = (short*)w; w += SZ_X;
  unsigned* kbits = (unsigned*)w; w += 4096;

  wt_kernel<<<dim3(16, 16, 4), 256, 0, stream>>>(Wq, Wk, Wv, Wo, Wtq, Wtk, Wtv, Wto);
  qkv_gemm<<<768, 256, 0, stream>>>(queries, keys, values,
                                    Wtq, Wtk, Wtv,
                                    bq, bk, bv, Qb, Kb, Vtb);
  key_mask_kernel<<<128, 256, 0, stream>>>(Kb, kbits);
  attn_kernel<<<1024, 128, 0, stream>>>(Qb, Kb, Vtb, kbits, Ab);
  out_gemm<<<dim3(8, 32), 256, 0, stream>>>(Ab, Wto, bo, proj);
  ln_kernel<<<4096, 256, 0, stream>>>(queries, proj, out);
}

// Round 15
// 149.104 us; speedup vs baseline: 1.1134x; 1.1073x over previous
//
#include <hip/hip_runtime.h>
#include <math.h>

typedef __bf16 bf16;
typedef __attribute__((ext_vector_type(8))) __bf16 bf16x8;
typedef __attribute__((ext_vector_type(4))) __bf16 bf16x4;
typedef __attribute__((ext_vector_type(4))) float f32x4;

typedef __attribute__((address_space(1))) unsigned int glb_u32;
typedef __attribute__((address_space(3))) unsigned int lds_u32;

#define NEGV (-4294967295.0f)
#define SCL2 0.18033688011112042f  /* 0.125 * log2(e), folded into Q */

__device__ __forceinline__ void async_cp16(const void* g, void* l) {
  __builtin_amdgcn_global_load_lds((glb_u32*)g, (lds_u32*)l, 16, 0, 0);
}

// ---- DPP 16-lane butterfly reduce (VALU pipe, not LDS) --------------------
template <int CTRL>
__device__ __forceinline__ float dppf(float x) {
  return __builtin_bit_cast(float,
      __builtin_amdgcn_mov_dpp(__builtin_bit_cast(int, x), CTRL, 0xF, 0xF, true));
}
__device__ __forceinline__ float dpp_max16(float x) {
  x = fmaxf(x, dppf<0xB1>(x));
  x = fmaxf(x, dppf<0x4E>(x));
  x = fmaxf(x, dppf<0x141>(x));
  x = fmaxf(x, dppf<0x140>(x));
  return x;
}

// ---------------- fp32 -> bf16 convert, all three inputs in one launch ----
__global__ __launch_bounds__(256) void cvt3_kernel(
    const float* __restrict__ q, const float* __restrict__ k,
    const float* __restrict__ v, short* xq, short* xk, short* xv) {
  const int bid = blockIdx.x;
  const int which = bid >> 12;           // 0..2
  const int i = (bid & 4095) * 256 + threadIdx.x;
  const float* src = which == 0 ? q : (which == 1 ? k : v);
  short* dst = which == 0 ? xq : (which == 1 ? xk : xv);
  float4 vv = ((const float4*)src)[i];
  bf16x4 o;
  o[0] = (bf16)vv.x; o[1] = (bf16)vv.y; o[2] = (bf16)vv.z; o[3] = (bf16)vv.w;
  ((bf16x4*)dst)[i] = o;
}

// ---------------- weight transpose + convert: T[n][k] = W[k][n] -----------
__global__ __launch_bounds__(256) void wt_kernel(
    const float* __restrict__ W0, const float* __restrict__ W1,
    const float* __restrict__ W2, const float* __restrict__ W3,
    short* T0, short* T1, short* T2, short* T3) {
  __shared__ float tile[64][65];
  const float* W = blockIdx.z == 0 ? W0 : (blockIdx.z == 1 ? W1 : (blockIdx.z == 2 ? W2 : W3));
  bf16* T = (bf16*)(blockIdx.z == 0 ? T0 : (blockIdx.z == 1 ? T1 : (blockIdx.z == 2 ? T2 : T3)));
  const int k0 = blockIdx.y * 64, n0 = blockIdx.x * 64;
  const int tid = threadIdx.x;
  const int c = tid & 63, rr = tid >> 6;
#pragma unroll
  for (int i = 0; i < 16; i++) {
    int r = i * 4 + rr;
    tile[r][c] = W[(size_t)(k0 + r) * 1024 + n0 + c];
  }
  __syncthreads();
#pragma unroll
  for (int i = 0; i < 16; i++) {
    int r = i * 4 + rr;
    T[(size_t)(n0 + r) * 1024 + k0 + c] = (bf16)tile[c][r];
  }
}

// ---- shared helpers: [128][32] bf16 tile, 64B rows, ((row>>1)&3)<<4 swz ---
__device__ __forceinline__ bf16x8 lds_read_swz64(const bf16* base, int row, int cbyte) {
  return *(const bf16x8*)((const char*)base + row * 64 + (cbyte ^ (((row >> 1) & 3) << 4)));
}

// ---------------- QKV projection GEMM: Y = relu(X @ W + b) ----------------
// bf16 A (from cvt3) + bf16 B; both tiles swizzled -> frag reads 2-way banks.
__global__ __launch_bounds__(256) void qkv_gemm(
    const short* Xq_, const short* Xk_, const short* Xv_,
    const short* Wtq_, const short* Wtk_, const short* Wtv_,
    const float* __restrict__ bq_, const float* __restrict__ bk_, const float* __restrict__ bv_,
    short* Qo_, short* Ko_, short* Vto_) {
  __shared__ bf16 Alds[128][32];
  __shared__ bf16 Blds[128][32];
  const int which = blockIdx.z;
  const bf16* X  = (const bf16*)(which == 0 ? Xq_  : (which == 1 ? Xk_  : Xv_));
  const bf16* Wt = (const bf16*)(which == 0 ? Wtq_ : (which == 1 ? Wtk_ : Wtv_));
  const float* bias = which == 0 ? bq_ : (which == 1 ? bk_ : bv_);
  const int m0 = blockIdx.y * 128, n0 = blockIdx.x * 128;
  const int tid = threadIdx.x, wid = tid >> 6, lane = tid & 63;
  const int wr = wid >> 1, wc = wid & 1;
  const int l15 = lane & 15, lg = lane >> 4;
  const f32x4 vzero = {0.f, 0.f, 0.f, 0.f};
  f32x4 acc[4][4];
#pragma unroll
  for (int m = 0; m < 4; m++)
#pragma unroll
    for (int n = 0; n < 4; n++) acc[m][n] = vzero;

  // staging: 4 lanes per 64B row; one call = 16 rows; 2 calls each
  const int srow = lane >> 2;                    // 0..15
  const int scbs = ((lane & 3) * 16) ^ (((srow >> 1) & 3) << 4);

  for (int kt = 0; kt < 32; ++kt) {
#pragma unroll
    for (int c = 0; c < 2; c++) {
      const char* ga = (const char*)(X + (size_t)(m0 + wid * 32 + c * 16 + srow) * 1024 + kt * 32) + scbs;
      async_cp16(ga, &Alds[wid * 32 + c * 16][0]);
      const char* gb = (const char*)(Wt + (size_t)(n0 + wid * 32 + c * 16 + srow) * 1024 + kt * 32) + scbs;
      async_cp16(gb, &Blds[wid * 32 + c * 16][0]);
    }
    __syncthreads();
    bf16x8 a[4], bb[4];
#pragma unroll
    for (int m = 0; m < 4; m++) a[m] = lds_read_swz64(&Alds[0][0], wr * 64 + m * 16 + l15, lg * 16);
#pragma unroll
    for (int n = 0; n < 4; n++) bb[n] = lds_read_swz64(&Blds[0][0], wc * 64 + n * 16 + l15, lg * 16);
#pragma unroll
    for (int m = 0; m < 4; m++)
#pragma unroll
      for (int n = 0; n < 4; n++)
        acc[m][n] = __builtin_amdgcn_mfma_f32_16x16x32_bf16(a[m], bb[n], acc[m][n], 0, 0, 0);
    __syncthreads();
  }

  if (which != 2) {
    bf16* Y = (bf16*)(which == 0 ? Qo_ : Ko_);
    const float osc = (which == 0) ? SCL2 : 1.0f;
#pragma unroll
    for (int n = 0; n < 4; n++) {
      const int col = n0 + wc * 64 + n * 16 + l15;
      const float bv = bias[col];
#pragma unroll
      for (int m = 0; m < 4; m++) {
        const int row0 = m0 + wr * 64 + m * 16 + lg * 4;
#pragma unroll
        for (int r = 0; r < 4; r++) {
          float v = acc[m][n][r] + bv;
          v = v > 0.f ? v : 0.f;
          Y[(size_t)(row0 + r) * 1024 + col] = (bf16)(v * osc);
        }
      }
    }
  } else {
    bf16* Vt = (bf16*)Vto_;
#pragma unroll
    for (int n = 0; n < 4; n++) {
      const int col = n0 + wc * 64 + n * 16 + l15;
      const float bv = bias[col];
#pragma unroll
      for (int m = 0; m < 4; m++) {
        const int row0 = m0 + wr * 64 + m * 16 + lg * 4;
        const int bb2 = row0 >> 11;
        const int s2 = row0 & 2047;
        bf16x4 pk;
#pragma unroll
        for (int r = 0; r < 4; r++) {
          float v = acc[m][n][r] + bv;
          v = v > 0.f ? v : 0.f;
          pk[r] = (bf16)v;
        }
        *(bf16x4*)(Vt + ((size_t)bb2 * 1024 + col) * 2048 + s2) = pk;
      }
    }
  }
}

// ---------------- output projection GEMM (bf16 out, swizzled tiles) -------
__global__ __launch_bounds__(256) void out_gemm(
    const short* A_, const short* Wt_, const float* __restrict__ bias,
    short* __restrict__ Y_) {
  __shared__ bf16 Alds[128][32];
  __shared__ bf16 Blds[128][32];
  const bf16* X = (const bf16*)A_;
  const bf16* Wt = (const bf16*)Wt_;
  bf16* Y = (bf16*)Y_;
  const int m0 = blockIdx.y * 128, n0 = blockIdx.x * 128;
  const int tid = threadIdx.x, wid = tid >> 6, lane = tid & 63;
  const int wr = wid >> 1, wc = wid & 1;
  const int l15 = lane & 15, lg = lane >> 4;
  const f32x4 vzero = {0.f, 0.f, 0.f, 0.f};
  f32x4 acc[4][4];
#pragma unroll
  for (int m = 0; m < 4; m++)
#pragma unroll
    for (int n = 0; n < 4; n++) acc[m][n] = vzero;

  const int srow = lane >> 2;
  const int scbs = ((lane & 3) * 16) ^ (((srow >> 1) & 3) << 4);

  for (int kt = 0; kt < 32; ++kt) {
#pragma unroll
    for (int c = 0; c < 2; c++) {
      const char* ga = (const char*)(X + (size_t)(m0 + wid * 32 + c * 16 + srow) * 1024 + kt * 32) + scbs;
      async_cp16(ga, &Alds[wid * 32 + c * 16][0]);
      const char* gb = (const char*)(Wt + (size_t)(n0 + wid * 32 + c * 16 + srow) * 1024 + kt * 32) + scbs;
      async_cp16(gb, &Blds[wid * 32 + c * 16][0]);
    }
    __syncthreads();
    bf16x8 a[4], bb[4];
#pragma unroll
    for (int m = 0; m < 4; m++) a[m] = lds_read_swz64(&Alds[0][0], wr * 64 + m * 16 + l15, lg * 16);
#pragma unroll
    for (int n = 0; n < 4; n++) bb[n] = lds_read_swz64(&Blds[0][0], wc * 64 + n * 16 + l15, lg * 16);
#pragma unroll
    for (int m = 0; m < 4; m++)
#pragma unroll
      for (int n = 0; n < 4; n++)
        acc[m][n] = __builtin_amdgcn_mfma_f32_16x16x32_bf16(a[m], bb[n], acc[m][n], 0, 0, 0);
    __syncthreads();
  }
#pragma unroll
  for (int n = 0; n < 4; n++) {
    const int col = n0 + wc * 64 + n * 16 + l15;
    const float bv = bias[col];
#pragma unroll
    for (int m = 0; m < 4; m++) {
      const int row0 = m0 + wr * 64 + m * 16 + lg * 4;
#pragma unroll
      for (int r = 0; r < 4; r++) {
        float v = acc[m][n][r] + bv;
        Y[(size_t)(row0 + r) * 1024 + col] = (bf16)(v > 0.f ? v : 0.f);
      }
    }
  }
}

// ------ key padding mask as bitmask: bit(row%32) of word[row/32] ----------
__global__ __launch_bounds__(256) void key_mask_kernel(const short* Kb_,
                                                       unsigned* __restrict__ kbits) {
  __shared__ unsigned bits[4];
  const bf16* Kb = (const bf16*)Kb_;
  const int wid = threadIdx.x >> 6, lane = threadIdx.x & 63;
  const int row0 = blockIdx.x * 32 + wid * 8;
  unsigned mybits = 0;
#pragma unroll
  for (int i = 0; i < 8; i++) {
    const bf16x8* p = (const bf16x8*)(Kb + (size_t)(row0 + i) * 1024);
    bf16x8 v0 = p[lane];
    bf16x8 v1 = p[64 + lane];
    float s = 0.f;
#pragma unroll
    for (int jj = 0; jj < 8; jj++) s += (float)v0[jj] + (float)v1[jj];
    for (int m = 32; m; m >>= 1) s += __shfl_xor(s, m);
    if (s != 0.f) mybits |= 1u << (wid * 8 + i);
  }
  if (lane == 0) bits[wid] = mybits;
  __syncthreads();
  if (threadIdx.x == 0) kbits[blockIdx.x] = bits[0] | bits[1] | bits[2] | bits[3];
}

// ---------------- causal flash attention, v8.1 (proven 66.6us) -------------
__device__ __forceinline__ bf16x8 lds_read_swz(const bf16* base, int row, int cbyte) {
  return *(const bf16x8*)((const char*)base + row * 128 + (cbyte ^ ((row & 7) << 4)));
}

__global__ __launch_bounds__(128) void attn_kernel(
    const short* Q_, const short* K_, const short* Vt_,
    const unsigned* __restrict__ kbits, short* O_) {
  __shared__ bf16 Klds[2][64][64];
  __shared__ bf16 Vlds[2][64][64];
  __shared__ bf16 Plds[2][16][64];
  const bf16* Q = (const bf16*)Q_;
  const bf16* K = (const bf16*)K_;
  const bf16* Vt = (const bf16*)Vt_;
  bf16* O = (bf16*)O_;

  const int f = blockIdx.x;
  const int xcd = f & 7, idx = f >> 3;
  const int qtb = idx & 31;
  const int hb = xcd + 8 * (idx >> 5);   // 0..31
  const int h = hb & 15, b = hb >> 4;

  const int tid = threadIdx.x, wid = tid >> 6, lane = tid & 63;
  const int l15 = lane & 15, lg = lane >> 4;
  const f32x4 vzero = {0.f, 0.f, 0.f, 0.f};
  bf16* const pbase = &Plds[wid][0][0];

  const int srow = lane >> 3;        // 0..7
  const int cb = (lane & 7) * 16;    // byte col in 128B row
  const int cbs = cb ^ ((srow & 7) << 4);

  bf16x8 vones;
#pragma unroll
  for (int i = 0; i < 8; i++) vones[i] = (bf16)1.0f;

  for (int seg = 0; seg < 2; ++seg) {
    const int qt = (seg == 0) ? qtb : 63 - qtb;
    const int q0 = qt * 32;
    const int nkt = (32 * qt + 95) >> 6;

    const int qrow = q0 + wid * 16 + l15;
    const bf16* qp = Q + ((size_t)b * 2048 + qrow) * 1024 + h * 64;
    const bf16x8 qf0 = *(const bf16x8*)(qp + lg * 8);
    const bf16x8 qf1 = *(const bf16x8*)(qp + 32 + lg * 8);

    float Mrow[4];
    f32x4 oacc[4], oaccL;
#pragma unroll
    for (int r = 0; r < 4; r++) Mrow[r] = -INFINITY;
#pragma unroll
    for (int n = 0; n < 4; n++) oacc[n] = vzero;
    oaccL = vzero;
    float Mmin = -INFINITY;

    const char* kn = (const char*)(K + ((size_t)b * 2048 + wid * 32 + srow) * 1024 + h * 64) + cbs;
    const char* vn = (const char*)(Vt + ((size_t)b * 1024 + h * 64 + wid * 32 + srow) * 2048) + cbs;

    auto STAGE = [&](int buf) {
#pragma unroll
      for (int c = 0; c < 4; c++) {
        async_cp16(kn + c * 16384, &Klds[buf][wid * 32 + c * 8][0]);
        async_cp16(vn + c * 32768, &Vlds[buf][wid * 32 + c * 8][0]);
      }
      kn += 131072;
      vn += 128;
    };

    STAGE(0);
    __syncthreads();
    int cur = 0;
    for (int kt = 0; kt < nkt; ++kt) {
      if (kt + 1 < nkt) STAGE(cur ^ 1);

      f32x4 sacc[4];
#pragma unroll
      for (int n = 0; n < 4; n++) sacc[n] = vzero;
      {
        bf16x8 kf[4];
#pragma unroll
        for (int n = 0; n < 4; n++)
          kf[n] = lds_read_swz(&Klds[cur][0][0], n * 16 + l15, lg * 16);
        __builtin_amdgcn_s_setprio(1);
#pragma unroll
        for (int n = 0; n < 4; n++)
          sacc[n] = __builtin_amdgcn_mfma_f32_16x16x32_bf16(qf0, kf[n], sacc[n], 0, 0, 0);
        __builtin_amdgcn_s_setprio(0);
#pragma unroll
        for (int n = 0; n < 4; n++)
          kf[n] = lds_read_swz(&Klds[cur][0][0], n * 16 + l15, 64 + lg * 16);
        __builtin_amdgcn_s_setprio(1);
#pragma unroll
        for (int n = 0; n < 4; n++)
          sacc[n] = __builtin_amdgcn_mfma_f32_16x16x32_bf16(qf1, kf[n], sacc[n], 0, 0, 0);
        __builtin_amdgcn_s_setprio(0);
      }

      const unsigned w0 = kbits[b * 64 + kt * 2];
      const unsigned w1 = kbits[b * 64 + kt * 2 + 1];
      const bool last = (kt == nkt - 1);
      if (last || ((w0 & w1) != 0xFFFFFFFFu)) {
        const int qrow0 = q0 + wid * 16 + lg * 4;
#pragma unroll
        for (int n = 0; n < 4; n++) {
          const unsigned wsel = (n < 2) ? w0 : w1;
          const bool on = (wsel >> ((n & 1) * 16 + l15)) & 1;
          const int kcol = kt * 64 + n * 16 + l15;
#pragma unroll
          for (int r = 0; r < 4; r++) {
            float sc = sacc[n][r];
            if (!on) sc = NEGV;
            if (last && kcol > qrow0 + r) sc = NEGV;
            sacc[n][r] = sc;
          }
        }
      }

      {
        float lm = sacc[0][0];
#pragma unroll
        for (int n = 0; n < 4; n++)
#pragma unroll
          for (int r = 0; r < 4; r++) lm = fmaxf(lm, sacc[n][r]);
        const float gmax = dpp_max16(lm);
        if (!__all(gmax <= Mmin + 8.f)) {
#pragma unroll
          for (int r = 0; r < 4; r++) {
            float tm = fmaxf(fmaxf(sacc[0][r], sacc[1][r]), fmaxf(sacc[2][r], sacc[3][r]));
            tm = dpp_max16(tm);
            const float Mn = fmaxf(Mrow[r], tm);
            const float sc = exp2f(Mrow[r] - Mn);
            Mrow[r] = Mn;
#pragma unroll
            for (int n = 0; n < 4; n++) oacc[n][r] *= sc;
            oaccL[r] *= sc;
          }
          Mmin = fminf(fminf(Mrow[0], Mrow[1]), fminf(Mrow[2], Mrow[3]));
        }
      }

#pragma unroll
      for (int n = 0; n < 4; n++)
#pragma unroll
        for (int r = 0; r < 4; r++) {
          const float p = exp2f(sacc[n][r] - Mrow[r]);
          const int prow = lg * 4 + r;
          *(bf16*)((char*)pbase + prow * 128 +
                   (((n * 16 + l15) * 2) ^ ((prow & 7) << 4))) = (bf16)p;
        }

#pragma unroll
      for (int ks = 0; ks < 2; ks++) {
        bf16x8 vf[4];
#pragma unroll
        for (int nd = 0; nd < 4; nd++)
          vf[nd] = lds_read_swz(&Vlds[cur][0][0], nd * 16 + l15, ks * 64 + lg * 16);
        const bf16x8 pf = lds_read_swz(pbase, l15, ks * 64 + lg * 16);
        __builtin_amdgcn_s_setprio(1);
#pragma unroll
        for (int nd = 0; nd < 4; nd++)
          oacc[nd] = __builtin_amdgcn_mfma_f32_16x16x32_bf16(pf, vf[nd], oacc[nd], 0, 0, 0);
        oaccL = __builtin_amdgcn_mfma_f32_16x16x32_bf16(pf, vones, oaccL, 0, 0, 0);
        __builtin_amdgcn_s_setprio(0);
      }

      __syncthreads();
      cur ^= 1;
    }

    float inv[4];
#pragma unroll
    for (int r = 0; r < 4; r++) inv[r] = 1.0f / oaccL[r];
#pragma unroll
    for (int nd = 0; nd < 4; nd++) {
      const int col = h * 64 + nd * 16 + l15;
#pragma unroll
      for (int r = 0; r < 4; r++) {
        const float v = oacc[nd][r] * inv[r];
        O[((size_t)b * 2048 + q0 + wid * 16 + lg * 4 + r) * 1024 + col] = (bf16)v;
      }
    }
  }
}

// ---------------- residual + LayerNorm (unbiased std, eps on std) ---------
__global__ __launch_bounds__(256) void ln_kernel(const float* __restrict__ qin,
                                                 const short* __restrict__ proj_,
                                                 float* __restrict__ out) {
  __shared__ float sbuf[4];
  const bf16* proj = (const bf16*)proj_;
  const int row = blockIdx.x, tid = threadIdx.x;
  const size_t base = (size_t)row * 1024 + tid * 4;
  const float4 a = *(const float4*)(qin + base);
  const bf16x4 pb = *(const bf16x4*)(proj + base);
  const float x0 = a.x + (float)pb[0], x1 = a.y + (float)pb[1];
  const float x2 = a.z + (float)pb[2], x3 = a.w + (float)pb[3];
  float s = x0 + x1 + x2 + x3;
  for (int m = 32; m; m >>= 1) s += __shfl_xor(s, m);
  if ((tid & 63) == 0) sbuf[tid >> 6] = s;
  __syncthreads();
  s = sbuf[0] + sbuf[1] + sbuf[2] + sbuf[3];
  const float mean = s * (1.f / 1024.f);
  const float d0 = x0 - mean, d1 = x1 - mean, d2 = x2 - mean, d3 = x3 - mean;
  float ss = d0 * d0 + d1 * d1 + d2 * d2 + d3 * d3;
  __syncthreads();
  for (int m = 32; m; m >>= 1) ss += __shfl_xor(ss, m);
  if ((tid & 63) == 0) sbuf[tid >> 6] = ss;
  __syncthreads();
  ss = sbuf[0] + sbuf[1] + sbuf[2] + sbuf[3];
  const float inv = 1.f / (sqrtf(ss * (1.f / 1023.f)) + 1e-8f);
  float4 o;
  o.x = d0 * inv; o.y = d1 * inv; o.z = d2 * inv; o.w = d3 * inv;
  *(float4*)(out + base) = o;
}

// ---------------- host orchestration --------------------------------------
extern "C" void kernel_launch(void* const* d_in, const int* in_sizes, int n_in,
                              void* d_out, int out_size, void* d_ws, size_t ws_size,
                              hipStream_t stream) {
  (void)in_sizes; (void)n_in; (void)out_size; (void)ws_size;
  const float* queries = (const float*)d_in[0];
  const float* keys    = (const float*)d_in[1];
  const float* values  = (const float*)d_in[2];
  const float* Wq = (const float*)d_in[3];  const float* bq = (const float*)d_in[4];
  const float* Wk = (const float*)d_in[5];  const float* bk = (const float*)d_in[6];
  const float* Wv = (const float*)d_in[7];  const float* bv = (const float*)d_in[8];
  const float* Wo = (const float*)d_in[9];  const float* bo = (const float*)d_in[10];
  float* out = (float*)d_out;

  char* w = (char*)d_ws;
  const size_t SZ_X = (size_t)4096 * 1024 * 2;   // 8 MB (bf16 [4096,1024])
  const size_t SZ_W = (size_t)1024 * 1024 * 2;   // 2 MB
  short* Xq  = (short*)w; w += SZ_X;
  short* Xk  = (short*)w; w += SZ_X;
  short* Xv  = (short*)w; w += SZ_X;
  short* Wtq = (short*)w; w += SZ_W;
  short* Wtk = (short*)w; w += SZ_W;
  short* Wtv = (short*)w; w += SZ_W;
  short* Wto = (short*)w; w += SZ_W;
  short* Qb  = (short*)w; w += SZ_X;
  short* Kb  = (short*)w; w += SZ_X;
  short* Vtb = (short*)w; w += SZ_X;
  short* Ab  = (short*)w; w += SZ_X;
  short* proj = (short*)w; w += SZ_X;
  unsigned* kbits = (unsigned*)w; w += 4096;

  cvt3_kernel<<<12288, 256, 0, stream>>>(queries, keys, values, Xq, Xk, Xv);
  wt_kernel<<<dim3(16, 16, 4), 256, 0, stream>>>(Wq, Wk, Wv, Wo, Wtq, Wtk, Wtv, Wto);
  qkv_gemm<<<dim3(8, 32, 3), 256, 0, stream>>>(Xq, Xk, Xv, Wtq, Wtk, Wtv,
                                               bq, bk, bv, Qb, Kb, Vtb);
  key_mask_kernel<<<128, 256, 0, stream>>>(Kb, kbits);
  attn_kernel<<<1024, 128, 0, stream>>>(Qb, Kb, Vtb, kbits, Ab);
  out_gemm<<<dim3(8, 32), 256, 0, stream>>>(Ab, Wto, bo, proj);
  ln_kernel<<<4096, 256, 0, stream>>>(queries, proj, out);
}

// Round 16
// 146.249 us; speedup vs baseline: 1.1351x; 1.0195x over previous
//
#include <hip/hip_runtime.h>
#include <math.h>

typedef __bf16 bf16;
typedef __attribute__((ext_vector_type(8))) __bf16 bf16x8;
typedef __attribute__((ext_vector_type(4))) __bf16 bf16x4;
typedef __attribute__((ext_vector_type(4))) float f32x4;

typedef __attribute__((address_space(1))) unsigned int glb_u32;
typedef __attribute__((address_space(3))) unsigned int lds_u32;

#define NEGV (-4294967295.0f)
#define SCL2 0.18033688011112042f  /* 0.125 * log2(e), folded into Q */

__device__ __forceinline__ void async_cp16(const void* g, void* l) {
  __builtin_amdgcn_global_load_lds((glb_u32*)g, (lds_u32*)l, 16, 0, 0);
}

// ---- DPP 16-lane butterfly reduce (VALU pipe, not LDS) --------------------
template <int CTRL>
__device__ __forceinline__ float dppf(float x) {
  return __builtin_bit_cast(float,
      __builtin_amdgcn_mov_dpp(__builtin_bit_cast(int, x), CTRL, 0xF, 0xF, true));
}
__device__ __forceinline__ float dpp_max16(float x) {
  x = fmaxf(x, dppf<0xB1>(x));
  x = fmaxf(x, dppf<0x4E>(x));
  x = fmaxf(x, dppf<0x141>(x));
  x = fmaxf(x, dppf<0x140>(x));
  return x;
}

// ---------------- fp32 -> bf16 convert, all three inputs in one launch ----
__global__ __launch_bounds__(256) void cvt3_kernel(
    const float* __restrict__ q, const float* __restrict__ k,
    const float* __restrict__ v, short* xq, short* xk, short* xv) {
  const int bid = blockIdx.x;
  const int which = bid >> 12;           // 0..2
  const int i = (bid & 4095) * 256 + threadIdx.x;
  const float* src = which == 0 ? q : (which == 1 ? k : v);
  short* dst = which == 0 ? xq : (which == 1 ? xk : xv);
  float4 vv = ((const float4*)src)[i];
  bf16x4 o;
  o[0] = (bf16)vv.x; o[1] = (bf16)vv.y; o[2] = (bf16)vv.z; o[3] = (bf16)vv.w;
  ((bf16x4*)dst)[i] = o;
}

// ---------------- weight transpose + convert: T[n][k] = W[k][n] -----------
__global__ __launch_bounds__(256) void wt_kernel(
    const float* __restrict__ W0, const float* __restrict__ W1,
    const float* __restrict__ W2, const float* __restrict__ W3,
    short* T0, short* T1, short* T2, short* T3) {
  __shared__ float tile[64][65];
  const float* W = blockIdx.z == 0 ? W0 : (blockIdx.z == 1 ? W1 : (blockIdx.z == 2 ? W2 : W3));
  bf16* T = (bf16*)(blockIdx.z == 0 ? T0 : (blockIdx.z == 1 ? T1 : (blockIdx.z == 2 ? T2 : T3)));
  const int k0 = blockIdx.y * 64, n0 = blockIdx.x * 64;
  const int tid = threadIdx.x;
  const int c = tid & 63, rr = tid >> 6;
#pragma unroll
  for (int i = 0; i < 16; i++) {
    int r = i * 4 + rr;
    tile[r][c] = W[(size_t)(k0 + r) * 1024 + n0 + c];
  }
  __syncthreads();
#pragma unroll
  for (int i = 0; i < 16; i++) {
    int r = i * 4 + rr;
    T[(size_t)(n0 + r) * 1024 + k0 + c] = (bf16)tile[c][r];
  }
}

// ---- shared helpers: bf16 tile, 64B rows, ((row>>1)&3)<<4 swz -------------
__device__ __forceinline__ bf16x8 lds_read_swz64(const bf16* base, int row, int cbyte) {
  return *(const bf16x8*)((const char*)base + row * 64 + (cbyte ^ (((row >> 1) & 3) << 4)));
}

// ---------------- QKV projection GEMM: Y = relu(X @ W + b) ----------------
__global__ __launch_bounds__(256) void qkv_gemm(
    const short* Xq_, const short* Xk_, const short* Xv_,
    const short* Wtq_, const short* Wtk_, const short* Wtv_,
    const float* __restrict__ bq_, const float* __restrict__ bk_, const float* __restrict__ bv_,
    short* Qo_, short* Ko_, short* Vto_) {
  __shared__ bf16 Alds[128][32];
  __shared__ bf16 Blds[128][32];
  const int which = blockIdx.z;
  const bf16* X  = (const bf16*)(which == 0 ? Xq_  : (which == 1 ? Xk_  : Xv_));
  const bf16* Wt = (const bf16*)(which == 0 ? Wtq_ : (which == 1 ? Wtk_ : Wtv_));
  const float* bias = which == 0 ? bq_ : (which == 1 ? bk_ : bv_);
  const int m0 = blockIdx.y * 128, n0 = blockIdx.x * 128;
  const int tid = threadIdx.x, wid = tid >> 6, lane = tid & 63;
  const int wr = wid >> 1, wc = wid & 1;
  const int l15 = lane & 15, lg = lane >> 4;
  const f32x4 vzero = {0.f, 0.f, 0.f, 0.f};
  f32x4 acc[4][4];
#pragma unroll
  for (int m = 0; m < 4; m++)
#pragma unroll
    for (int n = 0; n < 4; n++) acc[m][n] = vzero;

  const int srow = lane >> 2;                    // 0..15
  const int scbs = ((lane & 3) * 16) ^ (((srow >> 1) & 3) << 4);

  for (int kt = 0; kt < 32; ++kt) {
#pragma unroll
    for (int c = 0; c < 2; c++) {
      const char* ga = (const char*)(X + (size_t)(m0 + wid * 32 + c * 16 + srow) * 1024 + kt * 32) + scbs;
      async_cp16(ga, &Alds[wid * 32 + c * 16][0]);
      const char* gb = (const char*)(Wt + (size_t)(n0 + wid * 32 + c * 16 + srow) * 1024 + kt * 32) + scbs;
      async_cp16(gb, &Blds[wid * 32 + c * 16][0]);
    }
    __syncthreads();
    bf16x8 a[4], bb[4];
#pragma unroll
    for (int m = 0; m < 4; m++) a[m] = lds_read_swz64(&Alds[0][0], wr * 64 + m * 16 + l15, lg * 16);
#pragma unroll
    for (int n = 0; n < 4; n++) bb[n] = lds_read_swz64(&Blds[0][0], wc * 64 + n * 16 + l15, lg * 16);
#pragma unroll
    for (int m = 0; m < 4; m++)
#pragma unroll
      for (int n = 0; n < 4; n++)
        acc[m][n] = __builtin_amdgcn_mfma_f32_16x16x32_bf16(a[m], bb[n], acc[m][n], 0, 0, 0);
    __syncthreads();
  }

  if (which != 2) {
    bf16* Y = (bf16*)(which == 0 ? Qo_ : Ko_);
    const float osc = (which == 0) ? SCL2 : 1.0f;
#pragma unroll
    for (int n = 0; n < 4; n++) {
      const int col = n0 + wc * 64 + n * 16 + l15;
      const float bv = bias[col];
#pragma unroll
      for (int m = 0; m < 4; m++) {
        const int row0 = m0 + wr * 64 + m * 16 + lg * 4;
#pragma unroll
        for (int r = 0; r < 4; r++) {
          float v = acc[m][n][r] + bv;
          v = v > 0.f ? v : 0.f;
          Y[(size_t)(row0 + r) * 1024 + col] = (bf16)(v * osc);
        }
      }
    }
  } else {
    bf16* Vt = (bf16*)Vto_;
#pragma unroll
    for (int n = 0; n < 4; n++) {
      const int col = n0 + wc * 64 + n * 16 + l15;
      const float bv = bias[col];
#pragma unroll
      for (int m = 0; m < 4; m++) {
        const int row0 = m0 + wr * 64 + m * 16 + lg * 4;
        const int bb2 = row0 >> 11;
        const int s2 = row0 & 2047;
        bf16x4 pk;
#pragma unroll
        for (int r = 0; r < 4; r++) {
          float v = acc[m][n][r] + bv;
          v = v > 0.f ? v : 0.f;
          pk[r] = (bf16)v;
        }
        *(bf16x4*)(Vt + ((size_t)bb2 * 1024 + col) * 2048 + s2) = pk;
      }
    }
  }
}

// ------- output projection GEMM: 64x128 tiles, 512 blocks (2/CU) ----------
__global__ __launch_bounds__(256) void out_gemm(
    const short* A_, const short* Wt_, const float* __restrict__ bias,
    short* __restrict__ Y_) {
  __shared__ bf16 Alds[64][32];
  __shared__ bf16 Blds[128][32];
  const bf16* X = (const bf16*)A_;
  const bf16* Wt = (const bf16*)Wt_;
  bf16* Y = (bf16*)Y_;
  const int m0 = blockIdx.y * 64, n0 = blockIdx.x * 128;
  const int tid = threadIdx.x, wid = tid >> 6, lane = tid & 63;
  const int wr = wid >> 1, wc = wid & 1;   // wave tile: 32 rows x 64 cols
  const int l15 = lane & 15, lg = lane >> 4;
  const f32x4 vzero = {0.f, 0.f, 0.f, 0.f};
  f32x4 acc[2][4];
#pragma unroll
  for (int m = 0; m < 2; m++)
#pragma unroll
    for (int n = 0; n < 4; n++) acc[m][n] = vzero;

  const int srow = lane >> 2;                    // 0..15
  const int scbs = ((lane & 3) * 16) ^ (((srow >> 1) & 3) << 4);

  for (int kt = 0; kt < 32; ++kt) {
    // A: 64 rows, one 16-row call per wave
    {
      const char* ga = (const char*)(X + (size_t)(m0 + wid * 16 + srow) * 1024 + kt * 32) + scbs;
      async_cp16(ga, &Alds[wid * 16][0]);
    }
    // B: 128 rows, two 16-row calls per wave
#pragma unroll
    for (int c = 0; c < 2; c++) {
      const char* gb = (const char*)(Wt + (size_t)(n0 + wid * 32 + c * 16 + srow) * 1024 + kt * 32) + scbs;
      async_cp16(gb, &Blds[wid * 32 + c * 16][0]);
    }
    __syncthreads();
    bf16x8 a[2], bb[4];
#pragma unroll
    for (int m = 0; m < 2; m++) a[m] = lds_read_swz64(&Alds[0][0], wr * 32 + m * 16 + l15, lg * 16);
#pragma unroll
    for (int n = 0; n < 4; n++) bb[n] = lds_read_swz64(&Blds[0][0], wc * 64 + n * 16 + l15, lg * 16);
#pragma unroll
    for (int m = 0; m < 2; m++)
#pragma unroll
      for (int n = 0; n < 4; n++)
        acc[m][n] = __builtin_amdgcn_mfma_f32_16x16x32_bf16(a[m], bb[n], acc[m][n], 0, 0, 0);
    __syncthreads();
  }
#pragma unroll
  for (int n = 0; n < 4; n++) {
    const int col = n0 + wc * 64 + n * 16 + l15;
    const float bv = bias[col];
#pragma unroll
    for (int m = 0; m < 2; m++) {
      const int row0 = m0 + wr * 32 + m * 16 + lg * 4;
#pragma unroll
      for (int r = 0; r < 4; r++) {
        float v = acc[m][n][r] + bv;
        Y[(size_t)(row0 + r) * 1024 + col] = (bf16)(v > 0.f ? v : 0.f);
      }
    }
  }
}

// ------ key padding mask as bitmask: bit(row%32) of word[row/32] ----------
__global__ __launch_bounds__(256) void key_mask_kernel(const short* Kb_,
                                                       unsigned* __restrict__ kbits) {
  __shared__ unsigned bits[4];
  const bf16* Kb = (const bf16*)Kb_;
  const int wid = threadIdx.x >> 6, lane = threadIdx.x & 63;
  const int row0 = blockIdx.x * 32 + wid * 8;
  unsigned mybits = 0;
#pragma unroll
  for (int i = 0; i < 8; i++) {
    const bf16x8* p = (const bf16x8*)(Kb + (size_t)(row0 + i) * 1024);
    bf16x8 v0 = p[lane];
    bf16x8 v1 = p[64 + lane];
    float s = 0.f;
#pragma unroll
    for (int jj = 0; jj < 8; jj++) s += (float)v0[jj] + (float)v1[jj];
    for (int m = 32; m; m >>= 1) s += __shfl_xor(s, m);
    if (s != 0.f) mybits |= 1u << (wid * 8 + i);
  }
  if (lane == 0) bits[wid] = mybits;
  __syncthreads();
  if (threadIdx.x == 0) kbits[blockIdx.x] = bits[0] | bits[1] | bits[2] | bits[3];
}

// ---------------- causal flash attention, v8.1 (proven 66.6us) -------------
__device__ __forceinline__ bf16x8 lds_read_swz(const bf16* base, int row, int cbyte) {
  return *(const bf16x8*)((const char*)base + row * 128 + (cbyte ^ ((row & 7) << 4)));
}

__global__ __launch_bounds__(128) void attn_kernel(
    const short* Q_, const short* K_, const short* Vt_,
    const unsigned* __restrict__ kbits, short* O_) {
  __shared__ bf16 Klds[2][64][64];
  __shared__ bf16 Vlds[2][64][64];
  __shared__ bf16 Plds[2][16][64];
  const bf16* Q = (const bf16*)Q_;
  const bf16* K = (const bf16*)K_;
  const bf16* Vt = (const bf16*)Vt_;
  bf16* O = (bf16*)O_;

  const int f = blockIdx.x;
  const int xcd = f & 7, idx = f >> 3;
  const int qtb = idx & 31;
  const int hb = xcd + 8 * (idx >> 5);   // 0..31
  const int h = hb & 15, b = hb >> 4;

  const int tid = threadIdx.x, wid = tid >> 6, lane = tid & 63;
  const int l15 = lane & 15, lg = lane >> 4;
  const f32x4 vzero = {0.f, 0.f, 0.f, 0.f};
  bf16* const pbase = &Plds[wid][0][0];

  const int srow = lane >> 3;        // 0..7
  const int cb = (lane & 7) * 16;    // byte col in 128B row
  const int cbs = cb ^ ((srow & 7) << 4);

  bf16x8 vones;
#pragma unroll
  for (int i = 0; i < 8; i++) vones[i] = (bf16)1.0f;

  for (int seg = 0; seg < 2; ++seg) {
    const int qt = (seg == 0) ? qtb : 63 - qtb;
    const int q0 = qt * 32;
    const int nkt = (32 * qt + 95) >> 6;

    const int qrow = q0 + wid * 16 + l15;
    const bf16* qp = Q + ((size_t)b * 2048 + qrow) * 1024 + h * 64;
    const bf16x8 qf0 = *(const bf16x8*)(qp + lg * 8);
    const bf16x8 qf1 = *(const bf16x8*)(qp + 32 + lg * 8);

    float Mrow[4];
    f32x4 oacc[4], oaccL;
#pragma unroll
    for (int r = 0; r < 4; r++) Mrow[r] = -INFINITY;
#pragma unroll
    for (int n = 0; n < 4; n++) oacc[n] = vzero;
    oaccL = vzero;
    float Mmin = -INFINITY;

    const char* kn = (const char*)(K + ((size_t)b * 2048 + wid * 32 + srow) * 1024 + h * 64) + cbs;
    const char* vn = (const char*)(Vt + ((size_t)b * 1024 + h * 64 + wid * 32 + srow) * 2048) + cbs;

    auto STAGE = [&](int buf) {
#pragma unroll
      for (int c = 0; c < 4; c++) {
        async_cp16(kn + c * 16384, &Klds[buf][wid * 32 + c * 8][0]);
        async_cp16(vn + c * 32768, &Vlds[buf][wid * 32 + c * 8][0]);
      }
      kn += 131072;
      vn += 128;
    };

    STAGE(0);
    __syncthreads();
    int cur = 0;
    for (int kt = 0; kt < nkt; ++kt) {
      if (kt + 1 < nkt) STAGE(cur ^ 1);

      f32x4 sacc[4];
#pragma unroll
      for (int n = 0; n < 4; n++) sacc[n] = vzero;
      {
        bf16x8 kf[4];
#pragma unroll
        for (int n = 0; n < 4; n++)
          kf[n] = lds_read_swz(&Klds[cur][0][0], n * 16 + l15, lg * 16);
        __builtin_amdgcn_s_setprio(1);
#pragma unroll
        for (int n = 0; n < 4; n++)
          sacc[n] = __builtin_amdgcn_mfma_f32_16x16x32_bf16(qf0, kf[n], sacc[n], 0, 0, 0);
        __builtin_amdgcn_s_setprio(0);
#pragma unroll
        for (int n = 0; n < 4; n++)
          kf[n] = lds_read_swz(&Klds[cur][0][0], n * 16 + l15, 64 + lg * 16);
        __builtin_amdgcn_s_setprio(1);
#pragma unroll
        for (int n = 0; n < 4; n++)
          sacc[n] = __builtin_amdgcn_mfma_f32_16x16x32_bf16(qf1, kf[n], sacc[n], 0, 0, 0);
        __builtin_amdgcn_s_setprio(0);
      }

      const unsigned w0 = kbits[b * 64 + kt * 2];
      const unsigned w1 = kbits[b * 64 + kt * 2 + 1];
      const bool last = (kt == nkt - 1);
      if (last || ((w0 & w1) != 0xFFFFFFFFu)) {
        const int qrow0 = q0 + wid * 16 + lg * 4;
#pragma unroll
        for (int n = 0; n < 4; n++) {
          const unsigned wsel = (n < 2) ? w0 : w1;
          const bool on = (wsel >> ((n & 1) * 16 + l15)) & 1;
          const int kcol = kt * 64 + n * 16 + l15;
#pragma unroll
          for (int r = 0; r < 4; r++) {
            float sc = sacc[n][r];
            if (!on) sc = NEGV;
            if (last && kcol > qrow0 + r) sc = NEGV;
            sacc[n][r] = sc;
          }
        }
      }

      {
        float lm = sacc[0][0];
#pragma unroll
        for (int n = 0; n < 4; n++)
#pragma unroll
          for (int r = 0; r < 4; r++) lm = fmaxf(lm, sacc[n][r]);
        const float gmax = dpp_max16(lm);
        if (!__all(gmax <= Mmin + 8.f)) {
#pragma unroll
          for (int r = 0; r < 4; r++) {
            float tm = fmaxf(fmaxf(sacc[0][r], sacc[1][r]), fmaxf(sacc[2][r], sacc[3][r]));
            tm = dpp_max16(tm);
            const float Mn = fmaxf(Mrow[r], tm);
            const float sc = exp2f(Mrow[r] - Mn);
            Mrow[r] = Mn;
#pragma unroll
            for (int n = 0; n < 4; n++) oacc[n][r] *= sc;
            oaccL[r] *= sc;
          }
          Mmin = fminf(fminf(Mrow[0], Mrow[1]), fminf(Mrow[2], Mrow[3]));
        }
      }

#pragma unroll
      for (int n = 0; n < 4; n++)
#pragma unroll
        for (int r = 0; r < 4; r++) {
          const float p = exp2f(sacc[n][r] - Mrow[r]);
          const int prow = lg * 4 + r;
          *(bf16*)((char*)pbase + prow * 128 +
                   (((n * 16 + l15) * 2) ^ ((prow & 7) << 4))) = (bf16)p;
        }

#pragma unroll
      for (int ks = 0; ks < 2; ks++) {
        bf16x8 vf[4];
#pragma unroll
        for (int nd = 0; nd < 4; nd++)
          vf[nd] = lds_read_swz(&Vlds[cur][0][0], nd * 16 + l15, ks * 64 + lg * 16);
        const bf16x8 pf = lds_read_swz(pbase, l15, ks * 64 + lg * 16);
        __builtin_amdgcn_s_setprio(1);
#pragma unroll
        for (int nd = 0; nd < 4; nd++)
          oacc[nd] = __builtin_amdgcn_mfma_f32_16x16x32_bf16(pf, vf[nd], oacc[nd], 0, 0, 0);
        oaccL = __builtin_amdgcn_mfma_f32_16x16x32_bf16(pf, vones, oaccL, 0, 0, 0);
        __builtin_amdgcn_s_setprio(0);
      }

      __syncthreads();
      cur ^= 1;
    }

    float inv[4];
#pragma unroll
    for (int r = 0; r < 4; r++) inv[r] = 1.0f / oaccL[r];
#pragma unroll
    for (int nd = 0; nd < 4; nd++) {
      const int col = h * 64 + nd * 16 + l15;
#pragma unroll
      for (int r = 0; r < 4; r++) {
        const float v = oacc[nd][r] * inv[r];
        O[((size_t)b * 2048 + q0 + wid * 16 + lg * 4 + r) * 1024 + col] = (bf16)v;
      }
    }
  }
}

// ---------------- residual + LayerNorm (unbiased std, eps on std) ---------
__global__ __launch_bounds__(256) void ln_kernel(const float* __restrict__ qin,
                                                 const short* __restrict__ proj_,
                                                 float* __restrict__ out) {
  __shared__ float sbuf[4];
  const bf16* proj = (const bf16*)proj_;
  const int row = blockIdx.x, tid = threadIdx.x;
  const size_t base = (size_t)row * 1024 + tid * 4;
  const float4 a = *(const float4*)(qin + base);
  const bf16x4 pb = *(const bf16x4*)(proj + base);
  const float x0 = a.x + (float)pb[0], x1 = a.y + (float)pb[1];
  const float x2 = a.z + (float)pb[2], x3 = a.w + (float)pb[3];
  float s = x0 + x1 + x2 + x3;
  for (int m = 32; m; m >>= 1) s += __shfl_xor(s, m);
  if ((tid & 63) == 0) sbuf[tid >> 6] = s;
  __syncthreads();
  s = sbuf[0] + sbuf[1] + sbuf[2] + sbuf[3];
  const float mean = s * (1.f / 1024.f);
  const float d0 = x0 - mean, d1 = x1 - mean, d2 = x2 - mean, d3 = x3 - mean;
  float ss = d0 * d0 + d1 * d1 + d2 * d2 + d3 * d3;
  __syncthreads();
  for (int m = 32; m; m >>= 1) ss += __shfl_xor(ss, m);
  if ((tid & 63) == 0) sbuf[tid >> 6] = ss;
  __syncthreads();
  ss = sbuf[0] + sbuf[1] + sbuf[2] + sbuf[3];
  const float inv = 1.f / (sqrtf(ss * (1.f / 1023.f)) + 1e-8f);
  float4 o;
  o.x = d0 * inv; o.y = d1 * inv; o.z = d2 * inv; o.w = d3 * inv;
  *(float4*)(out + base) = o;
}

// ---------------- host orchestration --------------------------------------
extern "C" void kernel_launch(void* const* d_in, const int* in_sizes, int n_in,
                              void* d_out, int out_size, void* d_ws, size_t ws_size,
                              hipStream_t stream) {
  (void)in_sizes; (void)n_in; (void)out_size; (void)ws_size;
  const float* queries = (const float*)d_in[0];
  const float* keys    = (const float*)d_in[1];
  const float* values  = (const float*)d_in[2];
  const float* Wq = (const float*)d_in[3];  const float* bq = (const float*)d_in[4];
  const float* Wk = (const float*)d_in[5];  const float* bk = (const float*)d_in[6];
  const float* Wv = (const float*)d_in[7];  const float* bv = (const float*)d_in[8];
  const float* Wo = (const float*)d_in[9];  const float* bo = (const float*)d_in[10];
  float* out = (float*)d_out;

  char* w = (char*)d_ws;
  const size_t SZ_X = (size_t)4096 * 1024 * 2;   // 8 MB (bf16 [4096,1024])
  const size_t SZ_W = (size_t)1024 * 1024 * 2;   // 2 MB
  short* Xq  = (short*)w; w += SZ_X;
  short* Xk  = (short*)w; w += SZ_X;
  short* Xv  = (short*)w; w += SZ_X;
  short* Wtq = (short*)w; w += SZ_W;
  short* Wtk = (short*)w; w += SZ_W;
  short* Wtv = (short*)w; w += SZ_W;
  short* Wto = (short*)w; w += SZ_W;
  short* Qb  = (short*)w; w += SZ_X;
  short* Kb  = (short*)w; w += SZ_X;
  short* Vtb = (short*)w; w += SZ_X;
  short* Ab  = (short*)w; w += SZ_X;
  short* proj = (short*)w; w += SZ_X;
  unsigned* kbits = (unsigned*)w; w += 4096;

  cvt3_kernel<<<12288, 256, 0, stream>>>(queries, keys, values, Xq, Xk, Xv);
  wt_kernel<<<dim3(16, 16, 4), 256, 0, stream>>>(Wq, Wk, Wv, Wo, Wtq, Wtk, Wtv, Wto);
  qkv_gemm<<<dim3(8, 32, 3), 256, 0, stream>>>(Xq, Xk, Xv, Wtq, Wtk, Wtv,
                                               bq, bk, bv, Qb, Kb, Vtb);
  key_mask_kernel<<<128, 256, 0, stream>>>(Kb, kbits);
  attn_kernel<<<1024, 128, 0, stream>>>(Qb, Kb, Vtb, kbits, Ab);
  out_gemm<<<dim3(8, 64), 256, 0, stream>>>(Ab, Wto, bo, proj);
  ln_kernel<<<4096, 256, 0, stream>>>(queries, proj, out);
}

// Round 17
// 145.016 us; speedup vs baseline: 1.1448x; 1.0085x over previous
//
#include <hip/hip_runtime.h>
#include <math.h>

typedef __bf16 bf16;
typedef __attribute__((ext_vector_type(8))) __bf16 bf16x8;
typedef __attribute__((ext_vector_type(4))) __bf16 bf16x4;
typedef __attribute__((ext_vector_type(4))) float f32x4;

typedef __attribute__((address_space(1))) unsigned int glb_u32;
typedef __attribute__((address_space(3))) unsigned int lds_u32;

#define NEGV (-4294967295.0f)
#define SCL2 0.18033688011112042f  /* 0.125 * log2(e), folded into Q */

__device__ __forceinline__ void async_cp16(const void* g, void* l) {
  __builtin_amdgcn_global_load_lds((glb_u32*)g, (lds_u32*)l, 16, 0, 0);
}

// ---- DPP 16-lane butterfly reduce (VALU pipe, not LDS) --------------------
template <int CTRL>
__device__ __forceinline__ float dppf(float x) {
  return __builtin_bit_cast(float,
      __builtin_amdgcn_mov_dpp(__builtin_bit_cast(int, x), CTRL, 0xF, 0xF, true));
}
__device__ __forceinline__ float dpp_max16(float x) {
  x = fmaxf(x, dppf<0xB1>(x));
  x = fmaxf(x, dppf<0x4E>(x));
  x = fmaxf(x, dppf<0x141>(x));
  x = fmaxf(x, dppf<0x140>(x));
  return x;
}

// ---------------- fused prep: cvt3 (blocks 0..12287) + wt (12288..13311) ---
__global__ __launch_bounds__(256) void prep_kernel(
    const float* __restrict__ q, const float* __restrict__ k,
    const float* __restrict__ v, short* xq, short* xk, short* xv,
    const float* __restrict__ W0, const float* __restrict__ W1,
    const float* __restrict__ W2, const float* __restrict__ W3,
    short* T0, short* T1, short* T2, short* T3) {
  __shared__ float tile[64][65];
  const int bid = blockIdx.x;
  if (bid < 12288) {
    const int which = bid >> 12;           // 0..2
    const int i = (bid & 4095) * 256 + threadIdx.x;
    const float* src = which == 0 ? q : (which == 1 ? k : v);
    short* dst = which == 0 ? xq : (which == 1 ? xk : xv);
    float4 vv = ((const float4*)src)[i];
    bf16x4 o;
    o[0] = (bf16)vv.x; o[1] = (bf16)vv.y; o[2] = (bf16)vv.z; o[3] = (bf16)vv.w;
    ((bf16x4*)dst)[i] = o;
  } else {
    const int wb = bid - 12288;            // 0..1023
    const int z = wb >> 8;                 // 0..3
    const int k0 = ((wb >> 4) & 15) * 64, n0 = (wb & 15) * 64;
    const float* W = z == 0 ? W0 : (z == 1 ? W1 : (z == 2 ? W2 : W3));
    bf16* T = (bf16*)(z == 0 ? T0 : (z == 1 ? T1 : (z == 2 ? T2 : T3)));
    const int tid = threadIdx.x;
    const int c = tid & 63, rr = tid >> 6;
#pragma unroll
    for (int i = 0; i < 16; i++) {
      int r = i * 4 + rr;
      tile[r][c] = W[(size_t)(k0 + r) * 1024 + n0 + c];
    }
    __syncthreads();
#pragma unroll
    for (int i = 0; i < 16; i++) {
      int r = i * 4 + rr;
      T[(size_t)(n0 + r) * 1024 + k0 + c] = (bf16)tile[c][r];
    }
  }
}

// ---- shared helpers: bf16 tile, 64B rows, ((row>>1)&3)<<4 swz -------------
__device__ __forceinline__ bf16x8 lds_read_swz64(const bf16* base, int row, int cbyte) {
  return *(const bf16x8*)((const char*)base + row * 64 + (cbyte ^ (((row >> 1) & 3) << 4)));
}

// ---------------- QKV projection GEMM: Y = relu(X @ W + b) ----------------
__global__ __launch_bounds__(256) void qkv_gemm(
    const short* Xq_, const short* Xk_, const short* Xv_,
    const short* Wtq_, const short* Wtk_, const short* Wtv_,
    const float* __restrict__ bq_, const float* __restrict__ bk_, const float* __restrict__ bv_,
    short* Qo_, short* Ko_, short* Vto_) {
  __shared__ bf16 Alds[128][32];
  __shared__ bf16 Blds[128][32];
  const int which = blockIdx.z;
  const bf16* X  = (const bf16*)(which == 0 ? Xq_  : (which == 1 ? Xk_  : Xv_));
  const bf16* Wt = (const bf16*)(which == 0 ? Wtq_ : (which == 1 ? Wtk_ : Wtv_));
  const float* bias = which == 0 ? bq_ : (which == 1 ? bk_ : bv_);
  const int m0 = blockIdx.y * 128, n0 = blockIdx.x * 128;
  const int tid = threadIdx.x, wid = tid >> 6, lane = tid & 63;
  const int wr = wid >> 1, wc = wid & 1;
  const int l15 = lane & 15, lg = lane >> 4;
  const f32x4 vzero = {0.f, 0.f, 0.f, 0.f};
  f32x4 acc[4][4];
#pragma unroll
  for (int m = 0; m < 4; m++)
#pragma unroll
    for (int n = 0; n < 4; n++) acc[m][n] = vzero;

  const int srow = lane >> 2;                    // 0..15
  const int scbs = ((lane & 3) * 16) ^ (((srow >> 1) & 3) << 4);

  for (int kt = 0; kt < 32; ++kt) {
#pragma unroll
    for (int c = 0; c < 2; c++) {
      const char* ga = (const char*)(X + (size_t)(m0 + wid * 32 + c * 16 + srow) * 1024 + kt * 32) + scbs;
      async_cp16(ga, &Alds[wid * 32 + c * 16][0]);
      const char* gb = (const char*)(Wt + (size_t)(n0 + wid * 32 + c * 16 + srow) * 1024 + kt * 32) + scbs;
      async_cp16(gb, &Blds[wid * 32 + c * 16][0]);
    }
    __syncthreads();
    bf16x8 a[4], bb[4];
#pragma unroll
    for (int m = 0; m < 4; m++) a[m] = lds_read_swz64(&Alds[0][0], wr * 64 + m * 16 + l15, lg * 16);
#pragma unroll
    for (int n = 0; n < 4; n++) bb[n] = lds_read_swz64(&Blds[0][0], wc * 64 + n * 16 + l15, lg * 16);
#pragma unroll
    for (int m = 0; m < 4; m++)
#pragma unroll
      for (int n = 0; n < 4; n++)
        acc[m][n] = __builtin_amdgcn_mfma_f32_16x16x32_bf16(a[m], bb[n], acc[m][n], 0, 0, 0);
    __syncthreads();
  }

  if (which != 2) {
    bf16* Y = (bf16*)(which == 0 ? Qo_ : Ko_);
    const float osc = (which == 0) ? SCL2 : 1.0f;
#pragma unroll
    for (int n = 0; n < 4; n++) {
      const int col = n0 + wc * 64 + n * 16 + l15;
      const float bv = bias[col];
#pragma unroll
      for (int m = 0; m < 4; m++) {
        const int row0 = m0 + wr * 64 + m * 16 + lg * 4;
#pragma unroll
        for (int r = 0; r < 4; r++) {
          float v = acc[m][n][r] + bv;
          v = v > 0.f ? v : 0.f;
          Y[(size_t)(row0 + r) * 1024 + col] = (bf16)(v * osc);
        }
      }
    }
  } else {
    bf16* Vt = (bf16*)Vto_;
#pragma unroll
    for (int n = 0; n < 4; n++) {
      const int col = n0 + wc * 64 + n * 16 + l15;
      const float bv = bias[col];
#pragma unroll
      for (int m = 0; m < 4; m++) {
        const int row0 = m0 + wr * 64 + m * 16 + lg * 4;
        const int bb2 = row0 >> 11;
        const int s2 = row0 & 2047;
        bf16x4 pk;
#pragma unroll
        for (int r = 0; r < 4; r++) {
          float v = acc[m][n][r] + bv;
          v = v > 0.f ? v : 0.f;
          pk[r] = (bf16)v;
        }
        *(bf16x4*)(Vt + ((size_t)bb2 * 1024 + col) * 2048 + s2) = pk;
      }
    }
  }
}

// ------- output projection GEMM: 64x128 tiles, 512 blocks (2/CU) ----------
__global__ __launch_bounds__(256) void out_gemm(
    const short* A_, const short* Wt_, const float* __restrict__ bias,
    short* __restrict__ Y_) {
  __shared__ bf16 Alds[64][32];
  __shared__ bf16 Blds[128][32];
  const bf16* X = (const bf16*)A_;
  const bf16* Wt = (const bf16*)Wt_;
  bf16* Y = (bf16*)Y_;
  const int m0 = blockIdx.y * 64, n0 = blockIdx.x * 128;
  const int tid = threadIdx.x, wid = tid >> 6, lane = tid & 63;
  const int wr = wid >> 1, wc = wid & 1;
  const int l15 = lane & 15, lg = lane >> 4;
  const f32x4 vzero = {0.f, 0.f, 0.f, 0.f};
  f32x4 acc[2][4];
#pragma unroll
  for (int m = 0; m < 2; m++)
#pragma unroll
    for (int n = 0; n < 4; n++) acc[m][n] = vzero;

  const int srow = lane >> 2;
  const int scbs = ((lane & 3) * 16) ^ (((srow >> 1) & 3) << 4);

  for (int kt = 0; kt < 32; ++kt) {
    {
      const char* ga = (const char*)(X + (size_t)(m0 + wid * 16 + srow) * 1024 + kt * 32) + scbs;
      async_cp16(ga, &Alds[wid * 16][0]);
    }
#pragma unroll
    for (int c = 0; c < 2; c++) {
      const char* gb = (const char*)(Wt + (size_t)(n0 + wid * 32 + c * 16 + srow) * 1024 + kt * 32) + scbs;
      async_cp16(gb, &Blds[wid * 32 + c * 16][0]);
    }
    __syncthreads();
    bf16x8 a[2], bb[4];
#pragma unroll
    for (int m = 0; m < 2; m++) a[m] = lds_read_swz64(&Alds[0][0], wr * 32 + m * 16 + l15, lg * 16);
#pragma unroll
    for (int n = 0; n < 4; n++) bb[n] = lds_read_swz64(&Blds[0][0], wc * 64 + n * 16 + l15, lg * 16);
#pragma unroll
    for (int m = 0; m < 2; m++)
#pragma unroll
      for (int n = 0; n < 4; n++)
        acc[m][n] = __builtin_amdgcn_mfma_f32_16x16x32_bf16(a[m], bb[n], acc[m][n], 0, 0, 0);
    __syncthreads();
  }
#pragma unroll
  for (int n = 0; n < 4; n++) {
    const int col = n0 + wc * 64 + n * 16 + l15;
    const float bv = bias[col];
#pragma unroll
    for (int m = 0; m < 2; m++) {
      const int row0 = m0 + wr * 32 + m * 16 + lg * 4;
#pragma unroll
      for (int r = 0; r < 4; r++) {
        float v = acc[m][n][r] + bv;
        Y[(size_t)(row0 + r) * 1024 + col] = (bf16)(v > 0.f ? v : 0.f);
      }
    }
  }
}

// ------ key padding mask as bitmask: bit(row%32) of word[row/32] ----------
__global__ __launch_bounds__(256) void key_mask_kernel(const short* Kb_,
                                                       unsigned* __restrict__ kbits) {
  __shared__ unsigned bits[4];
  const bf16* Kb = (const bf16*)Kb_;
  const int wid = threadIdx.x >> 6, lane = threadIdx.x & 63;
  const int row0 = blockIdx.x * 32 + wid * 8;
  unsigned mybits = 0;
#pragma unroll
  for (int i = 0; i < 8; i++) {
    const bf16x8* p = (const bf16x8*)(Kb + (size_t)(row0 + i) * 1024);
    bf16x8 v0 = p[lane];
    bf16x8 v1 = p[64 + lane];
    float s = 0.f;
#pragma unroll
    for (int jj = 0; jj < 8; jj++) s += (float)v0[jj] + (float)v1[jj];
    for (int m = 32; m; m >>= 1) s += __shfl_xor(s, m);
    if (s != 0.f) mybits |= 1u << (wid * 8 + i);
  }
  if (lane == 0) bits[wid] = mybits;
  __syncthreads();
  if (threadIdx.x == 0) kbits[blockIdx.x] = bits[0] | bits[1] | bits[2] | bits[3];
}

// ---------------- causal flash attention, v8.1 (proven 66.6us) -------------
__device__ __forceinline__ bf16x8 lds_read_swz(const bf16* base, int row, int cbyte) {
  return *(const bf16x8*)((const char*)base + row * 128 + (cbyte ^ ((row & 7) << 4)));
}

__global__ __launch_bounds__(128) void attn_kernel(
    const short* Q_, const short* K_, const short* Vt_,
    const unsigned* __restrict__ kbits, short* O_) {
  __shared__ bf16 Klds[2][64][64];
  __shared__ bf16 Vlds[2][64][64];
  __shared__ bf16 Plds[2][16][64];
  const bf16* Q = (const bf16*)Q_;
  const bf16* K = (const bf16*)K_;
  const bf16* Vt = (const bf16*)Vt_;
  bf16* O = (bf16*)O_;

  const int f = blockIdx.x;
  const int xcd = f & 7, idx = f >> 3;
  const int qtb = idx & 31;
  const int hb = xcd + 8 * (idx >> 5);   // 0..31
  const int h = hb & 15, b = hb >> 4;

  const int tid = threadIdx.x, wid = tid >> 6, lane = tid & 63;
  const int l15 = lane & 15, lg = lane >> 4;
  const f32x4 vzero = {0.f, 0.f, 0.f, 0.f};
  bf16* const pbase = &Plds[wid][0][0];

  const int srow = lane >> 3;        // 0..7
  const int cb = (lane & 7) * 16;    // byte col in 128B row
  const int cbs = cb ^ ((srow & 7) << 4);

  bf16x8 vones;
#pragma unroll
  for (int i = 0; i < 8; i++) vones[i] = (bf16)1.0f;

  for (int seg = 0; seg < 2; ++seg) {
    const int qt = (seg == 0) ? qtb : 63 - qtb;
    const int q0 = qt * 32;
    const int nkt = (32 * qt + 95) >> 6;

    const int qrow = q0 + wid * 16 + l15;
    const bf16* qp = Q + ((size_t)b * 2048 + qrow) * 1024 + h * 64;
    const bf16x8 qf0 = *(const bf16x8*)(qp + lg * 8);
    const bf16x8 qf1 = *(const bf16x8*)(qp + 32 + lg * 8);

    float Mrow[4];
    f32x4 oacc[4], oaccL;
#pragma unroll
    for (int r = 0; r < 4; r++) Mrow[r] = -INFINITY;
#pragma unroll
    for (int n = 0; n < 4; n++) oacc[n] = vzero;
    oaccL = vzero;
    float Mmin = -INFINITY;

    const char* kn = (const char*)(K + ((size_t)b * 2048 + wid * 32 + srow) * 1024 + h * 64) + cbs;
    const char* vn = (const char*)(Vt + ((size_t)b * 1024 + h * 64 + wid * 32 + srow) * 2048) + cbs;

    auto STAGE = [&](int buf) {
#pragma unroll
      for (int c = 0; c < 4; c++) {
        async_cp16(kn + c * 16384, &Klds[buf][wid * 32 + c * 8][0]);
        async_cp16(vn + c * 32768, &Vlds[buf][wid * 32 + c * 8][0]);
      }
      kn += 131072;
      vn += 128;
    };

    STAGE(0);
    __syncthreads();
    int cur = 0;
    for (int kt = 0; kt < nkt; ++kt) {
      if (kt + 1 < nkt) STAGE(cur ^ 1);

      f32x4 sacc[4];
#pragma unroll
      for (int n = 0; n < 4; n++) sacc[n] = vzero;
      {
        bf16x8 kf[4];
#pragma unroll
        for (int n = 0; n < 4; n++)
          kf[n] = lds_read_swz(&Klds[cur][0][0], n * 16 + l15, lg * 16);
        __builtin_amdgcn_s_setprio(1);
#pragma unroll
        for (int n = 0; n < 4; n++)
          sacc[n] = __builtin_amdgcn_mfma_f32_16x16x32_bf16(qf0, kf[n], sacc[n], 0, 0, 0);
        __builtin_amdgcn_s_setprio(0);
#pragma unroll
        for (int n = 0; n < 4; n++)
          kf[n] = lds_read_swz(&Klds[cur][0][0], n * 16 + l15, 64 + lg * 16);
        __builtin_amdgcn_s_setprio(1);
#pragma unroll
        for (int n = 0; n < 4; n++)
          sacc[n] = __builtin_amdgcn_mfma_f32_16x16x32_bf16(qf1, kf[n], sacc[n], 0, 0, 0);
        __builtin_amdgcn_s_setprio(0);
      }

      const unsigned w0 = kbits[b * 64 + kt * 2];
      const unsigned w1 = kbits[b * 64 + kt * 2 + 1];
      const bool last = (kt == nkt - 1);
      if (last || ((w0 & w1) != 0xFFFFFFFFu)) {
        const int qrow0 = q0 + wid * 16 + lg * 4;
#pragma unroll
        for (int n = 0; n < 4; n++) {
          const unsigned wsel = (n < 2) ? w0 : w1;
          const bool on = (wsel >> ((n & 1) * 16 + l15)) & 1;
          const int kcol = kt * 64 + n * 16 + l15;
#pragma unroll
          for (int r = 0; r < 4; r++) {
            float sc = sacc[n][r];
            if (!on) sc = NEGV;
            if (last && kcol > qrow0 + r) sc = NEGV;
            sacc[n][r] = sc;
          }
        }
      }

      {
        float lm = sacc[0][0];
#pragma unroll
        for (int n = 0; n < 4; n++)
#pragma unroll
          for (int r = 0; r < 4; r++) lm = fmaxf(lm, sacc[n][r]);
        const float gmax = dpp_max16(lm);
        if (!__all(gmax <= Mmin + 8.f)) {
#pragma unroll
          for (int r = 0; r < 4; r++) {
            float tm = fmaxf(fmaxf(sacc[0][r], sacc[1][r]), fmaxf(sacc[2][r], sacc[3][r]));
            tm = dpp_max16(tm);
            const float Mn = fmaxf(Mrow[r], tm);
            const float sc = exp2f(Mrow[r] - Mn);
            Mrow[r] = Mn;
#pragma unroll
            for (int n = 0; n < 4; n++) oacc[n][r] *= sc;
            oaccL[r] *= sc;
          }
          Mmin = fminf(fminf(Mrow[0], Mrow[1]), fminf(Mrow[2], Mrow[3]));
        }
      }

#pragma unroll
      for (int n = 0; n < 4; n++)
#pragma unroll
        for (int r = 0; r < 4; r++) {
          const float p = exp2f(sacc[n][r] - Mrow[r]);
          const int prow = lg * 4 + r;
          *(bf16*)((char*)pbase + prow * 128 +
                   (((n * 16 + l15) * 2) ^ ((prow & 7) << 4))) = (bf16)p;
        }

#pragma unroll
      for (int ks = 0; ks < 2; ks++) {
        bf16x8 vf[4];
#pragma unroll
        for (int nd = 0; nd < 4; nd++)
          vf[nd] = lds_read_swz(&Vlds[cur][0][0], nd * 16 + l15, ks * 64 + lg * 16);
        const bf16x8 pf = lds_read_swz(pbase, l15, ks * 64 + lg * 16);
        __builtin_amdgcn_s_setprio(1);
#pragma unroll
        for (int nd = 0; nd < 4; nd++)
          oacc[nd] = __builtin_amdgcn_mfma_f32_16x16x32_bf16(pf, vf[nd], oacc[nd], 0, 0, 0);
        oaccL = __builtin_amdgcn_mfma_f32_16x16x32_bf16(pf, vones, oaccL, 0, 0, 0);
        __builtin_amdgcn_s_setprio(0);
      }

      __syncthreads();
      cur ^= 1;
    }

    float inv[4];
#pragma unroll
    for (int r = 0; r < 4; r++) inv[r] = 1.0f / oaccL[r];
#pragma unroll
    for (int nd = 0; nd < 4; nd++) {
      const int col = h * 64 + nd * 16 + l15;
#pragma unroll
      for (int r = 0; r < 4; r++) {
        const float v = oacc[nd][r] * inv[r];
        O[((size_t)b * 2048 + q0 + wid * 16 + lg * 4 + r) * 1024 + col] = (bf16)v;
      }
    }
  }
}

// -------- residual + LayerNorm: wave-per-row, no barriers/LDS -------------
__global__ __launch_bounds__(256) void ln_kernel(const float* __restrict__ qin,
                                                 const short* __restrict__ proj_,
                                                 float* __restrict__ out) {
  const bf16* proj = (const bf16*)proj_;
  const int row = blockIdx.x * 4 + (threadIdx.x >> 6);
  const int lane = threadIdx.x & 63;
  const size_t rbase = (size_t)row * 1024;

  float x[16];
  float s = 0.f;
#pragma unroll
  for (int c = 0; c < 4; c++) {
    const size_t off = rbase + c * 256 + lane * 4;
    const float4 a = *(const float4*)(qin + off);
    const bf16x4 p = *(const bf16x4*)(proj + off);
    x[c * 4 + 0] = a.x + (float)p[0];
    x[c * 4 + 1] = a.y + (float)p[1];
    x[c * 4 + 2] = a.z + (float)p[2];
    x[c * 4 + 3] = a.w + (float)p[3];
    s += x[c * 4 + 0] + x[c * 4 + 1] + x[c * 4 + 2] + x[c * 4 + 3];
  }
  for (int m = 32; m; m >>= 1) s += __shfl_xor(s, m);
  const float mean = s * (1.f / 1024.f);
  float ss = 0.f;
#pragma unroll
  for (int j = 0; j < 16; j++) {
    x[j] -= mean;
    ss += x[j] * x[j];
  }
  for (int m = 32; m; m >>= 1) ss += __shfl_xor(ss, m);
  const float inv = 1.f / (sqrtf(ss * (1.f / 1023.f)) + 1e-8f);
#pragma unroll
  for (int c = 0; c < 4; c++) {
    const size_t off = rbase + c * 256 + lane * 4;
    float4 o;
    o.x = x[c * 4 + 0] * inv; o.y = x[c * 4 + 1] * inv;
    o.z = x[c * 4 + 2] * inv; o.w = x[c * 4 + 3] * inv;
    *(float4*)(out + off) = o;
  }
}

// ---------------- host orchestration --------------------------------------
extern "C" void kernel_launch(void* const* d_in, const int* in_sizes, int n_in,
                              void* d_out, int out_size, void* d_ws, size_t ws_size,
                              hipStream_t stream) {
  (void)in_sizes; (void)n_in; (void)out_size; (void)ws_size;
  const float* queries = (const float*)d_in[0];
  const float* keys    = (const float*)d_in[1];
  const float* values  = (const float*)d_in[2];
  const float* Wq = (const float*)d_in[3];  const float* bq = (const float*)d_in[4];
  const float* Wk = (const float*)d_in[5];  const float* bk = (const float*)d_in[6];
  const float* Wv = (const float*)d_in[7];  const float* bv = (const float*)d_in[8];
  const float* Wo = (const float*)d_in[9];  const float* bo = (const float*)d_in[10];
  float* out = (float*)d_out;

  char* w = (char*)d_ws;
  const size_t SZ_X = (size_t)4096 * 1024 * 2;   // 8 MB (bf16 [4096,1024])
  const size_t SZ_W = (size_t)1024 * 1024 * 2;   // 2 MB
  short* Xq  = (short*)w; w += SZ_X;
  short* Xk  = (short*)w; w += SZ_X;
  short* Xv  = (short*)w; w += SZ_X;
  short* Wtq = (short*)w; w += SZ_W;
  short* Wtk = (short*)w; w += SZ_W;
  short* Wtv = (short*)w; w += SZ_W;
  short* Wto = (short*)w; w += SZ_W;
  short* Qb  = (short*)w; w += SZ_X;
  short* Kb  = (short*)w; w += SZ_X;
  short* Vtb = (short*)w; w += SZ_X;
  short* Ab  = (short*)w; w += SZ_X;
  short* proj = (short*)w; w += SZ_X;
  unsigned* kbits = (unsigned*)w; w += 4096;

  prep_kernel<<<13312, 256, 0, stream>>>(queries, keys, values, Xq, Xk, Xv,
                                         Wq, Wk, Wv, Wo, Wtq, Wtk, Wtv, Wto);
  qkv_gemm<<<dim3(8, 32, 3), 256, 0, stream>>>(Xq, Xk, Xv, Wtq, Wtk, Wtv,
                                               bq, bk, bv, Qb, Kb, Vtb);
  key_mask_kernel<<<128, 256, 0, stream>>>(Kb, kbits);
  attn_kernel<<<1024, 128, 0, stream>>>(Qb, Kb, Vtb, kbits, Ab);
  out_gemm<<<dim3(8, 64), 256, 0, stream>>>(Ab, Wto, bo, proj);
  ln_kernel<<<1024, 256, 0, stream>>>(queries, proj, out);
}

// Round 18
// 141.026 us; speedup vs baseline: 1.1772x; 1.0283x over previous
//
#include <hip/hip_runtime.h>
#include <math.h>

typedef __bf16 bf16;
typedef __attribute__((ext_vector_type(8))) __bf16 bf16x8;
typedef __attribute__((ext_vector_type(4))) __bf16 bf16x4;
typedef __attribute__((ext_vector_type(4))) float f32x4;

typedef __attribute__((address_space(1))) unsigned int glb_u32;
typedef __attribute__((address_space(3))) unsigned int lds_u32;

#define NEGV (-4294967295.0f)
#define SCL2 0.18033688011112042f  /* 0.125 * log2(e), folded into Q */

__device__ __forceinline__ void async_cp16(const void* g, void* l) {
  __builtin_amdgcn_global_load_lds((glb_u32*)g, (lds_u32*)l, 16, 0, 0);
}

// ---- DPP 16-lane butterfly reduce (VALU pipe, not LDS) --------------------
template <int CTRL>
__device__ __forceinline__ float dppf(float x) {
  return __builtin_bit_cast(float,
      __builtin_amdgcn_mov_dpp(__builtin_bit_cast(int, x), CTRL, 0xF, 0xF, true));
}
__device__ __forceinline__ float dpp_max16(float x) {
  x = fmaxf(x, dppf<0xB1>(x));
  x = fmaxf(x, dppf<0x4E>(x));
  x = fmaxf(x, dppf<0x141>(x));
  x = fmaxf(x, dppf<0x140>(x));
  return x;
}

// ---------------- fused prep: cvt3 (blocks 0..12287) + wt (12288..13311) ---
__global__ __launch_bounds__(256) void prep_kernel(
    const float* __restrict__ q, const float* __restrict__ k,
    const float* __restrict__ v, short* xq, short* xk, short* xv,
    const float* __restrict__ W0, const float* __restrict__ W1,
    const float* __restrict__ W2, const float* __restrict__ W3,
    short* T0, short* T1, short* T2, short* T3) {
  __shared__ float tile[64][65];
  const int bid = blockIdx.x;
  if (bid < 12288) {
    const int which = bid >> 12;           // 0..2
    const int i = (bid & 4095) * 256 + threadIdx.x;
    const float* src = which == 0 ? q : (which == 1 ? k : v);
    short* dst = which == 0 ? xq : (which == 1 ? xk : xv);
    float4 vv = ((const float4*)src)[i];
    bf16x4 o;
    o[0] = (bf16)vv.x; o[1] = (bf16)vv.y; o[2] = (bf16)vv.z; o[3] = (bf16)vv.w;
    ((bf16x4*)dst)[i] = o;
  } else {
    const int wb = bid - 12288;            // 0..1023
    const int z = wb >> 8;                 // 0..3
    const int k0 = ((wb >> 4) & 15) * 64, n0 = (wb & 15) * 64;
    const float* W = z == 0 ? W0 : (z == 1 ? W1 : (z == 2 ? W2 : W3));
    bf16* T = (bf16*)(z == 0 ? T0 : (z == 1 ? T1 : (z == 2 ? T2 : T3)));
    const int tid = threadIdx.x;
    const int c = tid & 63, rr = tid >> 6;
#pragma unroll
    for (int i = 0; i < 16; i++) {
      int r = i * 4 + rr;
      tile[r][c] = W[(size_t)(k0 + r) * 1024 + n0 + c];
    }
    __syncthreads();
#pragma unroll
    for (int i = 0; i < 16; i++) {
      int r = i * 4 + rr;
      T[(size_t)(n0 + r) * 1024 + k0 + c] = (bf16)tile[c][r];
    }
  }
}

// ---- shared helpers: bf16 tile, 64B rows, ((row>>1)&3)<<4 swz -------------
__device__ __forceinline__ bf16x8 lds_read_swz64(const bf16* base, int row, int cbyte) {
  return *(const bf16x8*)((const char*)base + row * 64 + (cbyte ^ (((row >> 1) & 3) << 4)));
}

// ---------------- QKV projection GEMM: Y = relu(X @ W + b) ----------------
__global__ __launch_bounds__(256) void qkv_gemm(
    const short* Xq_, const short* Xk_, const short* Xv_,
    const short* Wtq_, const short* Wtk_, const short* Wtv_,
    const float* __restrict__ bq_, const float* __restrict__ bk_, const float* __restrict__ bv_,
    short* Qo_, short* Ko_, short* Vto_) {
  __shared__ bf16 Alds[128][32];
  __shared__ bf16 Blds[128][32];
  const int which = blockIdx.z;
  const bf16* X  = (const bf16*)(which == 0 ? Xq_  : (which == 1 ? Xk_  : Xv_));
  const bf16* Wt = (const bf16*)(which == 0 ? Wtq_ : (which == 1 ? Wtk_ : Wtv_));
  const float* bias = which == 0 ? bq_ : (which == 1 ? bk_ : bv_);
  const int m0 = blockIdx.y * 128, n0 = blockIdx.x * 128;
  const int tid = threadIdx.x, wid = tid >> 6, lane = tid & 63;
  const int wr = wid >> 1, wc = wid & 1;
  const int l15 = lane & 15, lg = lane >> 4;
  const f32x4 vzero = {0.f, 0.f, 0.f, 0.f};
  f32x4 acc[4][4];
#pragma unroll
  for (int m = 0; m < 4; m++)
#pragma unroll
    for (int n = 0; n < 4; n++) acc[m][n] = vzero;

  const int srow = lane >> 2;                    // 0..15
  const int scbs = ((lane & 3) * 16) ^ (((srow >> 1) & 3) << 4);

  for (int kt = 0; kt < 32; ++kt) {
#pragma unroll
    for (int c = 0; c < 2; c++) {
      const char* ga = (const char*)(X + (size_t)(m0 + wid * 32 + c * 16 + srow) * 1024 + kt * 32) + scbs;
      async_cp16(ga, &Alds[wid * 32 + c * 16][0]);
      const char* gb = (const char*)(Wt + (size_t)(n0 + wid * 32 + c * 16 + srow) * 1024 + kt * 32) + scbs;
      async_cp16(gb, &Blds[wid * 32 + c * 16][0]);
    }
    __syncthreads();
    bf16x8 a[4], bb[4];
#pragma unroll
    for (int m = 0; m < 4; m++) a[m] = lds_read_swz64(&Alds[0][0], wr * 64 + m * 16 + l15, lg * 16);
#pragma unroll
    for (int n = 0; n < 4; n++) bb[n] = lds_read_swz64(&Blds[0][0], wc * 64 + n * 16 + l15, lg * 16);
#pragma unroll
    for (int m = 0; m < 4; m++)
#pragma unroll
      for (int n = 0; n < 4; n++)
        acc[m][n] = __builtin_amdgcn_mfma_f32_16x16x32_bf16(a[m], bb[n], acc[m][n], 0, 0, 0);
    __syncthreads();
  }

  if (which != 2) {
    bf16* Y = (bf16*)(which == 0 ? Qo_ : Ko_);
    const float osc = (which == 0) ? SCL2 : 1.0f;
#pragma unroll
    for (int n = 0; n < 4; n++) {
      const int col = n0 + wc * 64 + n * 16 + l15;
      const float bv = bias[col];
#pragma unroll
      for (int m = 0; m < 4; m++) {
        const int row0 = m0 + wr * 64 + m * 16 + lg * 4;
#pragma unroll
        for (int r = 0; r < 4; r++) {
          float v = acc[m][n][r] + bv;
          v = v > 0.f ? v : 0.f;
          Y[(size_t)(row0 + r) * 1024 + col] = (bf16)(v * osc);
        }
      }
    }
  } else {
    bf16* Vt = (bf16*)Vto_;
#pragma unroll
    for (int n = 0; n < 4; n++) {
      const int col = n0 + wc * 64 + n * 16 + l15;
      const float bv = bias[col];
#pragma unroll
      for (int m = 0; m < 4; m++) {
        const int row0 = m0 + wr * 64 + m * 16 + lg * 4;
        const int bb2 = row0 >> 11;
        const int s2 = row0 & 2047;
        bf16x4 pk;
#pragma unroll
        for (int r = 0; r < 4; r++) {
          float v = acc[m][n][r] + bv;
          v = v > 0.f ? v : 0.f;
          pk[r] = (bf16)v;
        }
        *(bf16x4*)(Vt + ((size_t)bb2 * 1024 + col) * 2048 + s2) = pk;
      }
    }
  }
}

// ------- output projection GEMM: 64x128 tiles, 512 blocks (2/CU) ----------
__global__ __launch_bounds__(256) void out_gemm(
    const short* A_, const short* Wt_, const float* __restrict__ bias,
    short* __restrict__ Y_) {
  __shared__ bf16 Alds[64][32];
  __shared__ bf16 Blds[128][32];
  const bf16* X = (const bf16*)A_;
  const bf16* Wt = (const bf16*)Wt_;
  bf16* Y = (bf16*)Y_;
  const int m0 = blockIdx.y * 64, n0 = blockIdx.x * 128;
  const int tid = threadIdx.x, wid = tid >> 6, lane = tid & 63;
  const int wr = wid >> 1, wc = wid & 1;
  const int l15 = lane & 15, lg = lane >> 4;
  const f32x4 vzero = {0.f, 0.f, 0.f, 0.f};
  f32x4 acc[2][4];
#pragma unroll
  for (int m = 0; m < 2; m++)
#pragma unroll
    for (int n = 0; n < 4; n++) acc[m][n] = vzero;

  const int srow = lane >> 2;
  const int scbs = ((lane & 3) * 16) ^ (((srow >> 1) & 3) << 4);

  for (int kt = 0; kt < 32; ++kt) {
    {
      const char* ga = (const char*)(X + (size_t)(m0 + wid * 16 + srow) * 1024 + kt * 32) + scbs;
      async_cp16(ga, &Alds[wid * 16][0]);
    }
#pragma unroll
    for (int c = 0; c < 2; c++) {
      const char* gb = (const char*)(Wt + (size_t)(n0 + wid * 32 + c * 16 + srow) * 1024 + kt * 32) + scbs;
      async_cp16(gb, &Blds[wid * 32 + c * 16][0]);
    }
    __syncthreads();
    bf16x8 a[2], bb[4];
#pragma unroll
    for (int m = 0; m < 2; m++) a[m] = lds_read_swz64(&Alds[0][0], wr * 32 + m * 16 + l15, lg * 16);
#pragma unroll
    for (int n = 0; n < 4; n++) bb[n] = lds_read_swz64(&Blds[0][0], wc * 64 + n * 16 + l15, lg * 16);
#pragma unroll
    for (int m = 0; m < 2; m++)
#pragma unroll
      for (int n = 0; n < 4; n++)
        acc[m][n] = __builtin_amdgcn_mfma_f32_16x16x32_bf16(a[m], bb[n], acc[m][n], 0, 0, 0);
    __syncthreads();
  }
#pragma unroll
  for (int n = 0; n < 4; n++) {
    const int col = n0 + wc * 64 + n * 16 + l15;
    const float bv = bias[col];
#pragma unroll
    for (int m = 0; m < 2; m++) {
      const int row0 = m0 + wr * 32 + m * 16 + lg * 4;
#pragma unroll
      for (int r = 0; r < 4; r++) {
        float v = acc[m][n][r] + bv;
        Y[(size_t)(row0 + r) * 1024 + col] = (bf16)(v > 0.f ? v : 0.f);
      }
    }
  }
}

// ------ key padding mask as bitmask: bit(row%32) of word[row/32] ----------
__global__ __launch_bounds__(256) void key_mask_kernel(const short* Kb_,
                                                       unsigned* __restrict__ kbits) {
  __shared__ unsigned bits[4];
  const bf16* Kb = (const bf16*)Kb_;
  const int wid = threadIdx.x >> 6, lane = threadIdx.x & 63;
  const int row0 = blockIdx.x * 32 + wid * 8;
  unsigned mybits = 0;
#pragma unroll
  for (int i = 0; i < 8; i++) {
    const bf16x8* p = (const bf16x8*)(Kb + (size_t)(row0 + i) * 1024);
    bf16x8 v0 = p[lane];
    bf16x8 v1 = p[64 + lane];
    float s = 0.f;
#pragma unroll
    for (int jj = 0; jj < 8; jj++) s += (float)v0[jj] + (float)v1[jj];
    for (int m = 32; m; m >>= 1) s += __shfl_xor(s, m);
    if (s != 0.f) mybits |= 1u << (wid * 8 + i);
  }
  if (lane == 0) bits[wid] = mybits;
  __syncthreads();
  if (threadIdx.x == 0) kbits[blockIdx.x] = bits[0] | bits[1] | bits[2] | bits[3];
}

// ---------------- causal flash attention, v9 -------------------------------
// 512 blocks x 256 threads (4 waves). 64-row q-tile per segment; K/V tile
// (64 keys) staged ONCE per block and shared by all 4 waves -> staging LDS
// traffic per q-row HALVED vs v8.1 (the measured LDS-pipe bottleneck).
// Pairing: block handles q-tiles {p, 31-p} -> exactly 33 iters, flat.
// 512 blocks = 2/CU resident (LDS 40KB), zero tail. Inner loop = v8.1.
__device__ __forceinline__ bf16x8 lds_read_swz(const bf16* base, int row, int cbyte) {
  return *(const bf16x8*)((const char*)base + row * 128 + (cbyte ^ ((row & 7) << 4)));
}

__global__ __launch_bounds__(256) void attn_kernel(
    const short* Q_, const short* K_, const short* Vt_,
    const unsigned* __restrict__ kbits, short* O_) {
  __shared__ bf16 Klds[2][64][64];
  __shared__ bf16 Vlds[2][64][64];
  __shared__ bf16 Plds[4][16][64];
  const bf16* Q = (const bf16*)Q_;
  const bf16* K = (const bf16*)K_;
  const bf16* Vt = (const bf16*)Vt_;
  bf16* O = (bf16*)O_;

  // XCD decode: 512 blocks = 8 xcd x 64; all 16 pair-blocks of one (h,b)
  // on one XCD.
  const int f = blockIdx.x;
  const int xcd = f & 7, idx = f >> 3;   // idx 0..63
  const int ptb = idx & 15;              // pair id 0..15
  const int hb = xcd + 8 * (idx >> 4);   // 0..31
  const int h = hb & 15, b = hb >> 4;

  const int tid = threadIdx.x, wid = tid >> 6, lane = tid & 63;
  const int l15 = lane & 15, lg = lane >> 4;
  const f32x4 vzero = {0.f, 0.f, 0.f, 0.f};
  bf16* const pbase = &Plds[wid][0][0];

  // staging: 8 lanes per 128B row; one call = 8 rows; wave stages its
  // 16 K-rows + 16 V-rows (2+2 calls)
  const int srow = lane >> 3;        // 0..7
  const int cb = (lane & 7) * 16;
  const int cbs = cb ^ ((srow & 7) << 4);

  bf16x8 vones;
#pragma unroll
  for (int i = 0; i < 8; i++) vones[i] = (bf16)1.0f;

  for (int seg = 0; seg < 2; ++seg) {
    const int qt = (seg == 0) ? ptb : 31 - ptb;   // 64-row tile id
    const int q0 = qt * 64;
    const int nkt = qt + 1;

    // Q fragments (wave owns rows q0 + wid*16 .. +15)
    const int qrow = q0 + wid * 16 + l15;
    const bf16* qp = Q + ((size_t)b * 2048 + qrow) * 1024 + h * 64;
    const bf16x8 qf0 = *(const bf16x8*)(qp + lg * 8);
    const bf16x8 qf1 = *(const bf16x8*)(qp + 32 + lg * 8);

    float Mrow[4];
    f32x4 oacc[4], oaccL;
#pragma unroll
    for (int r = 0; r < 4; r++) Mrow[r] = -INFINITY;
#pragma unroll
    for (int n = 0; n < 4; n++) oacc[n] = vzero;
    oaccL = vzero;
    float Mmin = -INFINITY;

    // running stage pointers: wave stages K rows [wid*16, wid*16+16) and
    // V rows [wid*16, wid*16+16) of each 64-key tile
    const char* kn = (const char*)(K + ((size_t)b * 2048 + wid * 16 + srow) * 1024 + h * 64) + cbs;
    const char* vn = (const char*)(Vt + ((size_t)b * 1024 + h * 64 + wid * 16 + srow) * 2048) + cbs;

    auto STAGE = [&](int buf) {
#pragma unroll
      for (int c = 0; c < 2; c++) {
        async_cp16(kn + c * 16384, &Klds[buf][wid * 16 + c * 8][0]);
        async_cp16(vn + c * 32768, &Vlds[buf][wid * 16 + c * 8][0]);
      }
      kn += 131072;   // 64 K-rows * 2048 B
      vn += 128;      // 64 tokens * 2 B
    };

    STAGE(0);
    __syncthreads();
    int cur = 0;
    for (int kt = 0; kt < nkt; ++kt) {
      if (kt + 1 < nkt) STAGE(cur ^ 1);

      // ---- S = Q K^T (scale folded into Q) ----
      f32x4 sacc[4];
#pragma unroll
      for (int n = 0; n < 4; n++) sacc[n] = vzero;
      {
        bf16x8 kf[4];
#pragma unroll
        for (int n = 0; n < 4; n++)
          kf[n] = lds_read_swz(&Klds[cur][0][0], n * 16 + l15, lg * 16);
        __builtin_amdgcn_s_setprio(1);
#pragma unroll
        for (int n = 0; n < 4; n++)
          sacc[n] = __builtin_amdgcn_mfma_f32_16x16x32_bf16(qf0, kf[n], sacc[n], 0, 0, 0);
        __builtin_amdgcn_s_setprio(0);
#pragma unroll
        for (int n = 0; n < 4; n++)
          kf[n] = lds_read_swz(&Klds[cur][0][0], n * 16 + l15, 64 + lg * 16);
        __builtin_amdgcn_s_setprio(1);
#pragma unroll
        for (int n = 0; n < 4; n++)
          sacc[n] = __builtin_amdgcn_mfma_f32_16x16x32_bf16(qf1, kf[n], sacc[n], 0, 0, 0);
        __builtin_amdgcn_s_setprio(0);
      }

      // ---- key-padding bitmask + causal: wave-uniform fast path ----
      const unsigned w0 = kbits[b * 64 + kt * 2];
      const unsigned w1 = kbits[b * 64 + kt * 2 + 1];
      const bool last = (kt == nkt - 1);
      if (last || ((w0 & w1) != 0xFFFFFFFFu)) {
        const int qrow0 = q0 + wid * 16 + lg * 4;
#pragma unroll
        for (int n = 0; n < 4; n++) {
          const unsigned wsel = (n < 2) ? w0 : w1;
          const bool on = (wsel >> ((n & 1) * 16 + l15)) & 1;
          const int kcol = kt * 64 + n * 16 + l15;
#pragma unroll
          for (int r = 0; r < 4; r++) {
            float sc = sacc[n][r];
            if (!on) sc = NEGV;
            if (last && kcol > qrow0 + r) sc = NEGV;
            sacc[n][r] = sc;
          }
        }
      }

      // ---- deferred-max gate: ONE dpp chain on the common path ----
      {
        float lm = sacc[0][0];
#pragma unroll
        for (int n = 0; n < 4; n++)
#pragma unroll
          for (int r = 0; r < 4; r++) lm = fmaxf(lm, sacc[n][r]);
        const float gmax = dpp_max16(lm);
        if (!__all(gmax <= Mmin + 8.f)) {
#pragma unroll
          for (int r = 0; r < 4; r++) {
            float tm = fmaxf(fmaxf(sacc[0][r], sacc[1][r]), fmaxf(sacc[2][r], sacc[3][r]));
            tm = dpp_max16(tm);
            const float Mn = fmaxf(Mrow[r], tm);
            const float sc = exp2f(Mrow[r] - Mn);
            Mrow[r] = Mn;
#pragma unroll
            for (int n = 0; n < 4; n++) oacc[n][r] *= sc;
            oaccL[r] *= sc;
          }
          Mmin = fminf(fminf(Mrow[0], Mrow[1]), fminf(Mrow[2], Mrow[3]));
        }
      }

      // ---- P = exp2(S - M) -> per-wave LDS ----
#pragma unroll
      for (int n = 0; n < 4; n++)
#pragma unroll
        for (int r = 0; r < 4; r++) {
          const float p = exp2f(sacc[n][r] - Mrow[r]);
          const int prow = lg * 4 + r;
          *(bf16*)((char*)pbase + prow * 128 +
                   (((n * 16 + l15) * 2) ^ ((prow & 7) << 4))) = (bf16)p;
        }

      // ---- O += P V ; L += P * 1 ----
#pragma unroll
      for (int ks = 0; ks < 2; ks++) {
        bf16x8 vf[4];
#pragma unroll
        for (int nd = 0; nd < 4; nd++)
          vf[nd] = lds_read_swz(&Vlds[cur][0][0], nd * 16 + l15, ks * 64 + lg * 16);
        const bf16x8 pf = lds_read_swz(pbase, l15, ks * 64 + lg * 16);
        __builtin_amdgcn_s_setprio(1);
#pragma unroll
        for (int nd = 0; nd < 4; nd++)
          oacc[nd] = __builtin_amdgcn_mfma_f32_16x16x32_bf16(pf, vf[nd], oacc[nd], 0, 0, 0);
        oaccL = __builtin_amdgcn_mfma_f32_16x16x32_bf16(pf, vones, oaccL, 0, 0, 0);
        __builtin_amdgcn_s_setprio(0);
      }

      __syncthreads();
      cur ^= 1;
    }

    // ---- epilogue: O /= L ----
    float inv[4];
#pragma unroll
    for (int r = 0; r < 4; r++) inv[r] = 1.0f / oaccL[r];
#pragma unroll
    for (int nd = 0; nd < 4; nd++) {
      const int col = h * 64 + nd * 16 + l15;
#pragma unroll
      for (int r = 0; r < 4; r++) {
        const float v = oacc[nd][r] * inv[r];
        O[((size_t)b * 2048 + q0 + wid * 16 + lg * 4 + r) * 1024 + col] = (bf16)v;
      }
    }
  }
}

// -------- residual + LayerNorm: wave-per-row, no barriers/LDS -------------
__global__ __launch_bounds__(256) void ln_kernel(const float* __restrict__ qin,
                                                 const short* __restrict__ proj_,
                                                 float* __restrict__ out) {
  const bf16* proj = (const bf16*)proj_;
  const int row = blockIdx.x * 4 + (threadIdx.x >> 6);
  const int lane = threadIdx.x & 63;
  const size_t rbase = (size_t)row * 1024;

  float x[16];
  float s = 0.f;
#pragma unroll
  for (int c = 0; c < 4; c++) {
    const size_t off = rbase + c * 256 + lane * 4;
    const float4 a = *(const float4*)(qin + off);
    const bf16x4 p = *(const bf16x4*)(proj + off);
    x[c * 4 + 0] = a.x + (float)p[0];
    x[c * 4 + 1] = a.y + (float)p[1];
    x[c * 4 + 2] = a.z + (float)p[2];
    x[c * 4 + 3] = a.w + (float)p[3];
    s += x[c * 4 + 0] + x[c * 4 + 1] + x[c * 4 + 2] + x[c * 4 + 3];
  }
  for (int m = 32; m; m >>= 1) s += __shfl_xor(s, m);
  const float mean = s * (1.f / 1024.f);
  float ss = 0.f;
#pragma unroll
  for (int j = 0; j < 16; j++) {
    x[j] -= mean;
    ss += x[j] * x[j];
  }
  for (int m = 32; m; m >>= 1) ss += __shfl_xor(ss, m);
  const float inv = 1.f / (sqrtf(ss * (1.f / 1023.f)) + 1e-8f);
#pragma unroll
  for (int c = 0; c < 4; c++) {
    const size_t off = rbase + c * 256 + lane * 4;
    float4 o;
    o.x = x[c * 4 + 0] * inv; o.y = x[c * 4 + 1] * inv;
    o.z = x[c * 4 + 2] * inv; o.w = x[c * 4 + 3] * inv;
    *(float4*)(out + off) = o;
  }
}

// ---------------- host orchestration --------------------------------------
extern "C" void kernel_launch(void* const* d_in, const int* in_sizes, int n_in,
                              void* d_out, int out_size, void* d_ws, size_t ws_size,
                              hipStream_t stream) {
  (void)in_sizes; (void)n_in; (void)out_size; (void)ws_size;
  const float* queries = (const float*)d_in[0];
  const float* keys    = (const float*)d_in[1];
  const float* values  = (const float*)d_in[2];
  const float* Wq = (const float*)d_in[3];  const float* bq = (const float*)d_in[4];
  const float* Wk = (const float*)d_in[5];  const float* bk = (const float*)d_in[6];
  const float* Wv = (const float*)d_in[7];  const float* bv = (const float*)d_in[8];
  const float* Wo = (const float*)d_in[9];  const float* bo = (const float*)d_in[10];
  float* out = (float*)d_out;

  char* w = (char*)d_ws;
  const size_t SZ_X = (size_t)4096 * 1024 * 2;   // 8 MB (bf16 [4096,1024])
  const size_t SZ_W = (size_t)1024 * 1024 * 2;   // 2 MB
  short* Xq  = (short*)w; w += SZ_X;
  short* Xk  = (short*)w; w += SZ_X;
  short* Xv  = (short*)w; w += SZ_X;
  short* Wtq = (short*)w; w += SZ_W;
  short* Wtk = (short*)w; w += SZ_W;
  short* Wtv = (short*)w; w += SZ_W;
  short* Wto = (short*)w; w += SZ_W;
  short* Qb  = (short*)w; w += SZ_X;
  short* Kb  = (short*)w; w += SZ_X;
  short* Vtb = (short*)w; w += SZ_X;
  short* Ab  = (short*)w; w += SZ_X;
  short* proj = (short*)w; w += SZ_X;
  unsigned* kbits = (unsigned*)w; w += 4096;

  prep_kernel<<<13312, 256, 0, stream>>>(queries, keys, values, Xq, Xk, Xv,
                                         Wq, Wk, Wv, Wo, Wtq, Wtk, Wtv, Wto);
  qkv_gemm<<<dim3(8, 32, 3), 256, 0, stream>>>(Xq, Xk, Xv, Wtq, Wtk, Wtv,
                                               bq, bk, bv, Qb, Kb, Vtb);
  key_mask_kernel<<<128, 256, 0, stream>>>(Kb, kbits);
  attn_kernel<<<512, 256, 0, stream>>>(Qb, Kb, Vtb, kbits, Ab);
  out_gemm<<<dim3(8, 64), 256, 0, stream>>>(Ab, Wto, bo, proj);
  ln_kernel<<<1024, 256, 0, stream>>>(queries, proj, out);
}

// Round 19
// 138.989 us; speedup vs baseline: 1.1944x; 1.0147x over previous
//
#include <hip/hip_runtime.h>
#include <math.h>

typedef __bf16 bf16;
typedef __attribute__((ext_vector_type(8))) __bf16 bf16x8;
typedef __attribute__((ext_vector_type(4))) __bf16 bf16x4;
typedef __attribute__((ext_vector_type(4))) float f32x4;

typedef __attribute__((address_space(1))) unsigned int glb_u32;
typedef __attribute__((address_space(3))) unsigned int lds_u32;

#define NEGV (-4294967295.0f)
#define SCL2 0.18033688011112042f  /* 0.125 * log2(e), folded into Q */

__device__ __forceinline__ void async_cp16(const void* g, void* l) {
  __builtin_amdgcn_global_load_lds((glb_u32*)g, (lds_u32*)l, 16, 0, 0);
}

// ---- DPP 16-lane butterfly reduce (VALU pipe, not LDS) --------------------
template <int CTRL>
__device__ __forceinline__ float dppf(float x) {
  return __builtin_bit_cast(float,
      __builtin_amdgcn_mov_dpp(__builtin_bit_cast(int, x), CTRL, 0xF, 0xF, true));
}
__device__ __forceinline__ float dpp_max16(float x) {
  x = fmaxf(x, dppf<0xB1>(x));
  x = fmaxf(x, dppf<0x4E>(x));
  x = fmaxf(x, dppf<0x141>(x));
  x = fmaxf(x, dppf<0x140>(x));
  return x;
}

// ---------------- fused prep: cvt3 (blocks 0..12287) + wt (12288..13311) ---
__global__ __launch_bounds__(256) void prep_kernel(
    const float* __restrict__ q, const float* __restrict__ k,
    const float* __restrict__ v, short* xq, short* xk, short* xv,
    const float* __restrict__ W0, const float* __restrict__ W1,
    const float* __restrict__ W2, const float* __restrict__ W3,
    short* T0, short* T1, short* T2, short* T3) {
  __shared__ float tile[64][65];
  const int bid = blockIdx.x;
  if (bid < 12288) {
    const int which = bid >> 12;           // 0..2
    const int i = (bid & 4095) * 256 + threadIdx.x;
    const float* src = which == 0 ? q : (which == 1 ? k : v);
    short* dst = which == 0 ? xq : (which == 1 ? xk : xv);
    float4 vv = ((const float4*)src)[i];
    bf16x4 o;
    o[0] = (bf16)vv.x; o[1] = (bf16)vv.y; o[2] = (bf16)vv.z; o[3] = (bf16)vv.w;
    ((bf16x4*)dst)[i] = o;
  } else {
    const int wb = bid - 12288;            // 0..1023
    const int z = wb >> 8;                 // 0..3
    const int k0 = ((wb >> 4) & 15) * 64, n0 = (wb & 15) * 64;
    const float* W = z == 0 ? W0 : (z == 1 ? W1 : (z == 2 ? W2 : W3));
    bf16* T = (bf16*)(z == 0 ? T0 : (z == 1 ? T1 : (z == 2 ? T2 : T3)));
    const int tid = threadIdx.x;
    const int c = tid & 63, rr = tid >> 6;
#pragma unroll
    for (int i = 0; i < 16; i++) {
      int r = i * 4 + rr;
      tile[r][c] = W[(size_t)(k0 + r) * 1024 + n0 + c];
    }
    __syncthreads();
#pragma unroll
    for (int i = 0; i < 16; i++) {
      int r = i * 4 + rr;
      T[(size_t)(n0 + r) * 1024 + k0 + c] = (bf16)tile[c][r];
    }
  }
}

// ---- shared helpers: bf16 tile, 64B rows, ((row>>1)&3)<<4 swz -------------
__device__ __forceinline__ bf16x8 lds_read_swz64(const bf16* base, int row, int cbyte) {
  return *(const bf16x8*)((const char*)base + row * 64 + (cbyte ^ (((row >> 1) & 3) << 4)));
}

// ---------------- QKV projection GEMM: Y = relu(X @ W + b) ----------------
__global__ __launch_bounds__(256) void qkv_gemm(
    const short* Xq_, const short* Xk_, const short* Xv_,
    const short* Wtq_, const short* Wtk_, const short* Wtv_,
    const float* __restrict__ bq_, const float* __restrict__ bk_, const float* __restrict__ bv_,
    short* Qo_, short* Ko_, short* Vto_) {
  __shared__ bf16 Alds[128][32];
  __shared__ bf16 Blds[128][32];
  const int which = blockIdx.z;
  const bf16* X  = (const bf16*)(which == 0 ? Xq_  : (which == 1 ? Xk_  : Xv_));
  const bf16* Wt = (const bf16*)(which == 0 ? Wtq_ : (which == 1 ? Wtk_ : Wtv_));
  const float* bias = which == 0 ? bq_ : (which == 1 ? bk_ : bv_);
  const int m0 = blockIdx.y * 128, n0 = blockIdx.x * 128;
  const int tid = threadIdx.x, wid = tid >> 6, lane = tid & 63;
  const int wr = wid >> 1, wc = wid & 1;
  const int l15 = lane & 15, lg = lane >> 4;
  const f32x4 vzero = {0.f, 0.f, 0.f, 0.f};
  f32x4 acc[4][4];
#pragma unroll
  for (int m = 0; m < 4; m++)
#pragma unroll
    for (int n = 0; n < 4; n++) acc[m][n] = vzero;

  const int srow = lane >> 2;                    // 0..15
  const int scbs = ((lane & 3) * 16) ^ (((srow >> 1) & 3) << 4);

  for (int kt = 0; kt < 32; ++kt) {
#pragma unroll
    for (int c = 0; c < 2; c++) {
      const char* ga = (const char*)(X + (size_t)(m0 + wid * 32 + c * 16 + srow) * 1024 + kt * 32) + scbs;
      async_cp16(ga, &Alds[wid * 32 + c * 16][0]);
      const char* gb = (const char*)(Wt + (size_t)(n0 + wid * 32 + c * 16 + srow) * 1024 + kt * 32) + scbs;
      async_cp16(gb, &Blds[wid * 32 + c * 16][0]);
    }
    __syncthreads();
    bf16x8 a[4], bb[4];
#pragma unroll
    for (int m = 0; m < 4; m++) a[m] = lds_read_swz64(&Alds[0][0], wr * 64 + m * 16 + l15, lg * 16);
#pragma unroll
    for (int n = 0; n < 4; n++) bb[n] = lds_read_swz64(&Blds[0][0], wc * 64 + n * 16 + l15, lg * 16);
#pragma unroll
    for (int m = 0; m < 4; m++)
#pragma unroll
      for (int n = 0; n < 4; n++)
        acc[m][n] = __builtin_amdgcn_mfma_f32_16x16x32_bf16(a[m], bb[n], acc[m][n], 0, 0, 0);
    __syncthreads();
  }

  if (which != 2) {
    bf16* Y = (bf16*)(which == 0 ? Qo_ : Ko_);
    const float osc = (which == 0) ? SCL2 : 1.0f;
#pragma unroll
    for (int n = 0; n < 4; n++) {
      const int col = n0 + wc * 64 + n * 16 + l15;
      const float bv = bias[col];
#pragma unroll
      for (int m = 0; m < 4; m++) {
        const int row0 = m0 + wr * 64 + m * 16 + lg * 4;
#pragma unroll
        for (int r = 0; r < 4; r++) {
          float v = acc[m][n][r] + bv;
          v = v > 0.f ? v : 0.f;
          Y[(size_t)(row0 + r) * 1024 + col] = (bf16)(v * osc);
        }
      }
    }
  } else {
    bf16* Vt = (bf16*)Vto_;
#pragma unroll
    for (int n = 0; n < 4; n++) {
      const int col = n0 + wc * 64 + n * 16 + l15;
      const float bv = bias[col];
#pragma unroll
      for (int m = 0; m < 4; m++) {
        const int row0 = m0 + wr * 64 + m * 16 + lg * 4;
        const int bb2 = row0 >> 11;
        const int s2 = row0 & 2047;
        bf16x4 pk;
#pragma unroll
        for (int r = 0; r < 4; r++) {
          float v = acc[m][n][r] + bv;
          v = v > 0.f ? v : 0.f;
          pk[r] = (bf16)v;
        }
        *(bf16x4*)(Vt + ((size_t)bb2 * 1024 + col) * 2048 + s2) = pk;
      }
    }
  }
}

// ------- output projection GEMM: 64x128 tiles, 512 blocks (2/CU) ----------
__global__ __launch_bounds__(256) void out_gemm(
    const short* A_, const short* Wt_, const float* __restrict__ bias,
    short* __restrict__ Y_) {
  __shared__ bf16 Alds[64][32];
  __shared__ bf16 Blds[128][32];
  const bf16* X = (const bf16*)A_;
  const bf16* Wt = (const bf16*)Wt_;
  bf16* Y = (bf16*)Y_;
  const int m0 = blockIdx.y * 64, n0 = blockIdx.x * 128;
  const int tid = threadIdx.x, wid = tid >> 6, lane = tid & 63;
  const int wr = wid >> 1, wc = wid & 1;
  const int l15 = lane & 15, lg = lane >> 4;
  const f32x4 vzero = {0.f, 0.f, 0.f, 0.f};
  f32x4 acc[2][4];
#pragma unroll
  for (int m = 0; m < 2; m++)
#pragma unroll
    for (int n = 0; n < 4; n++) acc[m][n] = vzero;

  const int srow = lane >> 2;
  const int scbs = ((lane & 3) * 16) ^ (((srow >> 1) & 3) << 4);

  for (int kt = 0; kt < 32; ++kt) {
    {
      const char* ga = (const char*)(X + (size_t)(m0 + wid * 16 + srow) * 1024 + kt * 32) + scbs;
      async_cp16(ga, &Alds[wid * 16][0]);
    }
#pragma unroll
    for (int c = 0; c < 2; c++) {
      const char* gb = (const char*)(Wt + (size_t)(n0 + wid * 32 + c * 16 + srow) * 1024 + kt * 32) + scbs;
      async_cp16(gb, &Blds[wid * 32 + c * 16][0]);
    }
    __syncthreads();
    bf16x8 a[2], bb[4];
#pragma unroll
    for (int m = 0; m < 2; m++) a[m] = lds_read_swz64(&Alds[0][0], wr * 32 + m * 16 + l15, lg * 16);
#pragma unroll
    for (int n = 0; n < 4; n++) bb[n] = lds_read_swz64(&Blds[0][0], wc * 64 + n * 16 + l15, lg * 16);
#pragma unroll
    for (int m = 0; m < 2; m++)
#pragma unroll
      for (int n = 0; n < 4; n++)
        acc[m][n] = __builtin_amdgcn_mfma_f32_16x16x32_bf16(a[m], bb[n], acc[m][n], 0, 0, 0);
    __syncthreads();
  }
#pragma unroll
  for (int n = 0; n < 4; n++) {
    const int col = n0 + wc * 64 + n * 16 + l15;
    const float bv = bias[col];
#pragma unroll
    for (int m = 0; m < 2; m++) {
      const int row0 = m0 + wr * 32 + m * 16 + lg * 4;
#pragma unroll
      for (int r = 0; r < 4; r++) {
        float v = acc[m][n][r] + bv;
        Y[(size_t)(row0 + r) * 1024 + col] = (bf16)(v > 0.f ? v : 0.f);
      }
    }
  }
}

// ------ key padding mask as bitmask: bit(row%32) of word[row/32] ----------
__global__ __launch_bounds__(256) void key_mask_kernel(const short* Kb_,
                                                       unsigned* __restrict__ kbits) {
  __shared__ unsigned bits[4];
  const bf16* Kb = (const bf16*)Kb_;
  const int wid = threadIdx.x >> 6, lane = threadIdx.x & 63;
  const int row0 = blockIdx.x * 32 + wid * 8;
  unsigned mybits = 0;
#pragma unroll
  for (int i = 0; i < 8; i++) {
    const bf16x8* p = (const bf16x8*)(Kb + (size_t)(row0 + i) * 1024);
    bf16x8 v0 = p[lane];
    bf16x8 v1 = p[64 + lane];
    float s = 0.f;
#pragma unroll
    for (int jj = 0; jj < 8; jj++) s += (float)v0[jj] + (float)v1[jj];
    for (int m = 32; m; m >>= 1) s += __shfl_xor(s, m);
    if (s != 0.f) mybits |= 1u << (wid * 8 + i);
  }
  if (lane == 0) bits[wid] = mybits;
  __syncthreads();
  if (threadIdx.x == 0) kbits[blockIdx.x] = bits[0] | bits[1] | bits[2] | bits[3];
}

// ---------------- causal flash attention, v10 ------------------------------
// v9 geometry (512 blocks x 4 waves, 64-row tiles, pairs {p,31-p} = 33 iters)
// + 4-buffer stage-2-ahead pipeline with counted vmcnt across raw barriers:
// the per-round barrier no longer drains the in-flight prefetch (T3/T4).
// Safety: buf B (t&3) overwritten at round t-2's stage; last read at
// compute(t-4)... concretely: write of buf (r+2)&3 at round r, last read of
// that buf at compute(r-2) in round r-2, with barrier(r-1) strictly between.
__device__ __forceinline__ bf16x8 lds_read_swz(const bf16* base, int row, int cbyte) {
  return *(const bf16x8*)((const char*)base + row * 128 + (cbyte ^ ((row & 7) << 4)));
}

__global__ __launch_bounds__(256) void attn_kernel(
    const short* Q_, const short* K_, const short* Vt_,
    const unsigned* __restrict__ kbits, short* O_) {
  __shared__ bf16 Klds[4][64][64];
  __shared__ bf16 Vlds[4][64][64];
  __shared__ bf16 Plds[4][16][64];
  const bf16* Q = (const bf16*)Q_;
  const bf16* K = (const bf16*)K_;
  const bf16* Vt = (const bf16*)Vt_;
  bf16* O = (bf16*)O_;

  const int f = blockIdx.x;
  const int xcd = f & 7, idx = f >> 3;   // idx 0..63
  const int ptb = idx & 15;              // pair id 0..15
  const int hb = xcd + 8 * (idx >> 4);   // 0..31
  const int h = hb & 15, b = hb >> 4;

  const int tid = threadIdx.x, wid = tid >> 6, lane = tid & 63;
  const int l15 = lane & 15, lg = lane >> 4;
  const f32x4 vzero = {0.f, 0.f, 0.f, 0.f};
  bf16* const pbase = &Plds[wid][0][0];

  const int srow = lane >> 3;        // 0..7
  const int cb = (lane & 7) * 16;
  const int cbs = cb ^ ((srow & 7) << 4);

  bf16x8 vones;
#pragma unroll
  for (int i = 0; i < 8; i++) vones[i] = (bf16)1.0f;

  for (int seg = 0; seg < 2; ++seg) {
    const int qt = (seg == 0) ? ptb : 31 - ptb;   // 64-row tile id
    const int q0 = qt * 64;
    const int nkt = qt + 1;

    const int qrow = q0 + wid * 16 + l15;
    const bf16* qp = Q + ((size_t)b * 2048 + qrow) * 1024 + h * 64;
    const bf16x8 qf0 = *(const bf16x8*)(qp + lg * 8);
    const bf16x8 qf1 = *(const bf16x8*)(qp + 32 + lg * 8);

    float Mrow[4];
    f32x4 oacc[4], oaccL;
#pragma unroll
    for (int r = 0; r < 4; r++) Mrow[r] = -INFINITY;
#pragma unroll
    for (int n = 0; n < 4; n++) oacc[n] = vzero;
    oaccL = vzero;
    float Mmin = -INFINITY;

    // running stage pointers: wave stages K rows [wid*16,+16) and V rows
    // [wid*16,+16) of each 64-key tile; pointers advance once per STAGE.
    const char* kn = (const char*)(K + ((size_t)b * 2048 + wid * 16 + srow) * 1024 + h * 64) + cbs;
    const char* vn = (const char*)(Vt + ((size_t)b * 1024 + h * 64 + wid * 16 + srow) * 2048) + cbs;

    auto STAGE = [&](int buf) {
#pragma unroll
      for (int c = 0; c < 2; c++) {
        async_cp16(kn + c * 16384, &Klds[buf][wid * 16 + c * 8][0]);
        async_cp16(vn + c * 32768, &Vlds[buf][wid * 16 + c * 8][0]);
      }
      kn += 131072;   // 64 K-rows * 2048 B
      vn += 128;      // 64 tokens * 2 B
    };

    // prologue: stage tiles 0 and 1 (each wave: 4 loads per stage)
    STAGE(0);
    if (nkt > 1) STAGE(1);

    for (int kt = 0; kt < nkt; ++kt) {
      // stage 2 ahead
      if (kt + 2 < nkt) STAGE((kt + 2) & 3);
      // counted wait: all but the newest 4*ahead loads complete => tile kt
      // (and all older) fully landed for THIS wave; barrier publishes it.
      const int ahead = (nkt - 1 - kt) < 2 ? (nkt - 1 - kt) : 2;
      if (ahead == 2)      asm volatile("s_waitcnt vmcnt(8)" ::: "memory");
      else if (ahead == 1) asm volatile("s_waitcnt vmcnt(4)" ::: "memory");
      else                 asm volatile("s_waitcnt vmcnt(0)" ::: "memory");
      __builtin_amdgcn_sched_barrier(0);
      __builtin_amdgcn_s_barrier();

      const int cur = kt & 3;

      // ---- S = Q K^T (scale folded into Q) ----
      f32x4 sacc[4];
#pragma unroll
      for (int n = 0; n < 4; n++) sacc[n] = vzero;
      {
        bf16x8 kf[4];
#pragma unroll
        for (int n = 0; n < 4; n++)
          kf[n] = lds_read_swz(&Klds[cur][0][0], n * 16 + l15, lg * 16);
        __builtin_amdgcn_s_setprio(1);
#pragma unroll
        for (int n = 0; n < 4; n++)
          sacc[n] = __builtin_amdgcn_mfma_f32_16x16x32_bf16(qf0, kf[n], sacc[n], 0, 0, 0);
        __builtin_amdgcn_s_setprio(0);
#pragma unroll
        for (int n = 0; n < 4; n++)
          kf[n] = lds_read_swz(&Klds[cur][0][0], n * 16 + l15, 64 + lg * 16);
        __builtin_amdgcn_s_setprio(1);
#pragma unroll
        for (int n = 0; n < 4; n++)
          sacc[n] = __builtin_amdgcn_mfma_f32_16x16x32_bf16(qf1, kf[n], sacc[n], 0, 0, 0);
        __builtin_amdgcn_s_setprio(0);
      }

      // ---- key-padding bitmask + causal: wave-uniform fast path ----
      const unsigned w0 = kbits[b * 64 + kt * 2];
      const unsigned w1 = kbits[b * 64 + kt * 2 + 1];
      const bool last = (kt == nkt - 1);
      if (last || ((w0 & w1) != 0xFFFFFFFFu)) {
        const int qrow0 = q0 + wid * 16 + lg * 4;
#pragma unroll
        for (int n = 0; n < 4; n++) {
          const unsigned wsel = (n < 2) ? w0 : w1;
          const bool on = (wsel >> ((n & 1) * 16 + l15)) & 1;
          const int kcol = kt * 64 + n * 16 + l15;
#pragma unroll
          for (int r = 0; r < 4; r++) {
            float sc = sacc[n][r];
            if (!on) sc = NEGV;
            if (last && kcol > qrow0 + r) sc = NEGV;
            sacc[n][r] = sc;
          }
        }
      }

      // ---- deferred-max gate: ONE dpp chain on the common path ----
      {
        float lm = sacc[0][0];
#pragma unroll
        for (int n = 0; n < 4; n++)
#pragma unroll
          for (int r = 0; r < 4; r++) lm = fmaxf(lm, sacc[n][r]);
        const float gmax = dpp_max16(lm);
        if (!__all(gmax <= Mmin + 8.f)) {
#pragma unroll
          for (int r = 0; r < 4; r++) {
            float tm = fmaxf(fmaxf(sacc[0][r], sacc[1][r]), fmaxf(sacc[2][r], sacc[3][r]));
            tm = dpp_max16(tm);
            const float Mn = fmaxf(Mrow[r], tm);
            const float sc = exp2f(Mrow[r] - Mn);
            Mrow[r] = Mn;
#pragma unroll
            for (int n = 0; n < 4; n++) oacc[n][r] *= sc;
            oaccL[r] *= sc;
          }
          Mmin = fminf(fminf(Mrow[0], Mrow[1]), fminf(Mrow[2], Mrow[3]));
        }
      }

      // ---- P = exp2(S - M) -> per-wave LDS ----
#pragma unroll
      for (int n = 0; n < 4; n++)
#pragma unroll
        for (int r = 0; r < 4; r++) {
          const float p = exp2f(sacc[n][r] - Mrow[r]);
          const int prow = lg * 4 + r;
          *(bf16*)((char*)pbase + prow * 128 +
                   (((n * 16 + l15) * 2) ^ ((prow & 7) << 4))) = (bf16)p;
        }

      // ---- O += P V ; L += P * 1 ----
#pragma unroll
      for (int ks = 0; ks < 2; ks++) {
        bf16x8 vf[4];
#pragma unroll
        for (int nd = 0; nd < 4; nd++)
          vf[nd] = lds_read_swz(&Vlds[cur][0][0], nd * 16 + l15, ks * 64 + lg * 16);
        const bf16x8 pf = lds_read_swz(pbase, l15, ks * 64 + lg * 16);
        __builtin_amdgcn_s_setprio(1);
#pragma unroll
        for (int nd = 0; nd < 4; nd++)
          oacc[nd] = __builtin_amdgcn_mfma_f32_16x16x32_bf16(pf, vf[nd], oacc[nd], 0, 0, 0);
        oaccL = __builtin_amdgcn_mfma_f32_16x16x32_bf16(pf, vones, oaccL, 0, 0, 0);
        __builtin_amdgcn_s_setprio(0);
      }
    }

    // ---- epilogue: O /= L ----
    float inv[4];
#pragma unroll
    for (int r = 0; r < 4; r++) inv[r] = 1.0f / oaccL[r];
#pragma unroll
    for (int nd = 0; nd < 4; nd++) {
      const int col = h * 64 + nd * 16 + l15;
#pragma unroll
      for (int r = 0; r < 4; r++) {
        const float v = oacc[nd][r] * inv[r];
        O[((size_t)b * 2048 + q0 + wid * 16 + lg * 4 + r) * 1024 + col] = (bf16)v;
      }
    }
    // isolate buffer reuse between segments (all loads already drained by
    // the ahead==0 vmcnt(0) in the final rounds of this segment)
    __syncthreads();
  }
}

// -------- residual + LayerNorm: wave-per-row, no barriers/LDS -------------
__global__ __launch_bounds__(256) void ln_kernel(const float* __restrict__ qin,
                                                 const short* __restrict__ proj_,
                                                 float* __restrict__ out) {
  const bf16* proj = (const bf16*)proj_;
  const int row = blockIdx.x * 4 + (threadIdx.x >> 6);
  const int lane = threadIdx.x & 63;
  const size_t rbase = (size_t)row * 1024;

  float x[16];
  float s = 0.f;
#pragma unroll
  for (int c = 0; c < 4; c++) {
    const size_t off = rbase + c * 256 + lane * 4;
    const float4 a = *(const float4*)(qin + off);
    const bf16x4 p = *(const bf16x4*)(proj + off);
    x[c * 4 + 0] = a.x + (float)p[0];
    x[c * 4 + 1] = a.y + (float)p[1];
    x[c * 4 + 2] = a.z + (float)p[2];
    x[c * 4 + 3] = a.w + (float)p[3];
    s += x[c * 4 + 0] + x[c * 4 + 1] + x[c * 4 + 2] + x[c * 4 + 3];
  }
  for (int m = 32; m; m >>= 1) s += __shfl_xor(s, m);
  const float mean = s * (1.f / 1024.f);
  float ss = 0.f;
#pragma unroll
  for (int j = 0; j < 16; j++) {
    x[j] -= mean;
    ss += x[j] * x[j];
  }
  for (int m = 32; m; m >>= 1) ss += __shfl_xor(ss, m);
  const float inv = 1.f / (sqrtf(ss * (1.f / 1023.f)) + 1e-8f);
#pragma unroll
  for (int c = 0; c < 4; c++) {
    const size_t off = rbase + c * 256 + lane * 4;
    float4 o;
    o.x = x[c * 4 + 0] * inv; o.y = x[c * 4 + 1] * inv;
    o.z = x[c * 4 + 2] * inv; o.w = x[c * 4 + 3] * inv;
    *(float4*)(out + off) = o;
  }
}

// ---------------- host orchestration --------------------------------------
extern "C" void kernel_launch(void* const* d_in, const int* in_sizes, int n_in,
                              void* d_out, int out_size, void* d_ws, size_t ws_size,
                              hipStream_t stream) {
  (void)in_sizes; (void)n_in; (void)out_size; (void)ws_size;
  const float* queries = (const float*)d_in[0];
  const float* keys    = (const float*)d_in[1];
  const float* values  = (const float*)d_in[2];
  const float* Wq = (const float*)d_in[3];  const float* bq = (const float*)d_in[4];
  const float* Wk = (const float*)d_in[5];  const float* bk = (const float*)d_in[6];
  const float* Wv = (const float*)d_in[7];  const float* bv = (const float*)d_in[8];
  const float* Wo = (const float*)d_in[9];  const float* bo = (const float*)d_in[10];
  float* out = (float*)d_out;

  char* w = (char*)d_ws;
  const size_t SZ_X = (size_t)4096 * 1024 * 2;   // 8 MB (bf16 [4096,1024])
  const size_t SZ_W = (size_t)1024 * 1024 * 2;   // 2 MB
  short* Xq  = (short*)w; w += SZ_X;
  short* Xk  = (short*)w; w += SZ_X;
  short* Xv  = (short*)w; w += SZ_X;
  short* Wtq = (short*)w; w += SZ_W;
  short* Wtk = (short*)w; w += SZ_W;
  short* Wtv = (short*)w; w += SZ_W;
  short* Wto = (short*)w; w += SZ_W;
  short* Qb  = (short*)w; w += SZ_X;
  short* Kb  = (short*)w; w += SZ_X;
  short* Vtb = (short*)w; w += SZ_X;
  short* Ab  = (short*)w; w += SZ_X;
  short* proj = (short*)w; w += SZ_X;
  unsigned* kbits = (unsigned*)w; w += 4096;

  prep_kernel<<<13312, 256, 0, stream>>>(queries, keys, values, Xq, Xk, Xv,
                                         Wq, Wk, Wv, Wo, Wtq, Wtk, Wtv, Wto);
  qkv_gemm<<<dim3(8, 32, 3), 256, 0, stream>>>(Xq, Xk, Xv, Wtq, Wtk, Wtv,
                                               bq, bk, bv, Qb, Kb, Vtb);
  key_mask_kernel<<<128, 256, 0, stream>>>(Kb, kbits);
  attn_kernel<<<512, 256, 0, stream>>>(Qb, Kb, Vtb, kbits, Ab);
  out_gemm<<<dim3(8, 64), 256, 0, stream>>>(Ab, Wto, bo, proj);
  ln_kernel<<<1024, 256, 0, stream>>>(queries, proj, out);
}

// Round 20
// 138.952 us; speedup vs baseline: 1.1947x; 1.0003x over previous
//
#include <hip/hip_runtime.h>
#include <math.h>

typedef __bf16 bf16;
typedef __attribute__((ext_vector_type(8))) __bf16 bf16x8;
typedef __attribute__((ext_vector_type(4))) __bf16 bf16x4;
typedef __attribute__((ext_vector_type(4))) float f32x4;

typedef __attribute__((address_space(1))) unsigned int glb_u32;
typedef __attribute__((address_space(3))) unsigned int lds_u32;

#define NEGV (-4294967295.0f)
#define SCL2 0.18033688011112042f  /* 0.125 * log2(e), folded into Q */

__device__ __forceinline__ void async_cp16(const void* g, void* l) {
  __builtin_amdgcn_global_load_lds((glb_u32*)g, (lds_u32*)l, 16, 0, 0);
}

// ---- DPP 16-lane butterfly reduce (VALU pipe, not LDS) --------------------
template <int CTRL>
__device__ __forceinline__ float dppf(float x) {
  return __builtin_bit_cast(float,
      __builtin_amdgcn_mov_dpp(__builtin_bit_cast(int, x), CTRL, 0xF, 0xF, true));
}
__device__ __forceinline__ float dpp_max16(float x) {
  x = fmaxf(x, dppf<0xB1>(x));
  x = fmaxf(x, dppf<0x4E>(x));
  x = fmaxf(x, dppf<0x141>(x));
  x = fmaxf(x, dppf<0x140>(x));
  return x;
}

// ---------------- fused prep: cvt3 (blocks 0..12287) + wt (12288..13311) ---
__global__ __launch_bounds__(256) void prep_kernel(
    const float* __restrict__ q, const float* __restrict__ k,
    const float* __restrict__ v, short* xq, short* xk, short* xv,
    const float* __restrict__ W0, const float* __restrict__ W1,
    const float* __restrict__ W2, const float* __restrict__ W3,
    short* T0, short* T1, short* T2, short* T3) {
  __shared__ float tile[64][65];
  const int bid = blockIdx.x;
  if (bid < 12288) {
    const int which = bid >> 12;           // 0..2
    const int i = (bid & 4095) * 256 + threadIdx.x;
    const float* src = which == 0 ? q : (which == 1 ? k : v);
    short* dst = which == 0 ? xq : (which == 1 ? xk : xv);
    float4 vv = ((const float4*)src)[i];
    bf16x4 o;
    o[0] = (bf16)vv.x; o[1] = (bf16)vv.y; o[2] = (bf16)vv.z; o[3] = (bf16)vv.w;
    ((bf16x4*)dst)[i] = o;
  } else {
    const int wb = bid - 12288;            // 0..1023
    const int z = wb >> 8;                 // 0..3
    const int k0 = ((wb >> 4) & 15) * 64, n0 = (wb & 15) * 64;
    const float* W = z == 0 ? W0 : (z == 1 ? W1 : (z == 2 ? W2 : W3));
    bf16* T = (bf16*)(z == 0 ? T0 : (z == 1 ? T1 : (z == 2 ? T2 : T3)));
    const int tid = threadIdx.x;
    const int c = tid & 63, rr = tid >> 6;
#pragma unroll
    for (int i = 0; i < 16; i++) {
      int r = i * 4 + rr;
      tile[r][c] = W[(size_t)(k0 + r) * 1024 + n0 + c];
    }
    __syncthreads();
#pragma unroll
    for (int i = 0; i < 16; i++) {
      int r = i * 4 + rr;
      T[(size_t)(n0 + r) * 1024 + k0 + c] = (bf16)tile[c][r];
    }
  }
}

// ---- shared helpers: bf16 tile, 64B rows, ((row>>1)&3)<<4 swz -------------
__device__ __forceinline__ bf16x8 lds_read_swz64(const bf16* base, int row, int cbyte) {
  return *(const bf16x8*)((const char*)base + row * 64 + (cbyte ^ (((row >> 1) & 3) << 4)));
}

// ---------------- QKV projection GEMM: Y = relu(X @ W + b) ----------------
__global__ __launch_bounds__(256) void qkv_gemm(
    const short* Xq_, const short* Xk_, const short* Xv_,
    const short* Wtq_, const short* Wtk_, const short* Wtv_,
    const float* __restrict__ bq_, const float* __restrict__ bk_, const float* __restrict__ bv_,
    short* Qo_, short* Ko_, short* Vto_) {
  __shared__ bf16 Alds[128][32];
  __shared__ bf16 Blds[128][32];
  const int which = blockIdx.z;
  const bf16* X  = (const bf16*)(which == 0 ? Xq_  : (which == 1 ? Xk_  : Xv_));
  const bf16* Wt = (const bf16*)(which == 0 ? Wtq_ : (which == 1 ? Wtk_ : Wtv_));
  const float* bias = which == 0 ? bq_ : (which == 1 ? bk_ : bv_);
  const int m0 = blockIdx.y * 128, n0 = blockIdx.x * 128;
  const int tid = threadIdx.x, wid = tid >> 6, lane = tid & 63;
  const int wr = wid >> 1, wc = wid & 1;
  const int l15 = lane & 15, lg = lane >> 4;
  const f32x4 vzero = {0.f, 0.f, 0.f, 0.f};
  f32x4 acc[4][4];
#pragma unroll
  for (int m = 0; m < 4; m++)
#pragma unroll
    for (int n = 0; n < 4; n++) acc[m][n] = vzero;

  const int srow = lane >> 2;                    // 0..15
  const int scbs = ((lane & 3) * 16) ^ (((srow >> 1) & 3) << 4);

  for (int kt = 0; kt < 32; ++kt) {
#pragma unroll
    for (int c = 0; c < 2; c++) {
      const char* ga = (const char*)(X + (size_t)(m0 + wid * 32 + c * 16 + srow) * 1024 + kt * 32) + scbs;
      async_cp16(ga, &Alds[wid * 32 + c * 16][0]);
      const char* gb = (const char*)(Wt + (size_t)(n0 + wid * 32 + c * 16 + srow) * 1024 + kt * 32) + scbs;
      async_cp16(gb, &Blds[wid * 32 + c * 16][0]);
    }
    __syncthreads();
    bf16x8 a[4], bb[4];
#pragma unroll
    for (int m = 0; m < 4; m++) a[m] = lds_read_swz64(&Alds[0][0], wr * 64 + m * 16 + l15, lg * 16);
#pragma unroll
    for (int n = 0; n < 4; n++) bb[n] = lds_read_swz64(&Blds[0][0], wc * 64 + n * 16 + l15, lg * 16);
#pragma unroll
    for (int m = 0; m < 4; m++)
#pragma unroll
      for (int n = 0; n < 4; n++)
        acc[m][n] = __builtin_amdgcn_mfma_f32_16x16x32_bf16(a[m], bb[n], acc[m][n], 0, 0, 0);
    __syncthreads();
  }

  if (which != 2) {
    bf16* Y = (bf16*)(which == 0 ? Qo_ : Ko_);
    const float osc = (which == 0) ? SCL2 : 1.0f;
#pragma unroll
    for (int n = 0; n < 4; n++) {
      const int col = n0 + wc * 64 + n * 16 + l15;
      const float bv = bias[col];
#pragma unroll
      for (int m = 0; m < 4; m++) {
        const int row0 = m0 + wr * 64 + m * 16 + lg * 4;
#pragma unroll
        for (int r = 0; r < 4; r++) {
          float v = acc[m][n][r] + bv;
          v = v > 0.f ? v : 0.f;
          Y[(size_t)(row0 + r) * 1024 + col] = (bf16)(v * osc);
        }
      }
    }
  } else {
    bf16* Vt = (bf16*)Vto_;
#pragma unroll
    for (int n = 0; n < 4; n++) {
      const int col = n0 + wc * 64 + n * 16 + l15;
      const float bv = bias[col];
#pragma unroll
      for (int m = 0; m < 4; m++) {
        const int row0 = m0 + wr * 64 + m * 16 + lg * 4;
        const int bb2 = row0 >> 11;
        const int s2 = row0 & 2047;
        bf16x4 pk;
#pragma unroll
        for (int r = 0; r < 4; r++) {
          float v = acc[m][n][r] + bv;
          v = v > 0.f ? v : 0.f;
          pk[r] = (bf16)v;
        }
        *(bf16x4*)(Vt + ((size_t)bb2 * 1024 + col) * 2048 + s2) = pk;
      }
    }
  }
}

// ------- output projection GEMM: 64x128 tiles, 512 blocks (2/CU) ----------
__global__ __launch_bounds__(256) void out_gemm(
    const short* A_, const short* Wt_, const float* __restrict__ bias,
    short* __restrict__ Y_) {
  __shared__ bf16 Alds[64][32];
  __shared__ bf16 Blds[128][32];
  const bf16* X = (const bf16*)A_;
  const bf16* Wt = (const bf16*)Wt_;
  bf16* Y = (bf16*)Y_;
  const int m0 = blockIdx.y * 64, n0 = blockIdx.x * 128;
  const int tid = threadIdx.x, wid = tid >> 6, lane = tid & 63;
  const int wr = wid >> 1, wc = wid & 1;
  const int l15 = lane & 15, lg = lane >> 4;
  const f32x4 vzero = {0.f, 0.f, 0.f, 0.f};
  f32x4 acc[2][4];
#pragma unroll
  for (int m = 0; m < 2; m++)
#pragma unroll
    for (int n = 0; n < 4; n++) acc[m][n] = vzero;

  const int srow = lane >> 2;
  const int scbs = ((lane & 3) * 16) ^ (((srow >> 1) & 3) << 4);

  for (int kt = 0; kt < 32; ++kt) {
    {
      const char* ga = (const char*)(X + (size_t)(m0 + wid * 16 + srow) * 1024 + kt * 32) + scbs;
      async_cp16(ga, &Alds[wid * 16][0]);
    }
#pragma unroll
    for (int c = 0; c < 2; c++) {
      const char* gb = (const char*)(Wt + (size_t)(n0 + wid * 32 + c * 16 + srow) * 1024 + kt * 32) + scbs;
      async_cp16(gb, &Blds[wid * 32 + c * 16][0]);
    }
    __syncthreads();
    bf16x8 a[2], bb[4];
#pragma unroll
    for (int m = 0; m < 2; m++) a[m] = lds_read_swz64(&Alds[0][0], wr * 32 + m * 16 + l15, lg * 16);
#pragma unroll
    for (int n = 0; n < 4; n++) bb[n] = lds_read_swz64(&Blds[0][0], wc * 64 + n * 16 + l15, lg * 16);
#pragma unroll
    for (int m = 0; m < 2; m++)
#pragma unroll
      for (int n = 0; n < 4; n++)
        acc[m][n] = __builtin_amdgcn_mfma_f32_16x16x32_bf16(a[m], bb[n], acc[m][n], 0, 0, 0);
    __syncthreads();
  }
#pragma unroll
  for (int n = 0; n < 4; n++) {
    const int col = n0 + wc * 64 + n * 16 + l15;
    const float bv = bias[col];
#pragma unroll
    for (int m = 0; m < 2; m++) {
      const int row0 = m0 + wr * 32 + m * 16 + lg * 4;
#pragma unroll
      for (int r = 0; r < 4; r++) {
        float v = acc[m][n][r] + bv;
        Y[(size_t)(row0 + r) * 1024 + col] = (bf16)(v > 0.f ? v : 0.f);
      }
    }
  }
}

// ------ key padding mask as bitmask: bit(row%32) of word[row/32] ----------
__global__ __launch_bounds__(256) void key_mask_kernel(const short* Kb_,
                                                       unsigned* __restrict__ kbits) {
  __shared__ unsigned bits[4];
  const bf16* Kb = (const bf16*)Kb_;
  const int wid = threadIdx.x >> 6, lane = threadIdx.x & 63;
  const int row0 = blockIdx.x * 32 + wid * 8;
  unsigned mybits = 0;
#pragma unroll
  for (int i = 0; i < 8; i++) {
    const bf16x8* p = (const bf16x8*)(Kb + (size_t)(row0 + i) * 1024);
    bf16x8 v0 = p[lane];
    bf16x8 v1 = p[64 + lane];
    float s = 0.f;
#pragma unroll
    for (int jj = 0; jj < 8; jj++) s += (float)v0[jj] + (float)v1[jj];
    for (int m = 32; m; m >>= 1) s += __shfl_xor(s, m);
    if (s != 0.f) mybits |= 1u << (wid * 8 + i);
  }
  if (lane == 0) bits[wid] = mybits;
  __syncthreads();
  if (threadIdx.x == 0) kbits[blockIdx.x] = bits[0] | bits[1] | bits[2] | bits[3];
}

// ---------------- causal flash attention, v10.1 ----------------------------
// v10 (4-buffer stage-2-ahead counted-vmcnt pipeline) with:
//  - s_setprio REMOVED (T5 is ~0/negative on barrier-locked lockstep waves,
//    m190; it only pays on independent-wave or phase-split schedules)
//  - kbits prefetched one iteration ahead (scalar loads issued pre-barrier)
__device__ __forceinline__ bf16x8 lds_read_swz(const bf16* base, int row, int cbyte) {
  return *(const bf16x8*)((const char*)base + row * 128 + (cbyte ^ ((row & 7) << 4)));
}

__global__ __launch_bounds__(256) void attn_kernel(
    const short* Q_, const short* K_, const short* Vt_,
    const unsigned* __restrict__ kbits, short* O_) {
  __shared__ bf16 Klds[4][64][64];
  __shared__ bf16 Vlds[4][64][64];
  __shared__ bf16 Plds[4][16][64];
  const bf16* Q = (const bf16*)Q_;
  const bf16* K = (const bf16*)K_;
  const bf16* Vt = (const bf16*)Vt_;
  bf16* O = (bf16*)O_;

  const int f = blockIdx.x;
  const int xcd = f & 7, idx = f >> 3;   // idx 0..63
  const int ptb = idx & 15;              // pair id 0..15
  const int hb = xcd + 8 * (idx >> 4);   // 0..31
  const int h = hb & 15, b = hb >> 4;

  const int tid = threadIdx.x, wid = tid >> 6, lane = tid & 63;
  const int l15 = lane & 15, lg = lane >> 4;
  const f32x4 vzero = {0.f, 0.f, 0.f, 0.f};
  bf16* const pbase = &Plds[wid][0][0];

  const int srow = lane >> 3;        // 0..7
  const int cb = (lane & 7) * 16;
  const int cbs = cb ^ ((srow & 7) << 4);

  bf16x8 vones;
#pragma unroll
  for (int i = 0; i < 8; i++) vones[i] = (bf16)1.0f;

  for (int seg = 0; seg < 2; ++seg) {
    const int qt = (seg == 0) ? ptb : 31 - ptb;   // 64-row tile id
    const int q0 = qt * 64;
    const int nkt = qt + 1;

    const int qrow = q0 + wid * 16 + l15;
    const bf16* qp = Q + ((size_t)b * 2048 + qrow) * 1024 + h * 64;
    const bf16x8 qf0 = *(const bf16x8*)(qp + lg * 8);
    const bf16x8 qf1 = *(const bf16x8*)(qp + 32 + lg * 8);

    float Mrow[4];
    f32x4 oacc[4], oaccL;
#pragma unroll
    for (int r = 0; r < 4; r++) Mrow[r] = -INFINITY;
#pragma unroll
    for (int n = 0; n < 4; n++) oacc[n] = vzero;
    oaccL = vzero;
    float Mmin = -INFINITY;

    const char* kn = (const char*)(K + ((size_t)b * 2048 + wid * 16 + srow) * 1024 + h * 64) + cbs;
    const char* vn = (const char*)(Vt + ((size_t)b * 1024 + h * 64 + wid * 16 + srow) * 2048) + cbs;

    auto STAGE = [&](int buf) {
#pragma unroll
      for (int c = 0; c < 2; c++) {
        async_cp16(kn + c * 16384, &Klds[buf][wid * 16 + c * 8][0]);
        async_cp16(vn + c * 32768, &Vlds[buf][wid * 16 + c * 8][0]);
      }
      kn += 131072;   // 64 K-rows * 2048 B
      vn += 128;      // 64 tokens * 2 B
    };

    // prologue: stage tiles 0 and 1
    STAGE(0);
    if (nkt > 1) STAGE(1);

    // kbits prefetch for kt=0
    unsigned w0 = kbits[b * 64], w1 = kbits[b * 64 + 1];

    for (int kt = 0; kt < nkt; ++kt) {
      if (kt + 2 < nkt) STAGE((kt + 2) & 3);
      // prefetch kbits for next iteration (uniform scalar loads)
      unsigned nw0 = 0xFFFFFFFFu, nw1 = 0xFFFFFFFFu;
      if (kt + 1 < nkt) {
        nw0 = kbits[b * 64 + (kt + 1) * 2];
        nw1 = kbits[b * 64 + (kt + 1) * 2 + 1];
      }
      const int ahead = (nkt - 1 - kt) < 2 ? (nkt - 1 - kt) : 2;
      if (ahead == 2)      asm volatile("s_waitcnt vmcnt(8)" ::: "memory");
      else if (ahead == 1) asm volatile("s_waitcnt vmcnt(4)" ::: "memory");
      else                 asm volatile("s_waitcnt vmcnt(0)" ::: "memory");
      __builtin_amdgcn_sched_barrier(0);
      __builtin_amdgcn_s_barrier();

      const int cur = kt & 3;

      // ---- S = Q K^T (scale folded into Q) ----
      f32x4 sacc[4];
#pragma unroll
      for (int n = 0; n < 4; n++) sacc[n] = vzero;
      {
        bf16x8 kf[4];
#pragma unroll
        for (int n = 0; n < 4; n++)
          kf[n] = lds_read_swz(&Klds[cur][0][0], n * 16 + l15, lg * 16);
#pragma unroll
        for (int n = 0; n < 4; n++)
          sacc[n] = __builtin_amdgcn_mfma_f32_16x16x32_bf16(qf0, kf[n], sacc[n], 0, 0, 0);
#pragma unroll
        for (int n = 0; n < 4; n++)
          kf[n] = lds_read_swz(&Klds[cur][0][0], n * 16 + l15, 64 + lg * 16);
#pragma unroll
        for (int n = 0; n < 4; n++)
          sacc[n] = __builtin_amdgcn_mfma_f32_16x16x32_bf16(qf1, kf[n], sacc[n], 0, 0, 0);
      }

      // ---- key-padding bitmask + causal: wave-uniform fast path ----
      const bool last = (kt == nkt - 1);
      if (last || ((w0 & w1) != 0xFFFFFFFFu)) {
        const int qrow0 = q0 + wid * 16 + lg * 4;
#pragma unroll
        for (int n = 0; n < 4; n++) {
          const unsigned wsel = (n < 2) ? w0 : w1;
          const bool on = (wsel >> ((n & 1) * 16 + l15)) & 1;
          const int kcol = kt * 64 + n * 16 + l15;
#pragma unroll
          for (int r = 0; r < 4; r++) {
            float sc = sacc[n][r];
            if (!on) sc = NEGV;
            if (last && kcol > qrow0 + r) sc = NEGV;
            sacc[n][r] = sc;
          }
        }
      }
      w0 = nw0; w1 = nw1;

      // ---- deferred-max gate: ONE dpp chain on the common path ----
      {
        float lm = sacc[0][0];
#pragma unroll
        for (int n = 0; n < 4; n++)
#pragma unroll
          for (int r = 0; r < 4; r++) lm = fmaxf(lm, sacc[n][r]);
        const float gmax = dpp_max16(lm);
        if (!__all(gmax <= Mmin + 8.f)) {
#pragma unroll
          for (int r = 0; r < 4; r++) {
            float tm = fmaxf(fmaxf(sacc[0][r], sacc[1][r]), fmaxf(sacc[2][r], sacc[3][r]));
            tm = dpp_max16(tm);
            const float Mn = fmaxf(Mrow[r], tm);
            const float sc = exp2f(Mrow[r] - Mn);
            Mrow[r] = Mn;
#pragma unroll
            for (int n = 0; n < 4; n++) oacc[n][r] *= sc;
            oaccL[r] *= sc;
          }
          Mmin = fminf(fminf(Mrow[0], Mrow[1]), fminf(Mrow[2], Mrow[3]));
        }
      }

      // ---- P = exp2(S - M) -> per-wave LDS ----
#pragma unroll
      for (int n = 0; n < 4; n++)
#pragma unroll
        for (int r = 0; r < 4; r++) {
          const float p = exp2f(sacc[n][r] - Mrow[r]);
          const int prow = lg * 4 + r;
          *(bf16*)((char*)pbase + prow * 128 +
                   (((n * 16 + l15) * 2) ^ ((prow & 7) << 4))) = (bf16)p;
        }

      // ---- O += P V ; L += P * 1 ----
#pragma unroll
      for (int ks = 0; ks < 2; ks++) {
        bf16x8 vf[4];
#pragma unroll
        for (int nd = 0; nd < 4; nd++)
          vf[nd] = lds_read_swz(&Vlds[cur][0][0], nd * 16 + l15, ks * 64 + lg * 16);
        const bf16x8 pf = lds_read_swz(pbase, l15, ks * 64 + lg * 16);
#pragma unroll
        for (int nd = 0; nd < 4; nd++)
          oacc[nd] = __builtin_amdgcn_mfma_f32_16x16x32_bf16(pf, vf[nd], oacc[nd], 0, 0, 0);
        oaccL = __builtin_amdgcn_mfma_f32_16x16x32_bf16(pf, vones, oaccL, 0, 0, 0);
      }
    }

    // ---- epilogue: O /= L ----
    float inv[4];
#pragma unroll
    for (int r = 0; r < 4; r++) inv[r] = 1.0f / oaccL[r];
#pragma unroll
    for (int nd = 0; nd < 4; nd++) {
      const int col = h * 64 + nd * 16 + l15;
#pragma unroll
      for (int r = 0; r < 4; r++) {
        const float v = oacc[nd][r] * inv[r];
        O[((size_t)b * 2048 + q0 + wid * 16 + lg * 4 + r) * 1024 + col] = (bf16)v;
      }
    }
    __syncthreads();
  }
}

// -------- residual + LayerNorm: wave-per-row, no barriers/LDS -------------
__global__ __launch_bounds__(256) void ln_kernel(const float* __restrict__ qin,
                                                 const short* __restrict__ proj_,
                                                 float* __restrict__ out) {
  const bf16* proj = (const bf16*)proj_;
  const int row = blockIdx.x * 4 + (threadIdx.x >> 6);
  const int lane = threadIdx.x & 63;
  const size_t rbase = (size_t)row * 1024;

  float x[16];
  float s = 0.f;
#pragma unroll
  for (int c = 0; c < 4; c++) {
    const size_t off = rbase + c * 256 + lane * 4;
    const float4 a = *(const float4*)(qin + off);
    const bf16x4 p = *(const bf16x4*)(proj + off);
    x[c * 4 + 0] = a.x + (float)p[0];
    x[c * 4 + 1] = a.y + (float)p[1];
    x[c * 4 + 2] = a.z + (float)p[2];
    x[c * 4 + 3] = a.w + (float)p[3];
    s += x[c * 4 + 0] + x[c * 4 + 1] + x[c * 4 + 2] + x[c * 4 + 3];
  }
  for (int m = 32; m; m >>= 1) s += __shfl_xor(s, m);
  const float mean = s * (1.f / 1024.f);
  float ss = 0.f;
#pragma unroll
  for (int j = 0; j < 16; j++) {
    x[j] -= mean;
    ss += x[j] * x[j];
  }
  for (int m = 32; m; m >>= 1) ss += __shfl_xor(ss, m);
  const float inv = 1.f / (sqrtf(ss * (1.f / 1023.f)) + 1e-8f);
#pragma unroll
  for (int c = 0; c < 4; c++) {
    const size_t off = rbase + c * 256 + lane * 4;
    float4 o;
    o.x = x[c * 4 + 0] * inv; o.y = x[c * 4 + 1] * inv;
    o.z = x[c * 4 + 2] * inv; o.w = x[c * 4 + 3] * inv;
    *(float4*)(out + off) = o;
  }
}

// ---------------- host orchestration --------------------------------------
extern "C" void kernel_launch(void* const* d_in, const int* in_sizes, int n_in,
                              void* d_out, int out_size, void* d_ws, size_t ws_size,
                              hipStream_t stream) {
  (void)in_sizes; (void)n_in; (void)out_size; (void)ws_size;
  const float* queries = (const float*)d_in[0];
  const float* keys    = (const float*)d_in[1];
  const float* values  = (const float*)d_in[2];
  const float* Wq = (const float*)d_in[3];  const float* bq = (const float*)d_in[4];
  const float* Wk = (const float*)d_in[5];  const float* bk = (const float*)d_in[6];
  const float* Wv = (const float*)d_in[7];  const float* bv = (const float*)d_in[8];
  const float* Wo = (const float*)d_in[9];  const float* bo = (const float*)d_in[10];
  float* out = (float*)d_out;

  char* w = (char*)d_ws;
  const size_t SZ_X = (size_t)4096 * 1024 * 2;   // 8 MB (bf16 [4096,1024])
  const size_t SZ_W = (size_t)1024 * 1024 * 2;   // 2 MB
  short* Xq  = (short*)w; w += SZ_X;
  short* Xk  = (short*)w; w += SZ_X;
  short* Xv  = (short*)w; w += SZ_X;
  short* Wtq = (short*)w; w += SZ_W;
  short* Wtk = (short*)w; w += SZ_W;
  short* Wtv = (short*)w; w += SZ_W;
  short* Wto = (short*)w; w += SZ_W;
  short* Qb  = (short*)w; w += SZ_X;
  short* Kb  = (short*)w; w += SZ_X;
  short* Vtb = (short*)w; w += SZ_X;
  short* Ab  = (short*)w; w += SZ_X;
  short* proj = (short*)w; w += SZ_X;
  unsigned* kbits = (unsigned*)w; w += 4096;

  prep_kernel<<<13312, 256, 0, stream>>>(queries, keys, values, Xq, Xk, Xv,
                                         Wq, Wk, Wv, Wo, Wtq, Wtk, Wtv, Wto);
  qkv_gemm<<<dim3(8, 32, 3), 256, 0, stream>>>(Xq, Xk, Xv, Wtq, Wtk, Wtv,
                                               bq, bk, bv, Qb, Kb, Vtb);
  key_mask_kernel<<<128, 256, 0, stream>>>(Kb, kbits);
  attn_kernel<<<512, 256, 0, stream>>>(Qb, Kb, Vtb, kbits, Ab);
  out_gemm<<<dim3(8, 64), 256, 0, stream>>>(Ab, Wto, bo, proj);
  ln_kernel<<<1024, 256, 0, stream>>>(queries, proj, out);
}